// Round 1
// baseline (3739.908 us; speedup 1.0000x reference)
//
#include <hip/hip_runtime.h>
#include <hip/hip_bf16.h>
#include <cstddef>
#include <cstdint>

#define DEV_INLINE __device__ __forceinline__

// Problem constants: BS=2, F=8, C=64, H=128, W=128, HEADS=4
// Nodes per batch: v:0-7, d:8-15, t:16, g:17  -> 36 nodes total
// Edges: 7 per batch (14), incidence entries: 67 per batch (134)

// col_start prefix sums for the 14 hyperedge segments (entries are contiguous)
__device__ __constant__ int c_cs[15] = {0,8,16,32,48,65,66,67,75,83,99,115,132,133,134};

// ---------------- text pool: tn[b, ch*4+j] = max_k (tf+tp)[b,ch,4j+k] ----------------
__global__ void k_text_pool(const float* __restrict__ tf, const float* __restrict__ tp,
                            float* __restrict__ tn) {
  int t = blockIdx.x * blockDim.x + threadIdx.x;
  if (t >= 512) return;
  int b = t >> 8, idx = t & 255;
  int ch = idx >> 2, j = idx & 3;
  const float* p = tf + ((size_t)b * 64 + ch) * 16 + j * 4;
  const float* q = tp + ((size_t)b * 64 + ch) * 16 + j * 4;
  float m = p[0] + q[0];
  m = fmaxf(m, p[1] + q[1]);
  m = fmaxf(m, p[2] + q[2]);
  m = fmaxf(m, p[3] + q[3]);
  tn[(size_t)b * 256 + idx] = m;
}

// ---------------- Conv2d k3 s2 p1 + bias + ReLU (optionally fused x=a+b input) -------
// Block: 256 thr = 16x16 output tile, 4 consecutive output channels per block.
template<int CI, bool FUSE>
__global__ __launch_bounds__(256) void k_conv_s2(
    const float* __restrict__ in, const float* __restrict__ in2,
    const float* __restrict__ w, const float* __restrict__ bias,
    float* __restrict__ out, int N, int CO, int HO, int WO) {
  const int H = HO * 2, W = WO * 2;
  const int tilesx = WO >> 4, tilesy = HO >> 4;
  int bid = blockIdx.x;
  int tx = bid % tilesx; bid /= tilesx;
  int ty = bid % tilesy; bid /= tilesy;
  int cb = bid % (CO >> 2); bid /= (CO >> 2);
  int n = bid;
  int co0 = cb << 2;
  int lx = threadIdx.x & 15, ly = threadIdx.x >> 4;
  int ox = (tx << 4) + lx, oy = (ty << 4) + ly;
  int ix0 = 2 * ox - 1, iy0 = 2 * oy - 1;
  bool vx0 = ix0 >= 0, vy0 = iy0 >= 0;           // only top/left can go OOB (stride2,p1)
  float acc[4] = {0.f, 0.f, 0.f, 0.f};
  const float* ip  = in + (size_t)n * CI * H * W;
  const float* ip2 = FUSE ? (in2 + (size_t)n * CI * H * W) : nullptr;
  for (int ci = 0; ci < CI; ++ci) {
    const float* rb  = ip + (size_t)ci * H * W;
    const float* rb2 = FUSE ? (ip2 + (size_t)ci * H * W) : nullptr;
    float t[9];
#pragma unroll
    for (int ky = 0; ky < 3; ++ky) {
      int iy = iy0 + ky;
      bool vy = (ky == 0) ? vy0 : true;
#pragma unroll
      for (int kx = 0; kx < 3; ++kx) {
        int ix = ix0 + kx;
        bool vx = (kx == 0) ? vx0 : true;
        float v = 0.f;
        if (vy && vx) {
          size_t o = (size_t)iy * W + ix;
          v = rb[o];
          if (FUSE) v += rb2[o];
        }
        t[ky * 3 + kx] = v;
      }
    }
#pragma unroll
    for (int c = 0; c < 4; ++c) {
      const float* ww = w + ((size_t)(co0 + c) * CI + ci) * 9;  // uniform -> s_load
      acc[c] += t[0]*ww[0] + t[1]*ww[1] + t[2]*ww[2]
              + t[3]*ww[3] + t[4]*ww[4] + t[5]*ww[5]
              + t[6]*ww[6] + t[7]*ww[7] + t[8]*ww[8];
    }
  }
#pragma unroll
  for (int c = 0; c < 4; ++c) {
    size_t o = ((size_t)(n * CO + co0 + c) * HO + oy) * WO + ox;
    out[o] = fmaxf(acc[c] + bias[co0 + c], 0.f);
  }
}

// ---------------- spatial max over HW + LayerNorm over 256 channels ----------------
__global__ __launch_bounds__(256) void k_maxln(const float* __restrict__ x,
                                               float* __restrict__ out, int HW) {
  int n = blockIdx.x, ch = threadIdx.x;  // C=256 fixed
  const float4* p4 = reinterpret_cast<const float4*>(x + ((size_t)n * 256 + ch) * HW);
  float m = -1e30f;
  for (int i = 0; i < (HW >> 2); ++i) {
    float4 v = p4[i];
    m = fmaxf(m, fmaxf(fmaxf(v.x, v.y), fmaxf(v.z, v.w)));
  }
  __shared__ float r1[256], r2[256];
  r1[ch] = m; __syncthreads();
  for (int s = 128; s > 0; s >>= 1) { if (ch < s) r1[ch] += r1[ch + s]; __syncthreads(); }
  float mu = r1[0] * (1.f / 256.f);
  float d = m - mu;
  r2[ch] = d * d; __syncthreads();
  for (int s = 128; s > 0; s >>= 1) { if (ch < s) r2[ch] += r2[ch + s]; __syncthreads(); }
  float var = r2[0] * (1.f / 256.f);
  out[(size_t)n * 256 + ch] = d * rsqrtf(var + 1e-5f);
}

// ---------------- build node features x0 (36,256): [vb, db, tn, obs] ----------------
__global__ void k_build_x(const float* __restrict__ vn, const float* __restrict__ dn,
                          const float* __restrict__ tn, float* __restrict__ x0) {
  int b = blockIdx.x, ch = threadIdx.x;
  float s = 0.f;
  for (int f = 0; f < 8; ++f) {
    float vv = vn[((size_t)b * 8 + f) * 256 + ch];
    float dd = dn[((size_t)b * 8 + f) * 256 + ch];
    s += vv + dd;
    x0[((size_t)b * 18 + f) * 256 + ch] = vv;
    x0[((size_t)b * 18 + 8 + f) * 256 + ch] = dd;
  }
  float tv = tn[(size_t)b * 256 + ch];
  x0[((size_t)b * 18 + 16) * 256 + ch] = tv;
  x0[((size_t)b * 18 + 17) * 256 + ch] = tv + s * (1.f / 8.f);
}

// ---------------- GNN linear: y(50,M) = [x(36,K); ea(14,K)] @ w(M,K)^T ----------------
__global__ __launch_bounds__(256) void k_gnn_lin(
    const float* __restrict__ x, const float* __restrict__ ea,
    const float* __restrict__ w, float* __restrict__ y, int K, int M) {
  int chunks = M >> 8;
  int r = blockIdx.x / chunks;
  int ob = (blockIdx.x % chunks) * 256 + threadIdx.x;
  const float* src = (r < 36) ? (x + (size_t)r * K) : (ea + (size_t)(r - 36) * K);
  __shared__ __align__(16) float sxr[512];
  for (int k = threadIdx.x; k < K; k += 256) sxr[k] = src[k];
  __syncthreads();
  const float4* w4 = reinterpret_cast<const float4*>(w + (size_t)ob * K);
  const float4* x4 = reinterpret_cast<const float4*>(sxr);
  float acc = 0.f;
  int k4 = K >> 2;
  for (int k = 0; k < k4; ++k) {
    float4 a = x4[k], b = w4[k];
    acc += a.x * b.x + a.y * b.y + a.z * b.z + a.w * b.w;
  }
  y[(size_t)r * M + ob] = acc;
}

// ---------------- attention dot products: sx(36,4), se(14,4) ----------------
__global__ void k_gnn_att(const float* __restrict__ y, const float* __restrict__ att,
                          float* __restrict__ sx, float* __restrict__ seb, int OC) {
  int t = threadIdx.x;
  if (t >= 200) return;
  int r = t >> 2, h = t & 3;
  const float* row = y + ((size_t)r * 4 + h) * OC;
  const float* ar = att + (size_t)h * 2 * OC + (r < 36 ? 0 : OC);
  float s = 0.f;
  for (int k = 0; k < OC; ++k) s += row[k] * ar[k];
  if (r < 36) sx[r * 4 + h] = s; else seb[(r - 36) * 4 + h] = s;
}

DEV_INLINE int row_of_entry(int c, int j) {
  int b = c / 7, lc = c % 7;
  int r;
  if (lc == 0) r = j;
  else if (lc == 1) r = 8 + j;
  else if (lc <= 4) r = j;      // groups v+d (j<16) and v+d+t (j<17, j==16 -> t)
  else if (lc == 5) r = 16;
  else r = 17;
  return 18 * b + r;
}

// ---------------- hypergraph attention softmax + 2-stage aggregation ----------------
__global__ __launch_bounds__(512) void k_gnn_agg(
    const float* __restrict__ y,    // (50, 4*OC): nodes then edges
    const float* __restrict__ sx,   // (36,4)
    const float* __restrict__ seb,  // (14,4)
    const float* __restrict__ ew,   // edge weights (34,), cols 0..13 used
    float* __restrict__ eb,         // scratch (14,4,OC)
    float* __restrict__ ho,         // out (36,OC) = relu(head-mean)
    int OC) {
  int t = threadIdx.x;
  __shared__ float a_s[536];
  // 1. raw attention logits + leaky_relu(0.2)
  for (int idx = t; idx < 536; idx += 512) {
    int i = idx >> 2, h = idx & 3;
    int b = i / 67, rr = i % 67;
    int lc, rowl;
    if (rr < 8)       { lc = 0; rowl = rr; }
    else if (rr < 16) { lc = 1; rowl = rr; }
    else if (rr < 32) { lc = 2; rowl = rr - 16; }
    else if (rr < 48) { lc = 3; rowl = rr - 32; }
    else if (rr < 65) { lc = 4; rowl = rr - 48; }
    else if (rr == 65){ lc = 5; rowl = 16; }
    else              { lc = 6; rowl = 17; }
    int row = 18 * b + rowl;
    int col = 7 * b + lc;
    float v = sx[row * 4 + h] + seb[col * 4 + h];
    a_s[idx] = (v > 0.f) ? v : 0.2f * v;
  }
  __syncthreads();
  // 2. per-(col,head) softmax over contiguous segment
  if (t < 56) {
    int c = t >> 2, h = t & 3;
    int st = c_cs[c], en = c_cs[c + 1];
    float m = -1e30f;
    for (int i = st; i < en; ++i) m = fmaxf(m, a_s[i * 4 + h]);
    float s = 0.f;
    for (int i = st; i < en; ++i) { float e = __expf(a_s[i * 4 + h] - m); a_s[i * 4 + h] = e; s += e; }
    float inv = 1.f / (s + 1e-16f);
    for (int i = st; i < en; ++i) a_s[i * 4 + h] *= inv;
  }
  __syncthreads();
  // 3. e[c,h,:] = (1/cnt) * sum_i a * xl[row(i),h,:]
  int M = 4 * OC;
  for (int idx = t; idx < 14 * 4 * OC; idx += 512) {
    int ch = idx % OC;
    int h  = (idx / OC) & 3;
    int c  = idx / (4 * OC);
    int st = c_cs[c], en = c_cs[c + 1];
    float Binv = 1.f / (float)(en - st);
    float s = 0.f;
    for (int i = st; i < en; ++i) {
      int row = row_of_entry(c, i - st);
      s += a_s[i * 4 + h] * y[(size_t)row * M + h * OC + ch];
    }
    eb[idx] = s * Binv;
  }
  __threadfence_block();
  __syncthreads();
  // 4. o[node,:] = relu( (D/4) * sum_h sum_{edges of node} a * e[col,h,:] )
  for (int idx = t; idx < 36 * OC; idx += 512) {
    int ch = idx % OC;
    int node = idx / OC;
    int b = node / 18, ln = node % 18;
    int ncols, cols[4], gis[4];
    if (ln < 16) {
      ncols = 4;
      cols[0] = b * 7 + (ln < 8 ? 0 : 1); gis[0] = b * 67 + ln;
      cols[1] = b * 7 + 2; gis[1] = b * 67 + 16 + ln;
      cols[2] = b * 7 + 3; gis[2] = b * 67 + 32 + ln;
      cols[3] = b * 7 + 4; gis[3] = b * 67 + 48 + ln;
    } else if (ln == 16) {
      ncols = 2;
      cols[0] = b * 7 + 4; gis[0] = b * 67 + 64;
      cols[1] = b * 7 + 5; gis[1] = b * 67 + 65;
      cols[2] = cols[3] = 0; gis[2] = gis[3] = 0;
    } else {
      ncols = 1;
      cols[0] = b * 7 + 6; gis[0] = b * 67 + 66;
      cols[1] = cols[2] = cols[3] = 0; gis[1] = gis[2] = gis[3] = 0;
    }
    float dsum = 0.f;
#pragma unroll
    for (int k = 0; k < 4; ++k) if (k < ncols) dsum += ew[cols[k]];
    float D = dsum > 0.f ? 1.f / dsum : 0.f;
    float s = 0.f;
#pragma unroll
    for (int k = 0; k < 4; ++k) {
      if (k < ncols) {
#pragma unroll
        for (int h = 0; h < 4; ++h)
          s += a_s[gis[k] * 4 + h] * eb[((size_t)cols[k] * 4 + h) * OC + ch];
      }
    }
    ho[idx] = fmaxf(0.25f * D * s, 0.f);
  }
}

// ---------------- GroupNorm(32) + SE layer (single block) ----------------
__global__ __launch_bounds__(512) void k_gn_se(
    const float* __restrict__ hin, const float* __restrict__ w1,
    const float* __restrict__ w2, float* __restrict__ x, int C, int Cr) {
  int t = threadIdx.x;
  int gs = C >> 5;  // C/32
  for (int idx = t; idx < 36 * 32; idx += 512) {
    int node = idx >> 5, g = idx & 31;
    const float* p = hin + (size_t)node * C + g * gs;
    float s = 0.f, s2 = 0.f;
    for (int k = 0; k < gs; ++k) { float v = p[k]; s += v; s2 += v * v; }
    float mu = s / gs;
    float var = s2 / gs - mu * mu;
    float inv = rsqrtf(fmaxf(var, 0.f) + 1e-5f);
    float* q = x + (size_t)node * C + g * gs;
    for (int k = 0; k < gs; ++k) q[k] = (p[k] - mu) * inv;
  }
  __threadfence_block();
  __syncthreads();
  __shared__ float smean[512];
  __shared__ float shid[32];
  __shared__ float sscale[512];
  if (t < C) {
    float s = 0.f;
    for (int nn = 0; nn < 36; ++nn) s += x[(size_t)nn * C + t];
    smean[t] = s * (1.f / 36.f);
  }
  __syncthreads();
  if (t < Cr) {
    float s = 0.f;
    for (int ch = 0; ch < C; ++ch) s += w1[(size_t)t * C + ch] * smean[ch];
    shid[t] = fmaxf(s, 0.f);
  }
  __syncthreads();
  if (t < C) {
    float s = 0.f;
    for (int k = 0; k < Cr; ++k) s += w2[(size_t)t * Cr + k] * shid[k];
    sscale[t] = 1.f / (1.f + __expf(-s));
  }
  __syncthreads();
  for (int idx = t; idx < 36 * C; idx += 512) x[idx] *= sscale[idx % C];
}

// ---------------- observers: out[b,ch] = max_j (tn + x2[node g])[ch*4+j] ----------------
__global__ void k_obs(const float* __restrict__ tn, const float* __restrict__ x2,
                      float* __restrict__ out) {
  int t = threadIdx.x;  // 128
  if (t >= 128) return;
  int b = t >> 6, ch = t & 63;
  const float* a = tn + (size_t)b * 256 + ch * 4;
  const float* c = x2 + ((size_t)b * 18 + 17) * 256 + ch * 4;
  float m = a[0] + c[0];
  m = fmaxf(m, a[1] + c[1]);
  m = fmaxf(m, a[2] + c[2]);
  m = fmaxf(m, a[3] + c[3]);
  out[b * 64 + ch] = m;
}

// ---------------- vr2 = v2 + vg broadcast ----------------
__global__ void k_addvg(float* __restrict__ v2, const float* __restrict__ x2) {
  int idx = blockIdx.x * 256 + threadIdx.x;  // total 16*256*1024
  if (idx >= 16 * 256 * 1024) return;
  int n = idx >> 18;
  int co = (idx >> 10) & 255;
  int b = n >> 3, fi = n & 7;
  v2[idx] += x2[((size_t)(b * 18 + fi)) * 256 + co];
}

// ---------------- ConvTranspose2d k3 s2 p1 op1 + bias + ReLU + residual ----------------
// Each thread computes a 2x2 output quad (uniform tap parity) x 4 output channels.
template<int CI, bool RES2>
__global__ __launch_bounds__(256) void k_deconv(
    const float* __restrict__ in, const float* __restrict__ w,
    const float* __restrict__ bias,
    const float* __restrict__ res, const float* __restrict__ resB,
    float* __restrict__ out, int N, int CO, int Hi, int Wi) {
  const int Ho = Hi * 2, Wo = Wi * 2;
  const int qtx = Wi >> 4, qty = Hi >> 4;
  int bid = blockIdx.x;
  int tqx = bid % qtx; bid /= qtx;
  int tqy = bid % qty; bid /= qty;
  int cb = bid % (CO >> 2); bid /= (CO >> 2);
  int n = bid;
  int co0 = cb << 2;
  int lx = threadIdx.x & 15, ly = threadIdx.x >> 4;
  int qx = (tqx << 4) + lx, qy = (tqy << 4) + ly;
  bool okx = (qx + 1) < Wi, oky = (qy + 1) < Hi;
  float acc[4][4];
#pragma unroll
  for (int c = 0; c < 4; ++c)
#pragma unroll
    for (int k = 0; k < 4; ++k) acc[c][k] = 0.f;
  for (int ci = 0; ci < CI; ++ci) {
    const float* ib = in + ((size_t)(n * CI + ci) * Hi + qy) * Wi + qx;
    float i00 = ib[0];
    float i01 = okx ? ib[1] : 0.f;
    float i10 = oky ? ib[Wi] : 0.f;
    float i11 = (okx && oky) ? ib[Wi + 1] : 0.f;
#pragma unroll
    for (int c = 0; c < 4; ++c) {
      const float* ww = w + ((size_t)ci * CO + co0 + c) * 9;  // uniform -> s_load
      float w00 = ww[0], w01 = ww[1], w02 = ww[2];
      float w10 = ww[3], w11 = ww[4], w12 = ww[5];
      float w20 = ww[6], w21 = ww[7], w22 = ww[8];
      acc[c][0] += i00 * w11;                                          // (even,even)
      acc[c][1] += i00 * w12 + i01 * w10;                              // (even,odd)
      acc[c][2] += i00 * w21 + i10 * w01;                              // (odd,even)
      acc[c][3] += i00 * w22 + i01 * w20 + i10 * w02 + i11 * w00;      // (odd,odd)
    }
  }
#pragma unroll
  for (int c = 0; c < 4; ++c) {
    float bv = bias[co0 + c];
#pragma unroll
    for (int dy = 0; dy < 2; ++dy)
#pragma unroll
      for (int dx = 0; dx < 2; ++dx) {
        int oy = 2 * qy + dy, ox = 2 * qx + dx;
        size_t o = ((size_t)(n * CO + co0 + c) * Ho + oy) * Wo + ox;
        float v = fmaxf(acc[c][dy * 2 + dx] + bv, 0.f);
        v += RES2 ? (res[o] + resB[o]) : res[o];
        out[o] = v;
      }
  }
}

extern "C" void kernel_launch(void* const* d_in, const int* in_sizes, int n_in,
                              void* d_out, int out_size, void* d_ws, size_t ws_size,
                              hipStream_t stream) {
  (void)in_sizes; (void)n_in; (void)out_size; (void)ws_size;
  const float* vf    = (const float*)d_in[0];
  const float* vp    = (const float*)d_in[1];
  const float* mf    = (const float*)d_in[2];
  const float* mp    = (const float*)d_in[3];
  const float* tf    = (const float*)d_in[4];
  const float* tp    = (const float*)d_in[5];
  const float* cv1w  = (const float*)d_in[6];
  const float* cv1b  = (const float*)d_in[7];
  const float* cv2w  = (const float*)d_in[8];
  const float* cv2b  = (const float*)d_in[9];
  const float* dc1w  = (const float*)d_in[10];
  const float* dc1b  = (const float*)d_in[11];
  const float* dc2w  = (const float*)d_in[12];
  const float* dc2b  = (const float*)d_in[13];
  const float* tc1w  = (const float*)d_in[14];
  const float* tc1b  = (const float*)d_in[15];
  const float* tc2w  = (const float*)d_in[16];
  const float* tc2b  = (const float*)d_in[17];
  const float* lin1w = (const float*)d_in[18];
  const float* att1  = (const float*)d_in[19];
  const float* lin2w = (const float*)d_in[20];
  const float* att2  = (const float*)d_in[21];
  const float* ew1   = (const float*)d_in[22];
  const float* ew2   = (const float*)d_in[23];
  const float* ea1   = (const float*)d_in[24];
  const float* ea2   = (const float*)d_in[25];
  const float* se1w1 = (const float*)d_in[26];
  const float* se1w2 = (const float*)d_in[27];
  const float* se2w1 = (const float*)d_in[28];
  const float* se2w2 = (const float*)d_in[29];

  float* ws  = (float*)d_ws;
  float* out = (float*)d_out;

  // workspace layout (floats); peak ~21.2M floats = ~85 MB
  float* bufD = ws;               // 8,388,608  : d1, later t1
  float* bufB = ws + 8388608;     // 8,388,608  : v1
  float* bufC = ws + 16777216;    // 4,194,304  : d2, later v2 (+vg)
  float* sm   = ws + 20971520;    // small buffers
  float* tn   = sm;               // 512
  float* vn   = sm + 512;         // 4096
  float* dn   = sm + 4608;        // 4096
  float* x0   = sm + 8704;        // 9216
  float* xl   = sm + 17920;       // 102400 (50x2048 L1 / 50x1024 L2)
  float* sx   = sm + 120320;      // 144
  float* seb  = sm + 120464;      // 56
  float* eb   = sm + 120520;      // 28672
  float* ho   = sm + 149192;      // 18432
  float* x1   = sm + 167624;      // 18432
  float* x2   = sm + 186056;      // 9216

  // 1. text pooling
  k_text_pool<<<2, 256, 0, stream>>>(tf, tp, tn);

  // 2. motion branch (pos add fused into conv1 reads)
  k_conv_s2<64,  true ><<<8192, 256, 0, stream>>>(mf, mp, dc1w, dc1b, bufD, 16, 128, 64, 64);
  k_conv_s2<128, false><<<4096, 256, 0, stream>>>(bufD, nullptr, dc2w, dc2b, bufC, 16, 256, 32, 32);
  k_maxln<<<16, 256, 0, stream>>>(bufC, dn, 1024);

  // 3. vision branch
  k_conv_s2<64,  true ><<<8192, 256, 0, stream>>>(vf, vp, cv1w, cv1b, bufB, 16, 128, 64, 64);
  k_conv_s2<128, false><<<4096, 256, 0, stream>>>(bufB, nullptr, cv2w, cv2b, bufC, 16, 256, 32, 32);
  k_maxln<<<16, 256, 0, stream>>>(bufC, vn, 1024);

  // 4. node features
  k_build_x<<<2, 256, 0, stream>>>(vn, dn, tn, x0);

  // 5. GNN layer 1 (in 256, OC 512)
  k_gnn_lin<<<50 * 8, 256, 0, stream>>>(x0, ea1, lin1w, xl, 256, 2048);
  k_gnn_att<<<1, 256, 0, stream>>>(xl, att1, sx, seb, 512);
  k_gnn_agg<<<1, 512, 0, stream>>>(xl, sx, seb, ew1, eb, ho, 512);
  k_gn_se<<<1, 512, 0, stream>>>(ho, se1w1, se1w2, x1, 512, 32);

  // 6. GNN layer 2 (in 512, OC 256)
  k_gnn_lin<<<50 * 4, 256, 0, stream>>>(x1, ea2, lin2w, xl, 512, 1024);
  k_gnn_att<<<1, 256, 0, stream>>>(xl, att2, sx, seb, 256);
  k_gnn_agg<<<1, 512, 0, stream>>>(xl, sx, seb, ew2, eb, ho, 256);
  k_gn_se<<<1, 512, 0, stream>>>(ho, se2w1, se2w2, x2, 256, 16);

  // 7. observers -> tail of d_out
  k_obs<<<1, 128, 0, stream>>>(tn, x2, out + 16777216);

  // 8. decoder: vr2 = v2 + vg ; t1 = v1 + relu(convT1(vr2)+b) ; out = (vf+vp) + relu(convT2(t1)+b)
  k_addvg<<<16384, 256, 0, stream>>>(bufC, x2);
  k_deconv<256, false><<<2048, 256, 0, stream>>>(bufC, tc1w, tc1b, bufB, nullptr, bufD, 16, 128, 32, 32);
  k_deconv<128, true ><<<4096, 256, 0, stream>>>(bufD, tc2w, tc2b, vf, vp, out, 16, 64, 64, 64);
}

// Round 2
// 1355.665 us; speedup vs baseline: 2.7587x; 2.7587x over previous
//
#include <hip/hip_runtime.h>
#include <hip/hip_bf16.h>
#include <cstddef>
#include <cstdint>

#define DEV_INLINE __device__ __forceinline__

typedef __attribute__((ext_vector_type(8))) short short8;
typedef __attribute__((ext_vector_type(4))) float f32x4;
typedef __attribute__((ext_vector_type(4))) unsigned short us4;

DEV_INLINE unsigned short f2bf(float f) {
  uint32_t u = __builtin_bit_cast(uint32_t, f);
  uint32_t r = (u + 0x7fffu + ((u >> 16) & 1u)) >> 16;
  return (unsigned short)r;
}

// Problem constants: BS=2, F=8, C=64, H=128, W=128, HEADS=4
// col_start prefix sums for the 14 hyperedge segments
__device__ __constant__ int c_cs[15] = {0,8,16,32,48,65,66,67,75,83,99,115,132,133,134};

// ---------------- text pool ----------------
__global__ void k_text_pool(const float* __restrict__ tf, const float* __restrict__ tp,
                            float* __restrict__ tn) {
  int t = blockIdx.x * blockDim.x + threadIdx.x;
  if (t >= 512) return;
  int b = t >> 8, idx = t & 255;
  int ch = idx >> 2, j = idx & 3;
  const float* p = tf + ((size_t)b * 64 + ch) * 16 + j * 4;
  const float* q = tp + ((size_t)b * 64 + ch) * 16 + j * 4;
  float m = p[0] + q[0];
  m = fmaxf(m, p[1] + q[1]);
  m = fmaxf(m, p[2] + q[2]);
  m = fmaxf(m, p[3] + q[3]);
  tn[(size_t)b * 256 + idx] = m;
}

// ---------------- input prep: (a+b) NCHW fp32 [16][64][128][128] -> NHWC bf16 ----------------
__global__ __launch_bounds__(256) void k_prep(const float* __restrict__ a,
                                              const float* __restrict__ b,
                                              unsigned short* __restrict__ o) {
  int bid = blockIdx.x;
  int xb = bid & 1, y = (bid >> 1) & 127, n = bid >> 8;
  __shared__ unsigned short s[64][68];
  int t = threadIdx.x;
  const size_t base = ((size_t)n * 64) * 16384 + (size_t)y * 128 + xb * 64;
#pragma unroll
  for (int r = 0; r < 16; ++r) {
    int t2 = t + r * 256; int ci = t2 >> 6, x = t2 & 63;
    size_t off = base + (size_t)ci * 16384 + x;
    s[ci][x] = f2bf(a[off] + b[off]);
  }
  __syncthreads();
  unsigned int* op = (unsigned int*)(o + (((size_t)n * 128 + y) * 128 + xb * 64) * 64);
#pragma unroll
  for (int r = 0; r < 8; ++r) {
    int t2 = t + r * 256; int x = t2 >> 5, c2 = (t2 & 31) * 2;
    unsigned int lo = s[c2][x], hi = s[c2 + 1][x];
    op[x * 32 + (c2 >> 1)] = lo | (hi << 16);
  }
}

// ---------------- weight transform: w[co][ci][3][3] fp32 -> wT[tap][co][ci] bf16 ----------------
__global__ void k_wtrans(const float* __restrict__ w, unsigned short* __restrict__ o,
                         int CO, int CI) {
  int idx = blockIdx.x * 256 + threadIdx.x;
  if (idx >= 9 * CO * CI) return;
  int ci = idx % CI; int r = idx / CI; int co = r % CO; int tap = r / CO;
  o[idx] = f2bf(w[((size_t)co * CI + ci) * 9 + tap]);
}

// ---------------- Conv2d k3 s2 p1 + bias + ReLU via bf16 MFMA implicit GEMM ----------------
// Block: 64 co x 64 pixels; 4 waves (2x2); wave = 2x2 fragments of 16x16x32.
// Input NHWC bf16; taps looped as 9 shifted GEMMs over K=ci.
template<int CI, int CO, int HO, int WO, int ROUT, bool WNHWC, bool WNCHW>
__global__ __launch_bounds__(256) void k_conv_mfma(
    const unsigned short* __restrict__ in,   // NHWC bf16 [N][2HO][2WO][CI]
    const unsigned short* __restrict__ wT,   // [9][CO][CI] bf16
    const float* __restrict__ bias,
    unsigned short* __restrict__ outn,       // NHWC bf16 [N][HO][WO][CO]
    float* __restrict__ outc) {              // NCHW fp32 [N][CO][HO][WO]
  constexpr int HIN = HO * 2, WIN = WO * 2;
  constexpr int XHP = WO + 2;          // padded xh count (x_idx = x+1 = 2*xh+p)
  constexpr int R = 2 * ROUT + 1;      // staged input rows
  constexpr int NCH = R * 2 * XHP * 4; // 16B chunks in LDS
  constexpr int CB = CO / 64;
  constexpr int OB = HO / ROUT;
  __shared__ short8 sIn[NCH];
  int bid = blockIdx.x;
  int cb = bid % CB; bid /= CB;
  int oyb = bid % OB; int n = bid / OB;
  int tid = threadIdx.x;
  int wid = tid >> 6, lane = tid & 63;
  int wm = wid >> 1, wn = wid & 1;
  int llo = lane & 15, lhi = lane >> 4;
  f32x4 acc[2][2] = {};
  const int iy0 = oyb * (2 * ROUT) - 1;
  for (int cs = 0; cs < CI / 32; ++cs) {
    // stage R rows x WIN x 32ci into parity-split LDS (linear chunk = thread idx)
    for (int i = tid; i < NCH; i += 256) {
      int c = i & 3, q = i >> 2;
      int xh = q % XHP; int q2 = q / XHP;
      int p = q2 & 1, l = q2 >> 1;
      int x = 2 * xh + p - 1;
      int iy = iy0 + l;
      short8 v = {};
      if (x >= 0 && x < WIN && iy >= 0 && iy < HIN)
        v = *reinterpret_cast<const short8*>(in + ((((size_t)n * HIN + iy) * WIN + x) * CI + cs * 32 + c * 8));
      sIn[i] = v;
    }
    __syncthreads();
#pragma unroll
    for (int tap = 0; tap < 9; ++tap) {
      const int ky = tap / 3, kx = tap % 3;
      short8 afr[2], bfr[2];
#pragma unroll
      for (int m = 0; m < 2; ++m) {
        int co = cb * 64 + wm * 32 + m * 16 + llo;
        afr[m] = *reinterpret_cast<const short8*>(wT + (((size_t)tap * CO + co) * CI + cs * 32 + lhi * 8));
      }
#pragma unroll
      for (int n2 = 0; n2 < 2; ++n2) {
        int pix = wn * 32 + n2 * 16 + llo;
        int oyl = (ROUT == 2) ? (pix >> 5) : 0;
        int ox = pix - oyl * WO;
        int lrow = 2 * oyl + ky;
        int chunk = ((lrow * 2 + (kx & 1)) * XHP + ox + (kx >> 1)) * 4 + lhi;
        bfr[n2] = sIn[chunk];
      }
#pragma unroll
      for (int m = 0; m < 2; ++m)
#pragma unroll
        for (int n2 = 0; n2 < 2; ++n2)
          acc[m][n2] = __builtin_amdgcn_mfma_f32_16x16x32_bf16(afr[m], bfr[n2], acc[m][n2], 0, 0, 0);
    }
    __syncthreads();
  }
  // epilogue: D col = lane&15 (pix), row = (lane>>4)*4 + r (co)
#pragma unroll
  for (int m = 0; m < 2; ++m) {
    int co0 = cb * 64 + wm * 32 + m * 16 + lhi * 4;
    float4 bv = *reinterpret_cast<const float4*>(bias + co0);
#pragma unroll
    for (int n2 = 0; n2 < 2; ++n2) {
      int pix = wn * 32 + n2 * 16 + llo;
      int oyl = (ROUT == 2) ? (pix >> 5) : 0;
      int ox = pix - oyl * WO;
      int oy = oyb * ROUT + oyl;
      float v0 = fmaxf(acc[m][n2][0] + bv.x, 0.f);
      float v1 = fmaxf(acc[m][n2][1] + bv.y, 0.f);
      float v2 = fmaxf(acc[m][n2][2] + bv.z, 0.f);
      float v3 = fmaxf(acc[m][n2][3] + bv.w, 0.f);
      if constexpr (WNHWC) {
        us4 pk = {f2bf(v0), f2bf(v1), f2bf(v2), f2bf(v3)};
        *reinterpret_cast<us4*>(outn + ((((size_t)n * HO + oy) * WO + ox) * CO + co0)) = pk;
      }
      if constexpr (WNCHW) {
        size_t ob = (((size_t)(n * CO + co0) * HO + oy)) * WO + ox;
        const size_t pl = (size_t)HO * WO;
        outc[ob] = v0; outc[ob + pl] = v1; outc[ob + 2 * pl] = v2; outc[ob + 3 * pl] = v3;
      }
    }
  }
}

// ---------------- spatial max over HW + LayerNorm over 256 channels ----------------
__global__ __launch_bounds__(256) void k_maxln(const float* __restrict__ x,
                                               float* __restrict__ out, int HW) {
  int n = blockIdx.x, ch = threadIdx.x;
  const float4* p4 = reinterpret_cast<const float4*>(x + ((size_t)n * 256 + ch) * HW);
  float m = -1e30f;
  for (int i = 0; i < (HW >> 2); ++i) {
    float4 v = p4[i];
    m = fmaxf(m, fmaxf(fmaxf(v.x, v.y), fmaxf(v.z, v.w)));
  }
  __shared__ float r1[256], r2[256];
  r1[ch] = m; __syncthreads();
  for (int s = 128; s > 0; s >>= 1) { if (ch < s) r1[ch] += r1[ch + s]; __syncthreads(); }
  float mu = r1[0] * (1.f / 256.f);
  float d = m - mu;
  r2[ch] = d * d; __syncthreads();
  for (int s = 128; s > 0; s >>= 1) { if (ch < s) r2[ch] += r2[ch + s]; __syncthreads(); }
  float var = r2[0] * (1.f / 256.f);
  out[(size_t)n * 256 + ch] = d * rsqrtf(var + 1e-5f);
}

// ---------------- build node features ----------------
__global__ void k_build_x(const float* __restrict__ vn, const float* __restrict__ dn,
                          const float* __restrict__ tn, float* __restrict__ x0) {
  int b = blockIdx.x, ch = threadIdx.x;
  float s = 0.f;
  for (int f = 0; f < 8; ++f) {
    float vv = vn[((size_t)b * 8 + f) * 256 + ch];
    float dd = dn[((size_t)b * 8 + f) * 256 + ch];
    s += vv + dd;
    x0[((size_t)b * 18 + f) * 256 + ch] = vv;
    x0[((size_t)b * 18 + 8 + f) * 256 + ch] = dd;
  }
  float tv = tn[(size_t)b * 256 + ch];
  x0[((size_t)b * 18 + 16) * 256 + ch] = tv;
  x0[((size_t)b * 18 + 17) * 256 + ch] = tv + s * (1.f / 8.f);
}

// ---------------- GNN linear ----------------
__global__ __launch_bounds__(256) void k_gnn_lin(
    const float* __restrict__ x, const float* __restrict__ ea,
    const float* __restrict__ w, float* __restrict__ y, int K, int M) {
  int chunks = M >> 8;
  int r = blockIdx.x / chunks;
  int ob = (blockIdx.x % chunks) * 256 + threadIdx.x;
  const float* src = (r < 36) ? (x + (size_t)r * K) : (ea + (size_t)(r - 36) * K);
  __shared__ __align__(16) float sxr[512];
  for (int k = threadIdx.x; k < K; k += 256) sxr[k] = src[k];
  __syncthreads();
  const float4* w4 = reinterpret_cast<const float4*>(w + (size_t)ob * K);
  const float4* x4 = reinterpret_cast<const float4*>(sxr);
  float acc = 0.f;
  int k4 = K >> 2;
  for (int k = 0; k < k4; ++k) {
    float4 a = x4[k], b = w4[k];
    acc += a.x * b.x + a.y * b.y + a.z * b.z + a.w * b.w;
  }
  y[(size_t)r * M + ob] = acc;
}

// ---------------- attention dot products ----------------
__global__ void k_gnn_att(const float* __restrict__ y, const float* __restrict__ att,
                          float* __restrict__ sx, float* __restrict__ seb, int OC) {
  int t = threadIdx.x;
  if (t >= 200) return;
  int r = t >> 2, h = t & 3;
  const float* row = y + ((size_t)r * 4 + h) * OC;
  const float* ar = att + (size_t)h * 2 * OC + (r < 36 ? 0 : OC);
  float s = 0.f;
  for (int k = 0; k < OC; ++k) s += row[k] * ar[k];
  if (r < 36) sx[r * 4 + h] = s; else seb[(r - 36) * 4 + h] = s;
}

DEV_INLINE int row_of_entry(int c, int j) {
  int b = c / 7, lc = c % 7;
  int r;
  if (lc == 0) r = j;
  else if (lc == 1) r = 8 + j;
  else if (lc <= 4) r = j;
  else if (lc == 5) r = 16;
  else r = 17;
  return 18 * b + r;
}

// ---------------- hypergraph attention softmax + aggregation ----------------
__global__ __launch_bounds__(512) void k_gnn_agg(
    const float* __restrict__ y, const float* __restrict__ sx,
    const float* __restrict__ seb, const float* __restrict__ ew,
    float* __restrict__ eb, float* __restrict__ ho, int OC) {
  int t = threadIdx.x;
  __shared__ float a_s[536];
  for (int idx = t; idx < 536; idx += 512) {
    int i = idx >> 2, h = idx & 3;
    int b = i / 67, rr = i % 67;
    int lc, rowl;
    if (rr < 8)       { lc = 0; rowl = rr; }
    else if (rr < 16) { lc = 1; rowl = rr; }
    else if (rr < 32) { lc = 2; rowl = rr - 16; }
    else if (rr < 48) { lc = 3; rowl = rr - 32; }
    else if (rr < 65) { lc = 4; rowl = rr - 48; }
    else if (rr == 65){ lc = 5; rowl = 16; }
    else              { lc = 6; rowl = 17; }
    int row = 18 * b + rowl;
    int col = 7 * b + lc;
    float v = sx[row * 4 + h] + seb[col * 4 + h];
    a_s[idx] = (v > 0.f) ? v : 0.2f * v;
  }
  __syncthreads();
  if (t < 56) {
    int c = t >> 2, h = t & 3;
    int st = c_cs[c], en = c_cs[c + 1];
    float m = -1e30f;
    for (int i = st; i < en; ++i) m = fmaxf(m, a_s[i * 4 + h]);
    float s = 0.f;
    for (int i = st; i < en; ++i) { float e = __expf(a_s[i * 4 + h] - m); a_s[i * 4 + h] = e; s += e; }
    float inv = 1.f / (s + 1e-16f);
    for (int i = st; i < en; ++i) a_s[i * 4 + h] *= inv;
  }
  __syncthreads();
  int M = 4 * OC;
  for (int idx = t; idx < 14 * 4 * OC; idx += 512) {
    int ch = idx % OC;
    int h  = (idx / OC) & 3;
    int c  = idx / (4 * OC);
    int st = c_cs[c], en = c_cs[c + 1];
    float Binv = 1.f / (float)(en - st);
    float s = 0.f;
    for (int i = st; i < en; ++i) {
      int row = row_of_entry(c, i - st);
      s += a_s[i * 4 + h] * y[(size_t)row * M + h * OC + ch];
    }
    eb[idx] = s * Binv;
  }
  __threadfence_block();
  __syncthreads();
  for (int idx = t; idx < 36 * OC; idx += 512) {
    int ch = idx % OC;
    int node = idx / OC;
    int b = node / 18, ln = node % 18;
    int ncols, cols[4], gis[4];
    if (ln < 16) {
      ncols = 4;
      cols[0] = b * 7 + (ln < 8 ? 0 : 1); gis[0] = b * 67 + ln;
      cols[1] = b * 7 + 2; gis[1] = b * 67 + 16 + ln;
      cols[2] = b * 7 + 3; gis[2] = b * 67 + 32 + ln;
      cols[3] = b * 7 + 4; gis[3] = b * 67 + 48 + ln;
    } else if (ln == 16) {
      ncols = 2;
      cols[0] = b * 7 + 4; gis[0] = b * 67 + 64;
      cols[1] = b * 7 + 5; gis[1] = b * 67 + 65;
      cols[2] = cols[3] = 0; gis[2] = gis[3] = 0;
    } else {
      ncols = 1;
      cols[0] = b * 7 + 6; gis[0] = b * 67 + 66;
      cols[1] = cols[2] = cols[3] = 0; gis[1] = gis[2] = gis[3] = 0;
    }
    float dsum = 0.f;
#pragma unroll
    for (int k = 0; k < 4; ++k) if (k < ncols) dsum += ew[cols[k]];
    float D = dsum > 0.f ? 1.f / dsum : 0.f;
    float s = 0.f;
#pragma unroll
    for (int k = 0; k < 4; ++k) {
      if (k < ncols) {
#pragma unroll
        for (int h = 0; h < 4; ++h)
          s += a_s[gis[k] * 4 + h] * eb[((size_t)cols[k] * 4 + h) * OC + ch];
      }
    }
    ho[idx] = fmaxf(0.25f * D * s, 0.f);
  }
}

// ---------------- GroupNorm(32) + SE layer ----------------
__global__ __launch_bounds__(512) void k_gn_se(
    const float* __restrict__ hin, const float* __restrict__ w1,
    const float* __restrict__ w2, float* __restrict__ x, int C, int Cr) {
  int t = threadIdx.x;
  int gs = C >> 5;
  for (int idx = t; idx < 36 * 32; idx += 512) {
    int node = idx >> 5, g = idx & 31;
    const float* p = hin + (size_t)node * C + g * gs;
    float s = 0.f, s2 = 0.f;
    for (int k = 0; k < gs; ++k) { float v = p[k]; s += v; s2 += v * v; }
    float mu = s / gs;
    float var = s2 / gs - mu * mu;
    float inv = rsqrtf(fmaxf(var, 0.f) + 1e-5f);
    float* q = x + (size_t)node * C + g * gs;
    for (int k = 0; k < gs; ++k) q[k] = (p[k] - mu) * inv;
  }
  __threadfence_block();
  __syncthreads();
  __shared__ float smean[512];
  __shared__ float shid[32];
  __shared__ float sscale[512];
  if (t < C) {
    float s = 0.f;
    for (int nn = 0; nn < 36; ++nn) s += x[(size_t)nn * C + t];
    smean[t] = s * (1.f / 36.f);
  }
  __syncthreads();
  if (t < Cr) {
    float s = 0.f;
    for (int ch = 0; ch < C; ++ch) s += w1[(size_t)t * C + ch] * smean[ch];
    shid[t] = fmaxf(s, 0.f);
  }
  __syncthreads();
  if (t < C) {
    float s = 0.f;
    for (int k = 0; k < Cr; ++k) s += w2[(size_t)t * Cr + k] * shid[k];
    sscale[t] = 1.f / (1.f + __expf(-s));
  }
  __syncthreads();
  for (int idx = t; idx < 36 * C; idx += 512) x[idx] *= sscale[idx % C];
}

// ---------------- observers ----------------
__global__ void k_obs(const float* __restrict__ tn, const float* __restrict__ x2,
                      float* __restrict__ out) {
  int t = threadIdx.x;
  if (t >= 128) return;
  int b = t >> 6, ch = t & 63;
  const float* a = tn + (size_t)b * 256 + ch * 4;
  const float* c = x2 + ((size_t)b * 18 + 17) * 256 + ch * 4;
  float m = a[0] + c[0];
  m = fmaxf(m, a[1] + c[1]);
  m = fmaxf(m, a[2] + c[2]);
  m = fmaxf(m, a[3] + c[3]);
  out[b * 64 + ch] = m;
}

// ---------------- vr2 = v2 + vg broadcast ----------------
__global__ void k_addvg(float* __restrict__ v2, const float* __restrict__ x2) {
  int idx = blockIdx.x * 256 + threadIdx.x;
  if (idx >= 16 * 256 * 1024) return;
  int n = idx >> 18;
  int co = (idx >> 10) & 255;
  int b = n >> 3, fi = n & 7;
  v2[idx] += x2[((size_t)(b * 18 + fi)) * 256 + co];
}

// ---------------- ConvTranspose2d k3 s2 p1 op1 + bias + ReLU + residual (fp32) ----------------
template<int CI, bool RES2>
__global__ __launch_bounds__(256) void k_deconv(
    const float* __restrict__ in, const float* __restrict__ w,
    const float* __restrict__ bias,
    const float* __restrict__ res, const float* __restrict__ resB,
    float* __restrict__ out, int N, int CO, int Hi, int Wi) {
  const int Ho = Hi * 2, Wo = Wi * 2;
  const int qtx = Wi >> 4, qty = Hi >> 4;
  int bid = blockIdx.x;
  int tqx = bid % qtx; bid /= qtx;
  int tqy = bid % qty; bid /= qty;
  int cb = bid % (CO >> 2); bid /= (CO >> 2);
  int n = bid;
  int co0 = cb << 2;
  int lx = threadIdx.x & 15, ly = threadIdx.x >> 4;
  int qx = (tqx << 4) + lx, qy = (tqy << 4) + ly;
  bool okx = (qx + 1) < Wi, oky = (qy + 1) < Hi;
  float acc[4][4];
#pragma unroll
  for (int c = 0; c < 4; ++c)
#pragma unroll
    for (int k = 0; k < 4; ++k) acc[c][k] = 0.f;
  for (int ci = 0; ci < CI; ++ci) {
    const float* ib = in + ((size_t)(n * CI + ci) * Hi + qy) * Wi + qx;
    float i00 = ib[0];
    float i01 = okx ? ib[1] : 0.f;
    float i10 = oky ? ib[Wi] : 0.f;
    float i11 = (okx && oky) ? ib[Wi + 1] : 0.f;
#pragma unroll
    for (int c = 0; c < 4; ++c) {
      const float* ww = w + ((size_t)ci * CO + co0 + c) * 9;
      float w00 = ww[0], w01 = ww[1], w02 = ww[2];
      float w10 = ww[3], w11 = ww[4], w12 = ww[5];
      float w20 = ww[6], w21 = ww[7], w22 = ww[8];
      acc[c][0] += i00 * w11;
      acc[c][1] += i00 * w12 + i01 * w10;
      acc[c][2] += i00 * w21 + i10 * w01;
      acc[c][3] += i00 * w22 + i01 * w20 + i10 * w02 + i11 * w00;
    }
  }
#pragma unroll
  for (int c = 0; c < 4; ++c) {
    float bv = bias[co0 + c];
#pragma unroll
    for (int dy = 0; dy < 2; ++dy)
#pragma unroll
      for (int dx = 0; dx < 2; ++dx) {
        int oy = 2 * qy + dy, ox = 2 * qx + dx;
        size_t o = ((size_t)(n * CO + co0 + c) * Ho + oy) * Wo + ox;
        float v = fmaxf(acc[c][dy * 2 + dx] + bv, 0.f);
        v += RES2 ? (res[o] + resB[o]) : res[o];
        out[o] = v;
      }
  }
}

extern "C" void kernel_launch(void* const* d_in, const int* in_sizes, int n_in,
                              void* d_out, int out_size, void* d_ws, size_t ws_size,
                              hipStream_t stream) {
  (void)in_sizes; (void)n_in; (void)out_size; (void)ws_size;
  const float* vf    = (const float*)d_in[0];
  const float* vp    = (const float*)d_in[1];
  const float* mf    = (const float*)d_in[2];
  const float* mp    = (const float*)d_in[3];
  const float* tf    = (const float*)d_in[4];
  const float* tp    = (const float*)d_in[5];
  const float* cv1w  = (const float*)d_in[6];
  const float* cv1b  = (const float*)d_in[7];
  const float* cv2w  = (const float*)d_in[8];
  const float* cv2b  = (const float*)d_in[9];
  const float* dc1w  = (const float*)d_in[10];
  const float* dc1b  = (const float*)d_in[11];
  const float* dc2w  = (const float*)d_in[12];
  const float* dc2b  = (const float*)d_in[13];
  const float* tc1w  = (const float*)d_in[14];
  const float* tc1b  = (const float*)d_in[15];
  const float* tc2w  = (const float*)d_in[16];
  const float* tc2b  = (const float*)d_in[17];
  const float* lin1w = (const float*)d_in[18];
  const float* att1  = (const float*)d_in[19];
  const float* lin2w = (const float*)d_in[20];
  const float* att2  = (const float*)d_in[21];
  const float* ew1   = (const float*)d_in[22];
  const float* ew2   = (const float*)d_in[23];
  const float* ea1   = (const float*)d_in[24];
  const float* ea2   = (const float*)d_in[25];
  const float* se1w1 = (const float*)d_in[26];
  const float* se1w2 = (const float*)d_in[27];
  const float* se2w1 = (const float*)d_in[28];
  const float* se2w2 = (const float*)d_in[29];

  float* ws  = (float*)d_ws;
  float* out = (float*)d_out;

  // workspace layout (floats); total ~25.7M floats = ~103 MB
  float* bufA = ws;                 // 8,388,608 f : P region (v0n/d0n NHWC bf16), later t1 NCHW fp32
  float* bufB = ws + 8388608;       // 8,388,608 f : v1 NCHW fp32 (deconv residual)
  float* bufC = ws + 16777216;      // 4,194,304 f : d2/v2 NCHW fp32
  float* bufQ = ws + 20971520;      // 4,194,304 f : d1n/v1n NHWC bf16
  unsigned short* wtb = (unsigned short*)(ws + 25165824);  // 737,280 bf16
  float* sm   = ws + 25534464;      // small buffers
  float* tn   = sm;                 // 512
  float* vn   = sm + 512;           // 4096
  float* dn   = sm + 4608;          // 4096
  float* x0   = sm + 8704;          // 9216
  float* xl   = sm + 17920;         // 102400
  float* sx   = sm + 120320;        // 144
  float* seb  = sm + 120464;        // 56
  float* eb   = sm + 120520;        // 28672
  float* ho   = sm + 149192;        // 18432
  float* x1   = sm + 167624;        // 18432
  float* x2   = sm + 186056;        // 9216

  unsigned short* p0n = (unsigned short*)bufA;  // NHWC bf16 input (16,128,128,64)
  unsigned short* q1n = (unsigned short*)bufQ;  // NHWC bf16 conv1 out (16,64,64,128)
  unsigned short* wTc1 = wtb;                   // 9*128*64
  unsigned short* wTd1 = wtb + 73728;
  unsigned short* wTc2 = wtb + 147456;          // 9*256*128
  unsigned short* wTd2 = wtb + 442368;

  // 0. weight transforms
  k_wtrans<<<288, 256, 0, stream>>>(cv1w, wTc1, 128, 64);
  k_wtrans<<<288, 256, 0, stream>>>(dc1w, wTd1, 128, 64);
  k_wtrans<<<1152, 256, 0, stream>>>(cv2w, wTc2, 256, 128);
  k_wtrans<<<1152, 256, 0, stream>>>(dc2w, wTd2, 256, 128);

  // 1. text pooling
  k_text_pool<<<2, 256, 0, stream>>>(tf, tp, tn);

  // 2. motion branch
  k_prep<<<4096, 256, 0, stream>>>(mf, mp, p0n);
  k_conv_mfma<64, 128, 64, 64, 1, true, false><<<2048, 256, 0, stream>>>(p0n, wTd1, dc1b, q1n, nullptr);
  k_conv_mfma<128, 256, 32, 32, 2, false, true><<<1024, 256, 0, stream>>>(q1n, wTd2, dc2b, nullptr, bufC);
  k_maxln<<<16, 256, 0, stream>>>(bufC, dn, 1024);

  // 3. vision branch (conv1 writes NHWC for conv2 + NCHW fp32 residual)
  k_prep<<<4096, 256, 0, stream>>>(vf, vp, p0n);
  k_conv_mfma<64, 128, 64, 64, 1, true, true><<<2048, 256, 0, stream>>>(p0n, wTc1, cv1b, q1n, bufB);
  k_conv_mfma<128, 256, 32, 32, 2, false, true><<<1024, 256, 0, stream>>>(q1n, wTc2, cv2b, nullptr, bufC);
  k_maxln<<<16, 256, 0, stream>>>(bufC, vn, 1024);

  // 4. node features
  k_build_x<<<2, 256, 0, stream>>>(vn, dn, tn, x0);

  // 5. GNN layer 1
  k_gnn_lin<<<50 * 8, 256, 0, stream>>>(x0, ea1, lin1w, xl, 256, 2048);
  k_gnn_att<<<1, 256, 0, stream>>>(xl, att1, sx, seb, 512);
  k_gnn_agg<<<1, 512, 0, stream>>>(xl, sx, seb, ew1, eb, ho, 512);
  k_gn_se<<<1, 512, 0, stream>>>(ho, se1w1, se1w2, x1, 512, 32);

  // 6. GNN layer 2
  k_gnn_lin<<<50 * 4, 256, 0, stream>>>(x1, ea2, lin2w, xl, 512, 1024);
  k_gnn_att<<<1, 256, 0, stream>>>(xl, att2, sx, seb, 256);
  k_gnn_agg<<<1, 512, 0, stream>>>(xl, sx, seb, ew2, eb, ho, 256);
  k_gn_se<<<1, 512, 0, stream>>>(ho, se2w1, se2w2, x2, 256, 16);

  // 7. observers
  k_obs<<<1, 128, 0, stream>>>(tn, x2, out + 16777216);

  // 8. decoder (fp32): vr2 = v2+vg ; t1 = v1 + relu(convT1(vr2)) ; out = (vf+vp) + relu(convT2(t1))
  k_addvg<<<16384, 256, 0, stream>>>(bufC, x2);
  k_deconv<256, false><<<2048, 256, 0, stream>>>(bufC, tc1w, tc1b, bufB, nullptr, bufA, 16, 128, 32, 32);
  k_deconv<128, true ><<<4096, 256, 0, stream>>>(bufA, tc2w, tc2b, vf, vp, out, 16, 64, 64, 64);
}

// Round 3
// 994.156 us; speedup vs baseline: 3.7619x; 1.3636x over previous
//
#include <hip/hip_runtime.h>
#include <hip/hip_bf16.h>
#include <cstddef>
#include <cstdint>

#define DEV_INLINE __device__ __forceinline__

typedef __attribute__((ext_vector_type(8))) short short8;
typedef __attribute__((ext_vector_type(4))) float f32x4;
typedef __attribute__((ext_vector_type(4))) unsigned short us4;

DEV_INLINE unsigned short f2bf(float f) {
  uint32_t u = __builtin_bit_cast(uint32_t, f);
  uint32_t r = (u + 0x7fffu + ((u >> 16) & 1u)) >> 16;
  return (unsigned short)r;
}
DEV_INLINE float bf2f(unsigned short u) {
  return __builtin_bit_cast(float, (uint32_t)u << 16);
}

// Problem constants: BS=2, F=8, C=64, H=128, W=128, HEADS=4
__device__ __constant__ int c_cs[15] = {0,8,16,32,48,65,66,67,75,83,99,115,132,133,134};

// ---------------- text pool ----------------
__global__ void k_text_pool(const float* __restrict__ tf, const float* __restrict__ tp,
                            float* __restrict__ tn) {
  int t = blockIdx.x * blockDim.x + threadIdx.x;
  if (t >= 512) return;
  int b = t >> 8, idx = t & 255;
  int ch = idx >> 2, j = idx & 3;
  const float* p = tf + ((size_t)b * 64 + ch) * 16 + j * 4;
  const float* q = tp + ((size_t)b * 64 + ch) * 16 + j * 4;
  float m = p[0] + q[0];
  m = fmaxf(m, p[1] + q[1]);
  m = fmaxf(m, p[2] + q[2]);
  m = fmaxf(m, p[3] + q[3]);
  tn[(size_t)b * 256 + idx] = m;
}

// ---------------- input prep: (a+b) NCHW fp32 -> NHWC bf16 ----------------
__global__ __launch_bounds__(256) void k_prep(const float* __restrict__ a,
                                              const float* __restrict__ b,
                                              unsigned short* __restrict__ o) {
  int bid = blockIdx.x;
  int xb = bid & 1, y = (bid >> 1) & 127, n = bid >> 8;
  __shared__ unsigned short s[64][68];
  int t = threadIdx.x;
  const size_t base = ((size_t)n * 64) * 16384 + (size_t)y * 128 + xb * 64;
#pragma unroll
  for (int r = 0; r < 16; ++r) {
    int t2 = t + r * 256; int ci = t2 >> 6, x = t2 & 63;
    size_t off = base + (size_t)ci * 16384 + x;
    s[ci][x] = f2bf(a[off] + b[off]);
  }
  __syncthreads();
  unsigned int* op = (unsigned int*)(o + (((size_t)n * 128 + y) * 128 + xb * 64) * 64);
#pragma unroll
  for (int r = 0; r < 8; ++r) {
    int t2 = t + r * 256; int x = t2 >> 5, c2 = (t2 & 31) * 2;
    unsigned int lo = s[c2][x], hi = s[c2 + 1][x];
    op[x * 32 + (c2 >> 1)] = lo | (hi << 16);
  }
}

// ---------------- weight transforms -> wT[tap][co][ci] bf16 ----------------
__global__ void k_wtrans(const float* __restrict__ w, unsigned short* __restrict__ o,
                         int CO, int CI) {  // forward: w[co][ci][3][3]
  int idx = blockIdx.x * 256 + threadIdx.x;
  if (idx >= 9 * CO * CI) return;
  int ci = idx % CI; int r = idx / CI; int co = r % CO; int tap = r / CO;
  o[idx] = f2bf(w[((size_t)co * CI + ci) * 9 + tap]);
}
__global__ void k_wtrans_t(const float* __restrict__ w, unsigned short* __restrict__ o,
                           int CO, int CI) {  // transposed: w[ci][co][3][3]
  int idx = blockIdx.x * 256 + threadIdx.x;
  if (idx >= 9 * CO * CI) return;
  int ci = idx % CI; int r = idx / CI; int co = r % CO; int tap = r / CO;
  o[idx] = f2bf(w[((size_t)ci * CO + co) * 9 + tap]);
}

// ---------------- Conv2d k3 s2 p1 + bias + ReLU via bf16 MFMA ----------------
template<int CI, int CO, int HO, int WO, int ROUT>
__global__ __launch_bounds__(256) void k_conv_mfma(
    const unsigned short* __restrict__ in,   // NHWC bf16 [N][2HO][2WO][CI]
    const unsigned short* __restrict__ wT,   // [9][CO][CI] bf16
    const float* __restrict__ bias,
    unsigned short* __restrict__ outn) {     // NHWC bf16 [N][HO][WO][CO]
  constexpr int HIN = HO * 2, WIN = WO * 2;
  constexpr int XHP = WO + 2;
  constexpr int R = 2 * ROUT + 1;
  constexpr int NPOS = R * 2 * XHP;
  constexpr int CB = CO / 64;
  constexpr int OB = HO / ROUT;
  __shared__ short8 sIn[NPOS * 5];
  int bid = blockIdx.x;
  int cb = bid % CB; bid /= CB;
  int oyb = bid % OB; int n = bid / OB;
  int tid = threadIdx.x;
  int wid = tid >> 6, lane = tid & 63;
  int wm = wid >> 1, wn = wid & 1;
  int llo = lane & 15, lhi = lane >> 4;
  f32x4 acc[2][2] = {};
  const int iy0 = oyb * (2 * ROUT) - 1;
  for (int cs = 0; cs < CI / 32; ++cs) {
    for (int i = tid; i < NPOS * 4; i += 256) {
      int c = i & 3, q = i >> 2;
      int xh = q % XHP; int q2 = q / XHP;
      int p = q2 & 1, l = q2 >> 1;
      int x = 2 * xh + p - 1;
      int iy = iy0 + l;
      short8 v = {};
      if (x >= 0 && x < WIN && iy >= 0 && iy < HIN)
        v = *reinterpret_cast<const short8*>(in + ((((size_t)n * HIN + iy) * WIN + x) * CI + cs * 32 + c * 8));
      sIn[q * 5 + c] = v;
    }
    __syncthreads();
#pragma unroll
    for (int tap = 0; tap < 9; ++tap) {
      const int ky = tap / 3, kx = tap % 3;
      short8 afr[2], bfr[2];
#pragma unroll
      for (int m = 0; m < 2; ++m) {
        int co = cb * 64 + wm * 32 + m * 16 + llo;
        afr[m] = *reinterpret_cast<const short8*>(wT + (((size_t)tap * CO + co) * CI + cs * 32 + lhi * 8));
      }
#pragma unroll
      for (int n2 = 0; n2 < 2; ++n2) {
        int pix = wn * 32 + n2 * 16 + llo;
        int oyl = (ROUT == 2) ? (pix >> 5) : 0;
        int ox = pix - oyl * WO;
        int lrow = 2 * oyl + ky;
        int pos = (lrow * 2 + (kx & 1)) * XHP + ox + (kx >> 1);
        bfr[n2] = sIn[pos * 5 + lhi];
      }
#pragma unroll
      for (int m = 0; m < 2; ++m)
#pragma unroll
        for (int n2 = 0; n2 < 2; ++n2)
          acc[m][n2] = __builtin_amdgcn_mfma_f32_16x16x32_bf16(afr[m], bfr[n2], acc[m][n2], 0, 0, 0);
    }
    __syncthreads();
  }
#pragma unroll
  for (int m = 0; m < 2; ++m) {
    int co0 = cb * 64 + wm * 32 + m * 16 + lhi * 4;
    float4 bv = *reinterpret_cast<const float4*>(bias + co0);
#pragma unroll
    for (int n2 = 0; n2 < 2; ++n2) {
      int pix = wn * 32 + n2 * 16 + llo;
      int oyl = (ROUT == 2) ? (pix >> 5) : 0;
      int ox = pix - oyl * WO;
      int oy = oyb * ROUT + oyl;
      us4 pk;
      pk[0] = f2bf(fmaxf(acc[m][n2][0] + bv.x, 0.f));
      pk[1] = f2bf(fmaxf(acc[m][n2][1] + bv.y, 0.f));
      pk[2] = f2bf(fmaxf(acc[m][n2][2] + bv.z, 0.f));
      pk[3] = f2bf(fmaxf(acc[m][n2][3] + bv.w, 0.f));
      *reinterpret_cast<us4*>(outn + ((((size_t)n * HO + oy) * WO + ox) * CO + co0)) = pk;
    }
  }
}

// ---------------- ConvTranspose2d k3 s2 p1 op1 via bf16 MFMA (4 parity classes) ------
// tap (ky,kx) -> parity acc p (dy*2+dx), B-offset bsel (a*2+b): verified fp32 mapping.
template<int CI, int CO, int Hi, int Wi, int QR, bool OBF>
__global__ __launch_bounds__(256) void k_deconv_mfma(
    const unsigned short* __restrict__ in,   // NHWC bf16 [N][Hi][Wi][CI]
    const unsigned short* __restrict__ wT,   // [9][CO][CI] bf16 (w[ci][co][ky][kx])
    const float* __restrict__ bias,
    const unsigned short* __restrict__ resn, // NHWC bf16 residual (OBF)
    const float* __restrict__ resA, const float* __restrict__ resB, // fp32 NCHW residuals
    unsigned short* __restrict__ outn,       // NHWC bf16 [N][2Hi][2Wi][CO]
    float* __restrict__ outc) {              // NCHW fp32
  constexpr int QC = 64 / QR;
  constexpr int WP = Wi + 1;
  constexpr int NPOS = (QR + 1) * WP;
  constexpr int CB = CO / 64;
  constexpr int OB = Hi / QR;
  constexpr int Ho = Hi * 2, Wo = Wi * 2;
  __shared__ short8 sIn[NPOS * 5];
  int bid = blockIdx.x;
  int cb = bid % CB; bid /= CB;
  int oyb = bid % OB; int n = bid / OB;
  int tid = threadIdx.x;
  int wid = tid >> 6, lane = tid & 63;
  int wm = wid >> 1, wn = wid & 1;
  int llo = lane & 15, lhi = lane >> 4;
  int qy0 = oyb * QR;
  f32x4 acc[4][2][2] = {};
  constexpr int tap_p[9] = {3,2,3,1,0,1,3,2,3};
  constexpr int tap_b[9] = {3,2,2,1,0,0,1,0,0};
  for (int cs = 0; cs < CI / 32; ++cs) {
    for (int i = tid; i < NPOS * 4; i += 256) {
      int c = i & 3, q = i >> 2;
      int x = q % WP, l = q / WP;
      int iy = qy0 + l;
      short8 v = {};
      if (x < Wi && iy < Hi)
        v = *reinterpret_cast<const short8*>(in + (((size_t)(n * Hi + iy) * Wi + x) * CI + cs * 32 + c * 8));
      sIn[q * 5 + c] = v;
    }
    __syncthreads();
    short8 bfr[2][4];
#pragma unroll
    for (int n2 = 0; n2 < 2; ++n2) {
      int pix = wn * 32 + n2 * 16 + llo;
      int qyl = pix / QC, qx = pix % QC;
#pragma unroll
      for (int bs = 0; bs < 4; ++bs) {
        int pos = (qyl + (bs >> 1)) * WP + qx + (bs & 1);
        bfr[n2][bs] = sIn[pos * 5 + lhi];
      }
    }
#pragma unroll
    for (int tap = 0; tap < 9; ++tap) {
      short8 afr[2];
#pragma unroll
      for (int m = 0; m < 2; ++m) {
        int co = cb * 64 + wm * 32 + m * 16 + llo;
        afr[m] = *reinterpret_cast<const short8*>(wT + (((size_t)tap * CO + co) * CI + cs * 32 + lhi * 8));
      }
#pragma unroll
      for (int m = 0; m < 2; ++m)
#pragma unroll
        for (int n2 = 0; n2 < 2; ++n2)
          acc[tap_p[tap]][m][n2] = __builtin_amdgcn_mfma_f32_16x16x32_bf16(
              afr[m], bfr[n2][tap_b[tap]], acc[tap_p[tap]][m][n2], 0, 0, 0);
    }
    __syncthreads();
  }
#pragma unroll
  for (int m = 0; m < 2; ++m) {
    int co0 = cb * 64 + wm * 32 + m * 16 + lhi * 4;
    float4 bv = *reinterpret_cast<const float4*>(bias + co0);
#pragma unroll
    for (int n2 = 0; n2 < 2; ++n2) {
      int pix = wn * 32 + n2 * 16 + llo;
      int qyl = pix / QC, qx = pix % QC;
      int qy = qy0 + qyl;
#pragma unroll
      for (int p = 0; p < 4; ++p) {
        int oy = 2 * qy + (p >> 1);
        int ox = 2 * qx + (p & 1);
        float v0 = fmaxf(acc[p][m][n2][0] + bv.x, 0.f);
        float v1 = fmaxf(acc[p][m][n2][1] + bv.y, 0.f);
        float v2 = fmaxf(acc[p][m][n2][2] + bv.z, 0.f);
        float v3 = fmaxf(acc[p][m][n2][3] + bv.w, 0.f);
        if constexpr (OBF) {
          size_t ad = ((size_t)(n * Ho + oy) * Wo + ox) * CO + co0;
          us4 r = *reinterpret_cast<const us4*>(resn + ad);
          us4 pk;
          pk[0] = f2bf(bf2f(r[0]) + v0);
          pk[1] = f2bf(bf2f(r[1]) + v1);
          pk[2] = f2bf(bf2f(r[2]) + v2);
          pk[3] = f2bf(bf2f(r[3]) + v3);
          *reinterpret_cast<us4*>(outn + ad) = pk;
        } else {
          size_t ob = ((size_t)(n * CO + co0) * Ho + oy) * Wo + ox;
          const size_t pl = (size_t)Ho * Wo;
          outc[ob]          = resA[ob]          + resB[ob]          + v0;
          outc[ob + pl]     = resA[ob + pl]     + resB[ob + pl]     + v1;
          outc[ob + 2 * pl] = resA[ob + 2 * pl] + resB[ob + 2 * pl] + v2;
          outc[ob + 3 * pl] = resA[ob + 3 * pl] + resB[ob + 3 * pl] + v3;
        }
      }
    }
  }
}

// ---------------- spatial max (NHWC bf16) + LayerNorm over 256 channels ----------------
__global__ __launch_bounds__(1024) void k_maxln_n(const unsigned short* __restrict__ x,
                                                  float* __restrict__ out) {
  int n = blockIdx.x, t = threadIdx.x;
  int ch = t & 255, pg = t >> 8;
  const unsigned short* base = x + (size_t)n * 1024 * 256 + ch;
  float m = -1e30f;
  for (int p = pg; p < 1024; p += 4)
    m = fmaxf(m, bf2f(base[(size_t)p * 256]));
  __shared__ float sm4[4][256];
  __shared__ float r1[256], r2[256];
  sm4[pg][ch] = m;
  __syncthreads();
  float mv = fmaxf(fmaxf(sm4[0][ch], sm4[1][ch]), fmaxf(sm4[2][ch], sm4[3][ch]));
  if (pg == 0) r1[ch] = mv;
  __syncthreads();
  for (int s = 128; s > 0; s >>= 1) { if (t < s) r1[t] += r1[t + s]; __syncthreads(); }
  float mu = r1[0] * (1.f / 256.f);
  float d = mv - mu;
  if (pg == 0) r2[ch] = d * d;
  __syncthreads();
  for (int s = 128; s > 0; s >>= 1) { if (t < s) r2[t] += r2[t + s]; __syncthreads(); }
  if (pg == 0) out[(size_t)n * 256 + ch] = d * rsqrtf(r2[0] * (1.f / 256.f) + 1e-5f);
}

// ---------------- build node features ----------------
__global__ void k_build_x(const float* __restrict__ vn, const float* __restrict__ dn,
                          const float* __restrict__ tn, float* __restrict__ x0) {
  int b = blockIdx.x, ch = threadIdx.x;
  float s = 0.f;
  for (int f = 0; f < 8; ++f) {
    float vv = vn[((size_t)b * 8 + f) * 256 + ch];
    float dd = dn[((size_t)b * 8 + f) * 256 + ch];
    s += vv + dd;
    x0[((size_t)b * 18 + f) * 256 + ch] = vv;
    x0[((size_t)b * 18 + 8 + f) * 256 + ch] = dd;
  }
  float tv = tn[(size_t)b * 256 + ch];
  x0[((size_t)b * 18 + 16) * 256 + ch] = tv;
  x0[((size_t)b * 18 + 17) * 256 + ch] = tv + s * (1.f / 8.f);
}

// ---------------- GNN linear ----------------
__global__ __launch_bounds__(256) void k_gnn_lin(
    const float* __restrict__ x, const float* __restrict__ ea,
    const float* __restrict__ w, float* __restrict__ y, int K, int M) {
  int chunks = M >> 8;
  int r = blockIdx.x / chunks;
  int ob = (blockIdx.x % chunks) * 256 + threadIdx.x;
  const float* src = (r < 36) ? (x + (size_t)r * K) : (ea + (size_t)(r - 36) * K);
  __shared__ __align__(16) float sxr[512];
  for (int k = threadIdx.x; k < K; k += 256) sxr[k] = src[k];
  __syncthreads();
  const float4* w4 = reinterpret_cast<const float4*>(w + (size_t)ob * K);
  const float4* x4 = reinterpret_cast<const float4*>(sxr);
  float acc = 0.f;
  int k4 = K >> 2;
  for (int k = 0; k < k4; ++k) {
    float4 a = x4[k], b = w4[k];
    acc += a.x * b.x + a.y * b.y + a.z * b.z + a.w * b.w;
  }
  y[(size_t)r * M + ob] = acc;
}

// ---------------- attention dot products ----------------
__global__ void k_gnn_att(const float* __restrict__ y, const float* __restrict__ att,
                          float* __restrict__ sx, float* __restrict__ seb, int OC) {
  int t = threadIdx.x;
  if (t >= 200) return;
  int r = t >> 2, h = t & 3;
  const float* row = y + ((size_t)r * 4 + h) * OC;
  const float* ar = att + (size_t)h * 2 * OC + (r < 36 ? 0 : OC);
  float s = 0.f;
  for (int k = 0; k < OC; ++k) s += row[k] * ar[k];
  if (r < 36) sx[r * 4 + h] = s; else seb[(r - 36) * 4 + h] = s;
}

DEV_INLINE int row_of_entry(int c, int j) {
  int b = c / 7, lc = c % 7;
  int r;
  if (lc == 0) r = j;
  else if (lc == 1) r = 8 + j;
  else if (lc <= 4) r = j;
  else if (lc == 5) r = 16;
  else r = 17;
  return 18 * b + r;
}

// ---------------- hypergraph attention softmax + aggregation ----------------
__global__ __launch_bounds__(512) void k_gnn_agg(
    const float* __restrict__ y, const float* __restrict__ sx,
    const float* __restrict__ seb, const float* __restrict__ ew,
    float* __restrict__ eb, float* __restrict__ ho, int OC) {
  int t = threadIdx.x;
  __shared__ float a_s[536];
  for (int idx = t; idx < 536; idx += 512) {
    int i = idx >> 2, h = idx & 3;
    int b = i / 67, rr = i % 67;
    int lc, rowl;
    if (rr < 8)       { lc = 0; rowl = rr; }
    else if (rr < 16) { lc = 1; rowl = rr; }
    else if (rr < 32) { lc = 2; rowl = rr - 16; }
    else if (rr < 48) { lc = 3; rowl = rr - 32; }
    else if (rr < 65) { lc = 4; rowl = rr - 48; }
    else if (rr == 65){ lc = 5; rowl = 16; }
    else              { lc = 6; rowl = 17; }
    int row = 18 * b + rowl;
    int col = 7 * b + lc;
    float v = sx[row * 4 + h] + seb[col * 4 + h];
    a_s[idx] = (v > 0.f) ? v : 0.2f * v;
  }
  __syncthreads();
  if (t < 56) {
    int c = t >> 2, h = t & 3;
    int st = c_cs[c], en = c_cs[c + 1];
    float m = -1e30f;
    for (int i = st; i < en; ++i) m = fmaxf(m, a_s[i * 4 + h]);
    float s = 0.f;
    for (int i = st; i < en; ++i) { float e = __expf(a_s[i * 4 + h] - m); a_s[i * 4 + h] = e; s += e; }
    float inv = 1.f / (s + 1e-16f);
    for (int i = st; i < en; ++i) a_s[i * 4 + h] *= inv;
  }
  __syncthreads();
  int M = 4 * OC;
  for (int idx = t; idx < 14 * 4 * OC; idx += 512) {
    int ch = idx % OC;
    int h  = (idx / OC) & 3;
    int c  = idx / (4 * OC);
    int st = c_cs[c], en = c_cs[c + 1];
    float Binv = 1.f / (float)(en - st);
    float s = 0.f;
    for (int i = st; i < en; ++i) {
      int row = row_of_entry(c, i - st);
      s += a_s[i * 4 + h] * y[(size_t)row * M + h * OC + ch];
    }
    eb[idx] = s * Binv;
  }
  __threadfence_block();
  __syncthreads();
  for (int idx = t; idx < 36 * OC; idx += 512) {
    int ch = idx % OC;
    int node = idx / OC;
    int b = node / 18, ln = node % 18;
    int ncols, cols[4], gis[4];
    if (ln < 16) {
      ncols = 4;
      cols[0] = b * 7 + (ln < 8 ? 0 : 1); gis[0] = b * 67 + ln;
      cols[1] = b * 7 + 2; gis[1] = b * 67 + 16 + ln;
      cols[2] = b * 7 + 3; gis[2] = b * 67 + 32 + ln;
      cols[3] = b * 7 + 4; gis[3] = b * 67 + 48 + ln;
    } else if (ln == 16) {
      ncols = 2;
      cols[0] = b * 7 + 4; gis[0] = b * 67 + 64;
      cols[1] = b * 7 + 5; gis[1] = b * 67 + 65;
      cols[2] = cols[3] = 0; gis[2] = gis[3] = 0;
    } else {
      ncols = 1;
      cols[0] = b * 7 + 6; gis[0] = b * 67 + 66;
      cols[1] = cols[2] = cols[3] = 0; gis[1] = gis[2] = gis[3] = 0;
    }
    float dsum = 0.f;
#pragma unroll
    for (int k = 0; k < 4; ++k) if (k < ncols) dsum += ew[cols[k]];
    float D = dsum > 0.f ? 1.f / dsum : 0.f;
    float s = 0.f;
#pragma unroll
    for (int k = 0; k < 4; ++k) {
      if (k < ncols) {
#pragma unroll
        for (int h = 0; h < 4; ++h)
          s += a_s[gis[k] * 4 + h] * eb[((size_t)cols[k] * 4 + h) * OC + ch];
      }
    }
    ho[idx] = fmaxf(0.25f * D * s, 0.f);
  }
}

// ---------------- GroupNorm(32) + SE layer ----------------
__global__ __launch_bounds__(512) void k_gn_se(
    const float* __restrict__ hin, const float* __restrict__ w1,
    const float* __restrict__ w2, float* __restrict__ x, int C, int Cr) {
  int t = threadIdx.x;
  int gs = C >> 5;
  for (int idx = t; idx < 36 * 32; idx += 512) {
    int node = idx >> 5, g = idx & 31;
    const float* p = hin + (size_t)node * C + g * gs;
    float s = 0.f, s2 = 0.f;
    for (int k = 0; k < gs; ++k) { float v = p[k]; s += v; s2 += v * v; }
    float mu = s / gs;
    float var = s2 / gs - mu * mu;
    float inv = rsqrtf(fmaxf(var, 0.f) + 1e-5f);
    float* q = x + (size_t)node * C + g * gs;
    for (int k = 0; k < gs; ++k) q[k] = (p[k] - mu) * inv;
  }
  __threadfence_block();
  __syncthreads();
  __shared__ float smean[512];
  __shared__ float shid[32];
  __shared__ float sscale[512];
  if (t < C) {
    float s = 0.f;
    for (int nn = 0; nn < 36; ++nn) s += x[(size_t)nn * C + t];
    smean[t] = s * (1.f / 36.f);
  }
  __syncthreads();
  if (t < Cr) {
    float s = 0.f;
    for (int ch = 0; ch < C; ++ch) s += w1[(size_t)t * C + ch] * smean[ch];
    shid[t] = fmaxf(s, 0.f);
  }
  __syncthreads();
  if (t < C) {
    float s = 0.f;
    for (int k = 0; k < Cr; ++k) s += w2[(size_t)t * Cr + k] * shid[k];
    sscale[t] = 1.f / (1.f + __expf(-s));
  }
  __syncthreads();
  for (int idx = t; idx < 36 * C; idx += 512) x[idx] *= sscale[idx % C];
}

// ---------------- observers ----------------
__global__ void k_obs(const float* __restrict__ tn, const float* __restrict__ x2,
                      float* __restrict__ out) {
  int t = threadIdx.x;
  if (t >= 128) return;
  int b = t >> 6, ch = t & 63;
  const float* a = tn + (size_t)b * 256 + ch * 4;
  const float* c = x2 + ((size_t)b * 18 + 17) * 256 + ch * 4;
  float m = a[0] + c[0];
  m = fmaxf(m, a[1] + c[1]);
  m = fmaxf(m, a[2] + c[2]);
  m = fmaxf(m, a[3] + c[3]);
  out[b * 64 + ch] = m;
}

// ---------------- v2n (NHWC bf16) += vg broadcast ----------------
__global__ void k_addvg_n(unsigned short* __restrict__ v2n, const float* __restrict__ x2) {
  int idx = blockIdx.x * 256 + threadIdx.x;  // 16*1024*128 uints
  if (idx >= 2097152) return;
  int c2 = (idx & 127) * 2;
  int p  = (idx >> 7) & 1023;
  int n  = idx >> 17;
  int b = n >> 3, fi = n & 7;
  unsigned int* ptr = (unsigned int*)(v2n + ((size_t)(n * 1024 + p) * 256 + c2));
  unsigned int u = *ptr;
  const float* g = x2 + ((size_t)(b * 18 + fi)) * 256 + c2;
  unsigned short lo = f2bf(bf2f((unsigned short)(u & 0xffff)) + g[0]);
  unsigned short hi = f2bf(bf2f((unsigned short)(u >> 16)) + g[1]);
  *ptr = (unsigned int)lo | ((unsigned int)hi << 16);
}

extern "C" void kernel_launch(void* const* d_in, const int* in_sizes, int n_in,
                              void* d_out, int out_size, void* d_ws, size_t ws_size,
                              hipStream_t stream) {
  (void)in_sizes; (void)n_in; (void)out_size; (void)ws_size;
  const float* vf    = (const float*)d_in[0];
  const float* vp    = (const float*)d_in[1];
  const float* mf    = (const float*)d_in[2];
  const float* mp    = (const float*)d_in[3];
  const float* tf    = (const float*)d_in[4];
  const float* tp    = (const float*)d_in[5];
  const float* cv1w  = (const float*)d_in[6];
  const float* cv1b  = (const float*)d_in[7];
  const float* cv2w  = (const float*)d_in[8];
  const float* cv2b  = (const float*)d_in[9];
  const float* dc1w  = (const float*)d_in[10];
  const float* dc1b  = (const float*)d_in[11];
  const float* dc2w  = (const float*)d_in[12];
  const float* dc2b  = (const float*)d_in[13];
  const float* tc1w  = (const float*)d_in[14];
  const float* tc1b  = (const float*)d_in[15];
  const float* tc2w  = (const float*)d_in[16];
  const float* tc2b  = (const float*)d_in[17];
  const float* lin1w = (const float*)d_in[18];
  const float* att1  = (const float*)d_in[19];
  const float* lin2w = (const float*)d_in[20];
  const float* att2  = (const float*)d_in[21];
  const float* ew1   = (const float*)d_in[22];
  const float* ew2   = (const float*)d_in[23];
  const float* ea1   = (const float*)d_in[24];
  const float* ea2   = (const float*)d_in[25];
  const float* se1w1 = (const float*)d_in[26];
  const float* se1w2 = (const float*)d_in[27];
  const float* se2w1 = (const float*)d_in[28];
  const float* se2w2 = (const float*)d_in[29];

  float* ws  = (float*)d_ws;
  float* out = (float*)d_out;

  // workspace layout (float units); total ~19.7M floats = ~79 MB
  unsigned short* p0n = (unsigned short*)(ws);             // 16x128x128x64 bf16
  unsigned short* q1n = (unsigned short*)(ws + 8388608);   // 16x64x64x128 bf16 (d1n/v1n)
  unsigned short* t1n = (unsigned short*)(ws + 12582912);  // 16x64x64x128 bf16
  unsigned short* v2n = (unsigned short*)(ws + 16777216);  // 16x32x32x256 bf16 (d2n/v2n)
  unsigned short* wtb = (unsigned short*)(ws + 18874368);  // 1,105,920 bf16
  float* sm   = ws + 19427328;
  float* tn   = sm;                 // 512
  float* vn   = sm + 512;           // 4096
  float* dn   = sm + 4608;          // 4096
  float* x0   = sm + 8704;          // 9216
  float* xl   = sm + 17920;         // 102400
  float* sx   = sm + 120320;        // 144
  float* seb  = sm + 120464;        // 56
  float* eb   = sm + 120520;        // 28672
  float* ho   = sm + 149192;        // 18432
  float* x1   = sm + 167624;        // 18432
  float* x2   = sm + 186056;        // 9216

  unsigned short* wTc1 = wtb;             // 9*128*64
  unsigned short* wTd1 = wtb + 73728;
  unsigned short* wTc2 = wtb + 147456;    // 9*256*128
  unsigned short* wTd2 = wtb + 442368;
  unsigned short* wTt1 = wtb + 737280;    // 9*128*256 (tc1: in256->out128)
  unsigned short* wTt2 = wtb + 1032192;   // 9*64*128  (tc2: in128->out64)

  // 0. weight transforms
  k_wtrans<<<288, 256, 0, stream>>>(cv1w, wTc1, 128, 64);
  k_wtrans<<<288, 256, 0, stream>>>(dc1w, wTd1, 128, 64);
  k_wtrans<<<1152, 256, 0, stream>>>(cv2w, wTc2, 256, 128);
  k_wtrans<<<1152, 256, 0, stream>>>(dc2w, wTd2, 256, 128);
  k_wtrans_t<<<1152, 256, 0, stream>>>(tc1w, wTt1, 128, 256);
  k_wtrans_t<<<288, 256, 0, stream>>>(tc2w, wTt2, 64, 128);

  // 1. text pooling
  k_text_pool<<<2, 256, 0, stream>>>(tf, tp, tn);

  // 2. motion branch
  k_prep<<<4096, 256, 0, stream>>>(mf, mp, p0n);
  k_conv_mfma<64, 128, 64, 64, 1><<<2048, 256, 0, stream>>>(p0n, wTd1, dc1b, q1n);
  k_conv_mfma<128, 256, 32, 32, 2><<<1024, 256, 0, stream>>>(q1n, wTd2, dc2b, v2n);
  k_maxln_n<<<16, 1024, 0, stream>>>(v2n, dn);

  // 3. vision branch (q1n = v1n kept as deconv1 residual)
  k_prep<<<4096, 256, 0, stream>>>(vf, vp, p0n);
  k_conv_mfma<64, 128, 64, 64, 1><<<2048, 256, 0, stream>>>(p0n, wTc1, cv1b, q1n);
  k_conv_mfma<128, 256, 32, 32, 2><<<1024, 256, 0, stream>>>(q1n, wTc2, cv2b, v2n);
  k_maxln_n<<<16, 1024, 0, stream>>>(v2n, vn);

  // 4. node features
  k_build_x<<<2, 256, 0, stream>>>(vn, dn, tn, x0);

  // 5. GNN layer 1
  k_gnn_lin<<<50 * 8, 256, 0, stream>>>(x0, ea1, lin1w, xl, 256, 2048);
  k_gnn_att<<<1, 256, 0, stream>>>(xl, att1, sx, seb, 512);
  k_gnn_agg<<<1, 512, 0, stream>>>(xl, sx, seb, ew1, eb, ho, 512);
  k_gn_se<<<1, 512, 0, stream>>>(ho, se1w1, se1w2, x1, 512, 32);

  // 6. GNN layer 2
  k_gnn_lin<<<50 * 4, 256, 0, stream>>>(x1, ea2, lin2w, xl, 512, 1024);
  k_gnn_att<<<1, 256, 0, stream>>>(xl, att2, sx, seb, 256);
  k_gnn_agg<<<1, 512, 0, stream>>>(xl, sx, seb, ew2, eb, ho, 256);
  k_gn_se<<<1, 512, 0, stream>>>(ho, se2w1, se2w2, x2, 256, 16);

  // 7. observers
  k_obs<<<1, 128, 0, stream>>>(tn, x2, out + 16777216);

  // 8. decoder: v2n += vg ; t1n = v1n + relu(convT1(v2n)) ; out = (vf+vp) + relu(convT2(t1n))
  k_addvg_n<<<8192, 256, 0, stream>>>(v2n, x2);
  k_deconv_mfma<256, 128, 32, 32, 2, true ><<<512, 256, 0, stream>>>(
      v2n, wTt1, tc1b, q1n, nullptr, nullptr, t1n, nullptr);
  k_deconv_mfma<128, 64, 64, 64, 1, false><<<1024, 256, 0, stream>>>(
      t1n, wTt2, tc2b, nullptr, vf, vp, nullptr, out);
}

// Round 4
// 670.532 us; speedup vs baseline: 5.5775x; 1.4826x over previous
//
#include <hip/hip_runtime.h>
#include <hip/hip_bf16.h>
#include <cstddef>
#include <cstdint>

#define DEV_INLINE __device__ __forceinline__

typedef __attribute__((ext_vector_type(8))) short short8;
typedef __attribute__((ext_vector_type(4))) float f32x4;
typedef __attribute__((ext_vector_type(4))) unsigned short us4;

DEV_INLINE unsigned short f2bf(float f) {
  uint32_t u = __builtin_bit_cast(uint32_t, f);
  uint32_t r = (u + 0x7fffu + ((u >> 16) & 1u)) >> 16;
  return (unsigned short)r;
}
DEV_INLINE float bf2f(unsigned short u) {
  return __builtin_bit_cast(float, (uint32_t)u << 16);
}

// Problem constants: BS=2, F=8, C=64, H=128, W=128, HEADS=4
// 36 nodes, 14 hyperedges, 134 incidence entries (segments contiguous per edge)
__device__ __constant__ int c_cs[15] = {0,8,16,32,48,65,66,67,75,83,99,115,132,133,134};
// global row (node) index per incidence entry
__device__ __constant__ int c_row[134] = {
  // b=0
  0,1,2,3,4,5,6,7,
  8,9,10,11,12,13,14,15,
  0,1,2,3,4,5,6,7,8,9,10,11,12,13,14,15,
  0,1,2,3,4,5,6,7,8,9,10,11,12,13,14,15,
  0,1,2,3,4,5,6,7,8,9,10,11,12,13,14,15,16,
  16,
  17,
  // b=1 (+18)
  18,19,20,21,22,23,24,25,
  26,27,28,29,30,31,32,33,
  18,19,20,21,22,23,24,25,26,27,28,29,30,31,32,33,
  18,19,20,21,22,23,24,25,26,27,28,29,30,31,32,33,
  18,19,20,21,22,23,24,25,26,27,28,29,30,31,32,33,34,
  34,
  35
};
// hyperedge (col) index per incidence entry
__device__ __constant__ int c_col[134] = {
  0,0,0,0,0,0,0,0,
  1,1,1,1,1,1,1,1,
  2,2,2,2,2,2,2,2,2,2,2,2,2,2,2,2,
  3,3,3,3,3,3,3,3,3,3,3,3,3,3,3,3,
  4,4,4,4,4,4,4,4,4,4,4,4,4,4,4,4,4,
  5,
  6,
  7,7,7,7,7,7,7,7,
  8,8,8,8,8,8,8,8,
  9,9,9,9,9,9,9,9,9,9,9,9,9,9,9,9,
  10,10,10,10,10,10,10,10,10,10,10,10,10,10,10,10,
  11,11,11,11,11,11,11,11,11,11,11,11,11,11,11,11,11,
  12,
  13
};

// ---------------- text pool ----------------
__global__ void k_text_pool(const float* __restrict__ tf, const float* __restrict__ tp,
                            float* __restrict__ tn) {
  int t = blockIdx.x * blockDim.x + threadIdx.x;
  if (t >= 512) return;
  int b = t >> 8, idx = t & 255;
  int ch = idx >> 2, j = idx & 3;
  const float* p = tf + ((size_t)b * 64 + ch) * 16 + j * 4;
  const float* q = tp + ((size_t)b * 64 + ch) * 16 + j * 4;
  float m = p[0] + q[0];
  m = fmaxf(m, p[1] + q[1]);
  m = fmaxf(m, p[2] + q[2]);
  m = fmaxf(m, p[3] + q[3]);
  tn[(size_t)b * 256 + idx] = m;
}

// ---------------- input prep: (a+b) NCHW fp32 -> NHWC bf16 ----------------
__global__ __launch_bounds__(256) void k_prep(const float* __restrict__ a,
                                              const float* __restrict__ b,
                                              unsigned short* __restrict__ o) {
  int bid = blockIdx.x;
  int xb = bid & 1, y = (bid >> 1) & 127, n = bid >> 8;
  __shared__ unsigned short s[64][68];
  int t = threadIdx.x;
  const size_t base = ((size_t)n * 64) * 16384 + (size_t)y * 128 + xb * 64;
#pragma unroll
  for (int r = 0; r < 16; ++r) {
    int t2 = t + r * 256; int ci = t2 >> 6, x = t2 & 63;
    size_t off = base + (size_t)ci * 16384 + x;
    s[ci][x] = f2bf(a[off] + b[off]);
  }
  __syncthreads();
  unsigned int* op = (unsigned int*)(o + (((size_t)n * 128 + y) * 128 + xb * 64) * 64);
#pragma unroll
  for (int r = 0; r < 8; ++r) {
    int t2 = t + r * 256; int x = t2 >> 5, c2 = (t2 & 31) * 2;
    unsigned int lo = s[c2][x], hi = s[c2 + 1][x];
    op[x * 32 + (c2 >> 1)] = lo | (hi << 16);
  }
}

// ---------------- weight transforms -> wT[tap][co][ci] bf16 ----------------
__global__ void k_wtrans(const float* __restrict__ w, unsigned short* __restrict__ o,
                         int CO, int CI) {  // forward: w[co][ci][3][3]
  int idx = blockIdx.x * 256 + threadIdx.x;
  if (idx >= 9 * CO * CI) return;
  int ci = idx % CI; int r = idx / CI; int co = r % CO; int tap = r / CO;
  o[idx] = f2bf(w[((size_t)co * CI + ci) * 9 + tap]);
}
__global__ void k_wtrans_t(const float* __restrict__ w, unsigned short* __restrict__ o,
                           int CO, int CI) {  // transposed: w[ci][co][3][3]
  int idx = blockIdx.x * 256 + threadIdx.x;
  if (idx >= 9 * CO * CI) return;
  int ci = idx % CI; int r = idx / CI; int co = r % CO; int tap = r / CO;
  o[idx] = f2bf(w[((size_t)ci * CO + co) * 9 + tap]);
}

// ---------------- Conv2d k3 s2 p1 + bias + ReLU via bf16 MFMA ----------------
template<int CI, int CO, int HO, int WO, int ROUT>
__global__ __launch_bounds__(256) void k_conv_mfma(
    const unsigned short* __restrict__ in,   // NHWC bf16 [N][2HO][2WO][CI]
    const unsigned short* __restrict__ wT,   // [9][CO][CI] bf16
    const float* __restrict__ bias,
    unsigned short* __restrict__ outn) {     // NHWC bf16 [N][HO][WO][CO]
  constexpr int HIN = HO * 2, WIN = WO * 2;
  constexpr int XHP = WO + 2;
  constexpr int R = 2 * ROUT + 1;
  constexpr int NPOS = R * 2 * XHP;
  constexpr int CB = CO / 64;
  constexpr int OB = HO / ROUT;
  __shared__ short8 sIn[NPOS * 5];
  int bid = blockIdx.x;
  int cb = bid % CB; bid /= CB;
  int oyb = bid % OB; int n = bid / OB;
  int tid = threadIdx.x;
  int wid = tid >> 6, lane = tid & 63;
  int wm = wid >> 1, wn = wid & 1;
  int llo = lane & 15, lhi = lane >> 4;
  f32x4 acc[2][2] = {};
  const int iy0 = oyb * (2 * ROUT) - 1;
  for (int cs = 0; cs < CI / 32; ++cs) {
    for (int i = tid; i < NPOS * 4; i += 256) {
      int c = i & 3, q = i >> 2;
      int xh = q % XHP; int q2 = q / XHP;
      int p = q2 & 1, l = q2 >> 1;
      int x = 2 * xh + p - 1;
      int iy = iy0 + l;
      short8 v = {};
      if (x >= 0 && x < WIN && iy >= 0 && iy < HIN)
        v = *reinterpret_cast<const short8*>(in + ((((size_t)n * HIN + iy) * WIN + x) * CI + cs * 32 + c * 8));
      sIn[q * 5 + c] = v;
    }
    __syncthreads();
#pragma unroll
    for (int tap = 0; tap < 9; ++tap) {
      const int ky = tap / 3, kx = tap % 3;
      short8 afr[2], bfr[2];
#pragma unroll
      for (int m = 0; m < 2; ++m) {
        int co = cb * 64 + wm * 32 + m * 16 + llo;
        afr[m] = *reinterpret_cast<const short8*>(wT + (((size_t)tap * CO + co) * CI + cs * 32 + lhi * 8));
      }
#pragma unroll
      for (int n2 = 0; n2 < 2; ++n2) {
        int pix = wn * 32 + n2 * 16 + llo;
        int oyl = (ROUT == 2) ? (pix >> 5) : 0;
        int ox = pix - oyl * WO;
        int lrow = 2 * oyl + ky;
        int pos = (lrow * 2 + (kx & 1)) * XHP + ox + (kx >> 1);
        bfr[n2] = sIn[pos * 5 + lhi];
      }
#pragma unroll
      for (int m = 0; m < 2; ++m)
#pragma unroll
        for (int n2 = 0; n2 < 2; ++n2)
          acc[m][n2] = __builtin_amdgcn_mfma_f32_16x16x32_bf16(afr[m], bfr[n2], acc[m][n2], 0, 0, 0);
    }
    __syncthreads();
  }
#pragma unroll
  for (int m = 0; m < 2; ++m) {
    int co0 = cb * 64 + wm * 32 + m * 16 + lhi * 4;
    float4 bv = *reinterpret_cast<const float4*>(bias + co0);
#pragma unroll
    for (int n2 = 0; n2 < 2; ++n2) {
      int pix = wn * 32 + n2 * 16 + llo;
      int oyl = (ROUT == 2) ? (pix >> 5) : 0;
      int ox = pix - oyl * WO;
      int oy = oyb * ROUT + oyl;
      us4 pk;
      pk[0] = f2bf(fmaxf(acc[m][n2][0] + bv.x, 0.f));
      pk[1] = f2bf(fmaxf(acc[m][n2][1] + bv.y, 0.f));
      pk[2] = f2bf(fmaxf(acc[m][n2][2] + bv.z, 0.f));
      pk[3] = f2bf(fmaxf(acc[m][n2][3] + bv.w, 0.f));
      *reinterpret_cast<us4*>(outn + ((((size_t)n * HO + oy) * WO + ox) * CO + co0)) = pk;
    }
  }
}

// ---------------- ConvTranspose2d k3 s2 p1 op1 via bf16 MFMA (4 parity classes) ------
template<int CI, int CO, int Hi, int Wi, int QR, bool OBF>
__global__ __launch_bounds__(256) void k_deconv_mfma(
    const unsigned short* __restrict__ in,   // NHWC bf16 [N][Hi][Wi][CI]
    const unsigned short* __restrict__ wT,   // [9][CO][CI] bf16 (w[ci][co][ky][kx])
    const float* __restrict__ bias,
    const unsigned short* __restrict__ resn, // NHWC bf16 residual (OBF)
    const float* __restrict__ resA, const float* __restrict__ resB, // fp32 NCHW residuals
    unsigned short* __restrict__ outn,       // NHWC bf16 [N][2Hi][2Wi][CO]
    float* __restrict__ outc) {              // NCHW fp32
  constexpr int QC = 64 / QR;
  constexpr int WP = Wi + 1;
  constexpr int NPOS = (QR + 1) * WP;
  constexpr int CB = CO / 64;
  constexpr int OB = Hi / QR;
  constexpr int Ho = Hi * 2, Wo = Wi * 2;
  __shared__ short8 sIn[NPOS * 5];
  int bid = blockIdx.x;
  int cb = bid % CB; bid /= CB;
  int oyb = bid % OB; int n = bid / OB;
  int tid = threadIdx.x;
  int wid = tid >> 6, lane = tid & 63;
  int wm = wid >> 1, wn = wid & 1;
  int llo = lane & 15, lhi = lane >> 4;
  int qy0 = oyb * QR;
  f32x4 acc[4][2][2] = {};
  constexpr int tap_p[9] = {3,2,3,1,0,1,3,2,3};
  constexpr int tap_b[9] = {3,2,2,1,0,0,1,0,0};
  for (int cs = 0; cs < CI / 32; ++cs) {
    for (int i = tid; i < NPOS * 4; i += 256) {
      int c = i & 3, q = i >> 2;
      int x = q % WP, l = q / WP;
      int iy = qy0 + l;
      short8 v = {};
      if (x < Wi && iy < Hi)
        v = *reinterpret_cast<const short8*>(in + (((size_t)(n * Hi + iy) * Wi + x) * CI + cs * 32 + c * 8));
      sIn[q * 5 + c] = v;
    }
    __syncthreads();
    short8 bfr[2][4];
#pragma unroll
    for (int n2 = 0; n2 < 2; ++n2) {
      int pix = wn * 32 + n2 * 16 + llo;
      int qyl = pix / QC, qx = pix % QC;
#pragma unroll
      for (int bs = 0; bs < 4; ++bs) {
        int pos = (qyl + (bs >> 1)) * WP + qx + (bs & 1);
        bfr[n2][bs] = sIn[pos * 5 + lhi];
      }
    }
#pragma unroll
    for (int tap = 0; tap < 9; ++tap) {
      short8 afr[2];
#pragma unroll
      for (int m = 0; m < 2; ++m) {
        int co = cb * 64 + wm * 32 + m * 16 + llo;
        afr[m] = *reinterpret_cast<const short8*>(wT + (((size_t)tap * CO + co) * CI + cs * 32 + lhi * 8));
      }
#pragma unroll
      for (int m = 0; m < 2; ++m)
#pragma unroll
        for (int n2 = 0; n2 < 2; ++n2)
          acc[tap_p[tap]][m][n2] = __builtin_amdgcn_mfma_f32_16x16x32_bf16(
              afr[m], bfr[n2][tap_b[tap]], acc[tap_p[tap]][m][n2], 0, 0, 0);
    }
    __syncthreads();
  }
#pragma unroll
  for (int m = 0; m < 2; ++m) {
    int co0 = cb * 64 + wm * 32 + m * 16 + lhi * 4;
    float4 bv = *reinterpret_cast<const float4*>(bias + co0);
#pragma unroll
    for (int n2 = 0; n2 < 2; ++n2) {
      int pix = wn * 32 + n2 * 16 + llo;
      int qyl = pix / QC, qx = pix % QC;
      int qy = qy0 + qyl;
#pragma unroll
      for (int p = 0; p < 4; ++p) {
        int oy = 2 * qy + (p >> 1);
        int ox = 2 * qx + (p & 1);
        float v0 = fmaxf(acc[p][m][n2][0] + bv.x, 0.f);
        float v1 = fmaxf(acc[p][m][n2][1] + bv.y, 0.f);
        float v2 = fmaxf(acc[p][m][n2][2] + bv.z, 0.f);
        float v3 = fmaxf(acc[p][m][n2][3] + bv.w, 0.f);
        if constexpr (OBF) {
          size_t ad = ((size_t)(n * Ho + oy) * Wo + ox) * CO + co0;
          us4 r = *reinterpret_cast<const us4*>(resn + ad);
          us4 pk;
          pk[0] = f2bf(bf2f(r[0]) + v0);
          pk[1] = f2bf(bf2f(r[1]) + v1);
          pk[2] = f2bf(bf2f(r[2]) + v2);
          pk[3] = f2bf(bf2f(r[3]) + v3);
          *reinterpret_cast<us4*>(outn + ad) = pk;
        } else {
          size_t ob = ((size_t)(n * CO + co0) * Ho + oy) * Wo + ox;
          const size_t pl = (size_t)Ho * Wo;
          outc[ob]          = resA[ob]          + resB[ob]          + v0;
          outc[ob + pl]     = resA[ob + pl]     + resB[ob + pl]     + v1;
          outc[ob + 2 * pl] = resA[ob + 2 * pl] + resB[ob + 2 * pl] + v2;
          outc[ob + 3 * pl] = resA[ob + 3 * pl] + resB[ob + 3 * pl] + v3;
        }
      }
    }
  }
}

// ---------------- spatial max (NHWC bf16) + LayerNorm over 256 channels ----------------
__global__ __launch_bounds__(1024) void k_maxln_n(const unsigned short* __restrict__ x,
                                                  float* __restrict__ out) {
  int n = blockIdx.x, t = threadIdx.x;
  int ch = t & 255, pg = t >> 8;
  const unsigned short* base = x + (size_t)n * 1024 * 256 + ch;
  float m = -1e30f;
  for (int p = pg; p < 1024; p += 4)
    m = fmaxf(m, bf2f(base[(size_t)p * 256]));
  __shared__ float sm4[4][256];
  __shared__ float r1[256], r2[256];
  sm4[pg][ch] = m;
  __syncthreads();
  float mv = fmaxf(fmaxf(sm4[0][ch], sm4[1][ch]), fmaxf(sm4[2][ch], sm4[3][ch]));
  if (pg == 0) r1[ch] = mv;
  __syncthreads();
  for (int s = 128; s > 0; s >>= 1) { if (t < s) r1[t] += r1[t + s]; __syncthreads(); }
  float mu = r1[0] * (1.f / 256.f);
  float d = mv - mu;
  if (pg == 0) r2[ch] = d * d;
  __syncthreads();
  for (int s = 128; s > 0; s >>= 1) { if (t < s) r2[t] += r2[t + s]; __syncthreads(); }
  if (pg == 0) out[(size_t)n * 256 + ch] = d * rsqrtf(r2[0] * (1.f / 256.f) + 1e-5f);
}

// ---------------- build node features ----------------
__global__ void k_build_x(const float* __restrict__ vn, const float* __restrict__ dn,
                          const float* __restrict__ tn, float* __restrict__ x0) {
  int b = blockIdx.x, ch = threadIdx.x;
  float s = 0.f;
  for (int f = 0; f < 8; ++f) {
    float vv = vn[((size_t)b * 8 + f) * 256 + ch];
    float dd = dn[((size_t)b * 8 + f) * 256 + ch];
    s += vv + dd;
    x0[((size_t)b * 18 + f) * 256 + ch] = vv;
    x0[((size_t)b * 18 + 8 + f) * 256 + ch] = dd;
  }
  float tv = tn[(size_t)b * 256 + ch];
  x0[((size_t)b * 18 + 16) * 256 + ch] = tv;
  x0[((size_t)b * 18 + 17) * 256 + ch] = tv + s * (1.f / 8.f);
}

// ---------------- GNN linear ----------------
__global__ __launch_bounds__(256) void k_gnn_lin(
    const float* __restrict__ x, const float* __restrict__ ea,
    const float* __restrict__ w, float* __restrict__ y, int K, int M) {
  int chunks = M >> 8;
  int r = blockIdx.x / chunks;
  int ob = (blockIdx.x % chunks) * 256 + threadIdx.x;
  const float* src = (r < 36) ? (x + (size_t)r * K) : (ea + (size_t)(r - 36) * K);
  __shared__ __align__(16) float sxr[512];
  for (int k = threadIdx.x; k < K; k += 256) sxr[k] = src[k];
  __syncthreads();
  const float4* w4 = reinterpret_cast<const float4*>(w + (size_t)ob * K);
  const float4* x4 = reinterpret_cast<const float4*>(sxr);
  float acc = 0.f;
  int k4 = K >> 2;
  for (int k = 0; k < k4; ++k) {
    float4 a = x4[k], b = w4[k];
    acc += a.x * b.x + a.y * b.y + a.z * b.z + a.w * b.w;
  }
  y[(size_t)r * M + ob] = acc;
}

// ---------------- fused attention dots + logits + segment softmax -> attw(134,4) ------
template<int OC>
__global__ __launch_bounds__(256) void k_gnn_attsm(
    const float* __restrict__ y, const float* __restrict__ att,
    float* __restrict__ attw) {
  int t = threadIdx.x;
  __shared__ float sx_s[144], seb_s[60];
  __shared__ float a_s[536];
  if (t < 200) {
    int r = t >> 2, h = t & 3;
    const float4* row = reinterpret_cast<const float4*>(y + ((size_t)r * 4 + h) * OC);
    const float4* ar = reinterpret_cast<const float4*>(att + (size_t)h * 2 * OC + (r < 36 ? 0 : OC));
    float s = 0.f;
#pragma unroll 4
    for (int k = 0; k < OC / 4; ++k) {
      float4 a = row[k], b = ar[k];
      s += a.x * b.x + a.y * b.y + a.z * b.z + a.w * b.w;
    }
    if (r < 36) sx_s[r * 4 + h] = s; else seb_s[(r - 36) * 4 + h] = s;
  }
  __syncthreads();
  for (int idx = t; idx < 536; idx += 256) {
    int i = idx >> 2, h = idx & 3;
    float v = sx_s[c_row[i] * 4 + h] + seb_s[c_col[i] * 4 + h];
    a_s[idx] = (v > 0.f) ? v : 0.2f * v;
  }
  __syncthreads();
  if (t < 56) {
    int c = t >> 2, h = t & 3;
    int st = c_cs[c], en = c_cs[c + 1];
    float m = -1e30f;
    for (int i = st; i < en; ++i) m = fmaxf(m, a_s[i * 4 + h]);
    float s = 0.f;
    for (int i = st; i < en; ++i) { float e = __expf(a_s[i * 4 + h] - m); a_s[i * 4 + h] = e; s += e; }
    float inv = 1.f / (s + 1e-16f);
    for (int i = st; i < en; ++i) a_s[i * 4 + h] *= inv;
  }
  __syncthreads();
  for (int idx = t; idx < 536; idx += 256) attw[idx] = a_s[idx];
}

// ---------------- edge aggregation: eb[c,h,ch] = (1/cnt) sum_i a*xl[row,h,ch] ----------
template<int OC>
__global__ __launch_bounds__(256) void k_edge_agg(
    const float* __restrict__ y, const float* __restrict__ attw,
    float* __restrict__ eb) {
  int idx = blockIdx.x * 256 + threadIdx.x;
  if (idx >= 14 * 4 * OC) return;
  int ch = idx % OC;
  int h = (idx / OC) & 3;
  int c = idx / (4 * OC);
  int st = c_cs[c], en = c_cs[c + 1];
  float s = 0.f;
  for (int i = st; i < en; ++i)
    s += attw[i * 4 + h] * y[(size_t)c_row[i] * (4 * OC) + h * OC + ch];
  eb[idx] = s * (1.f / (float)(en - st));
}

// ---------------- node aggregation: ho[node,ch] = relu((D/4) sum a*e) ----------------
template<int OC>
__global__ __launch_bounds__(256) void k_node_agg(
    const float* __restrict__ attw, const float* __restrict__ eb,
    const float* __restrict__ ew, float* __restrict__ ho) {
  int idx = blockIdx.x * 256 + threadIdx.x;
  if (idx >= 36 * OC) return;
  int ch = idx % OC;
  int node = idx / OC;
  int b = node / 18, ln = node % 18;
  int ncols, cols[4], gis[4];
  if (ln < 16) {
    ncols = 4;
    cols[0] = b * 7 + (ln < 8 ? 0 : 1); gis[0] = b * 67 + ln;
    cols[1] = b * 7 + 2; gis[1] = b * 67 + 16 + ln;
    cols[2] = b * 7 + 3; gis[2] = b * 67 + 32 + ln;
    cols[3] = b * 7 + 4; gis[3] = b * 67 + 48 + ln;
  } else if (ln == 16) {
    ncols = 2;
    cols[0] = b * 7 + 4; gis[0] = b * 67 + 64;
    cols[1] = b * 7 + 5; gis[1] = b * 67 + 65;
    cols[2] = cols[3] = 0; gis[2] = gis[3] = 0;
  } else {
    ncols = 1;
    cols[0] = b * 7 + 6; gis[0] = b * 67 + 66;
    cols[1] = cols[2] = cols[3] = 0; gis[1] = gis[2] = gis[3] = 0;
  }
  float dsum = 0.f;
#pragma unroll
  for (int k = 0; k < 4; ++k) if (k < ncols) dsum += ew[cols[k]];
  float D = dsum > 0.f ? 1.f / dsum : 0.f;
  float s = 0.f;
#pragma unroll
  for (int k = 0; k < 4; ++k) {
    if (k < ncols) {
#pragma unroll
      for (int h = 0; h < 4; ++h)
        s += attw[gis[k] * 4 + h] * eb[((size_t)cols[k] * 4 + h) * OC + ch];
    }
  }
  ho[idx] = fmaxf(0.25f * D * s, 0.f);
}

// ---------------- GroupNorm(32) + SE layer ----------------
template<int C, int Cr>
__global__ __launch_bounds__(512) void k_gn_se(
    const float* __restrict__ hin, const float* __restrict__ w1,
    const float* __restrict__ w2, float* __restrict__ x) {
  int t = threadIdx.x;
  constexpr int gs = C >> 5;
  for (int idx = t; idx < 36 * 32; idx += 512) {
    int node = idx >> 5, g = idx & 31;
    const float* p = hin + (size_t)node * C + g * gs;
    float s = 0.f, s2 = 0.f;
#pragma unroll
    for (int k = 0; k < gs; ++k) { float v = p[k]; s += v; s2 += v * v; }
    float mu = s * (1.f / gs);
    float var = s2 * (1.f / gs) - mu * mu;
    float inv = rsqrtf(fmaxf(var, 0.f) + 1e-5f);
    float* q = x + (size_t)node * C + g * gs;
#pragma unroll
    for (int k = 0; k < gs; ++k) q[k] = (p[k] - mu) * inv;
  }
  __threadfence_block();
  __syncthreads();
  __shared__ float smean[C];
  __shared__ float spart[Cr][17];
  __shared__ float shid[Cr];
  __shared__ float sscale[C];
  if (t < C) {
    float s = 0.f;
    for (int nn = 0; nn < 36; ++nn) s += x[(size_t)nn * C + t];
    smean[t] = s * (1.f / 36.f);
  }
  __syncthreads();
  if (t < Cr * 16) {
    int hid = t >> 4, sub = t & 15;
    constexpr int CH = C / 16;
    float s = 0.f;
#pragma unroll
    for (int k = 0; k < CH; ++k)
      s += w1[(size_t)hid * C + sub * CH + k] * smean[sub * CH + k];
    spart[hid][sub] = s;
  }
  __syncthreads();
  if (t < Cr) {
    float s = 0.f;
#pragma unroll
    for (int k = 0; k < 16; ++k) s += spart[t][k];
    shid[t] = fmaxf(s, 0.f);
  }
  __syncthreads();
  if (t < C) {
    float s = 0.f;
#pragma unroll
    for (int k = 0; k < Cr; ++k) s += w2[(size_t)t * Cr + k] * shid[k];
    sscale[t] = 1.f / (1.f + __expf(-s));
  }
  __syncthreads();
  for (int idx = t; idx < 36 * C; idx += 512) x[idx] *= sscale[idx % C];
}

// ---------------- observers ----------------
__global__ void k_obs(const float* __restrict__ tn, const float* __restrict__ x2,
                      float* __restrict__ out) {
  int t = threadIdx.x;
  if (t >= 128) return;
  int b = t >> 6, ch = t & 63;
  const float* a = tn + (size_t)b * 256 + ch * 4;
  const float* c = x2 + ((size_t)b * 18 + 17) * 256 + ch * 4;
  float m = a[0] + c[0];
  m = fmaxf(m, a[1] + c[1]);
  m = fmaxf(m, a[2] + c[2]);
  m = fmaxf(m, a[3] + c[3]);
  out[b * 64 + ch] = m;
}

// ---------------- v2n (NHWC bf16) += vg broadcast ----------------
__global__ void k_addvg_n(unsigned short* __restrict__ v2n, const float* __restrict__ x2) {
  int idx = blockIdx.x * 256 + threadIdx.x;  // 16*1024*128 uints
  if (idx >= 2097152) return;
  int c2 = (idx & 127) * 2;
  int p  = (idx >> 7) & 1023;
  int n  = idx >> 17;
  int b = n >> 3, fi = n & 7;
  unsigned int* ptr = (unsigned int*)(v2n + ((size_t)(n * 1024 + p) * 256 + c2));
  unsigned int u = *ptr;
  const float* g = x2 + ((size_t)(b * 18 + fi)) * 256 + c2;
  unsigned short lo = f2bf(bf2f((unsigned short)(u & 0xffff)) + g[0]);
  unsigned short hi = f2bf(bf2f((unsigned short)(u >> 16)) + g[1]);
  *ptr = (unsigned int)lo | ((unsigned int)hi << 16);
}

extern "C" void kernel_launch(void* const* d_in, const int* in_sizes, int n_in,
                              void* d_out, int out_size, void* d_ws, size_t ws_size,
                              hipStream_t stream) {
  (void)in_sizes; (void)n_in; (void)out_size; (void)ws_size;
  const float* vf    = (const float*)d_in[0];
  const float* vp    = (const float*)d_in[1];
  const float* mf    = (const float*)d_in[2];
  const float* mp    = (const float*)d_in[3];
  const float* tf    = (const float*)d_in[4];
  const float* tp    = (const float*)d_in[5];
  const float* cv1w  = (const float*)d_in[6];
  const float* cv1b  = (const float*)d_in[7];
  const float* cv2w  = (const float*)d_in[8];
  const float* cv2b  = (const float*)d_in[9];
  const float* dc1w  = (const float*)d_in[10];
  const float* dc1b  = (const float*)d_in[11];
  const float* dc2w  = (const float*)d_in[12];
  const float* dc2b  = (const float*)d_in[13];
  const float* tc1w  = (const float*)d_in[14];
  const float* tc1b  = (const float*)d_in[15];
  const float* tc2w  = (const float*)d_in[16];
  const float* tc2b  = (const float*)d_in[17];
  const float* lin1w = (const float*)d_in[18];
  const float* att1  = (const float*)d_in[19];
  const float* lin2w = (const float*)d_in[20];
  const float* att2  = (const float*)d_in[21];
  const float* ew1   = (const float*)d_in[22];
  const float* ew2   = (const float*)d_in[23];
  const float* ea1   = (const float*)d_in[24];
  const float* ea2   = (const float*)d_in[25];
  const float* se1w1 = (const float*)d_in[26];
  const float* se1w2 = (const float*)d_in[27];
  const float* se2w1 = (const float*)d_in[28];
  const float* se2w2 = (const float*)d_in[29];

  float* ws  = (float*)d_ws;
  float* out = (float*)d_out;

  // workspace layout (float units)
  unsigned short* p0n = (unsigned short*)(ws);             // 16x128x128x64 bf16
  unsigned short* q1n = (unsigned short*)(ws + 8388608);   // 16x64x64x128 bf16 (d1n/v1n)
  unsigned short* t1n = (unsigned short*)(ws + 12582912);  // 16x64x64x128 bf16
  unsigned short* v2n = (unsigned short*)(ws + 16777216);  // 16x32x32x256 bf16 (d2n/v2n)
  unsigned short* wtb = (unsigned short*)(ws + 18874368);  // 1,105,920 bf16
  float* sm   = ws + 19427328;
  float* tn   = sm;                 // 512
  float* vn   = sm + 512;           // 4096
  float* dn   = sm + 4608;          // 4096
  float* x0   = sm + 8704;          // 9216
  float* xl   = sm + 17920;         // 102400
  float* eb   = sm + 120520;        // 28672
  float* ho   = sm + 149192;        // 18432
  float* x1   = sm + 167624;        // 18432
  float* x2   = sm + 186056;        // 9216
  float* attw = sm + 195272;        // 536

  unsigned short* wTc1 = wtb;             // 9*128*64
  unsigned short* wTd1 = wtb + 73728;
  unsigned short* wTc2 = wtb + 147456;    // 9*256*128
  unsigned short* wTd2 = wtb + 442368;
  unsigned short* wTt1 = wtb + 737280;    // 9*128*256 (tc1: in256->out128)
  unsigned short* wTt2 = wtb + 1032192;   // 9*64*128  (tc2: in128->out64)

  // 0. weight transforms
  k_wtrans<<<288, 256, 0, stream>>>(cv1w, wTc1, 128, 64);
  k_wtrans<<<288, 256, 0, stream>>>(dc1w, wTd1, 128, 64);
  k_wtrans<<<1152, 256, 0, stream>>>(cv2w, wTc2, 256, 128);
  k_wtrans<<<1152, 256, 0, stream>>>(dc2w, wTd2, 256, 128);
  k_wtrans_t<<<1152, 256, 0, stream>>>(tc1w, wTt1, 128, 256);
  k_wtrans_t<<<288, 256, 0, stream>>>(tc2w, wTt2, 64, 128);

  // 1. text pooling
  k_text_pool<<<2, 256, 0, stream>>>(tf, tp, tn);

  // 2. motion branch
  k_prep<<<4096, 256, 0, stream>>>(mf, mp, p0n);
  k_conv_mfma<64, 128, 64, 64, 1><<<2048, 256, 0, stream>>>(p0n, wTd1, dc1b, q1n);
  k_conv_mfma<128, 256, 32, 32, 2><<<1024, 256, 0, stream>>>(q1n, wTd2, dc2b, v2n);
  k_maxln_n<<<16, 1024, 0, stream>>>(v2n, dn);

  // 3. vision branch (q1n = v1n kept as deconv1 residual)
  k_prep<<<4096, 256, 0, stream>>>(vf, vp, p0n);
  k_conv_mfma<64, 128, 64, 64, 1><<<2048, 256, 0, stream>>>(p0n, wTc1, cv1b, q1n);
  k_conv_mfma<128, 256, 32, 32, 2><<<1024, 256, 0, stream>>>(q1n, wTc2, cv2b, v2n);
  k_maxln_n<<<16, 1024, 0, stream>>>(v2n, vn);

  // 4. node features
  k_build_x<<<2, 256, 0, stream>>>(vn, dn, tn, x0);

  // 5. GNN layer 1 (OC=512)
  k_gnn_lin<<<50 * 8, 256, 0, stream>>>(x0, ea1, lin1w, xl, 256, 2048);
  k_gnn_attsm<512><<<1, 256, 0, stream>>>(xl, att1, attw);
  k_edge_agg<512><<<112, 256, 0, stream>>>(xl, attw, eb);
  k_node_agg<512><<<72, 256, 0, stream>>>(attw, eb, ew1, ho);
  k_gn_se<512, 32><<<1, 512, 0, stream>>>(ho, se1w1, se1w2, x1);

  // 6. GNN layer 2 (OC=256)
  k_gnn_lin<<<50 * 4, 256, 0, stream>>>(x1, ea2, lin2w, xl, 512, 1024);
  k_gnn_attsm<256><<<1, 256, 0, stream>>>(xl, att2, attw);
  k_edge_agg<256><<<56, 256, 0, stream>>>(xl, attw, eb);
  k_node_agg<256><<<36, 256, 0, stream>>>(attw, eb, ew2, ho);
  k_gn_se<256, 16><<<1, 512, 0, stream>>>(ho, se2w1, se2w2, x2);

  // 7. observers
  k_obs<<<1, 128, 0, stream>>>(tn, x2, out + 16777216);

  // 8. decoder: v2n += vg ; t1n = v1n + relu(convT1(v2n)) ; out = (vf+vp) + relu(convT2(t1n))
  k_addvg_n<<<8192, 256, 0, stream>>>(v2n, x2);
  k_deconv_mfma<256, 128, 32, 32, 2, true ><<<512, 256, 0, stream>>>(
      v2n, wTt1, tc1b, q1n, nullptr, nullptr, t1n, nullptr);
  k_deconv_mfma<128, 64, 64, 64, 1, false><<<1024, 256, 0, stream>>>(
      t1n, wTt2, tc2b, nullptr, vf, vp, nullptr, out);
}

// Round 5
// 586.971 us; speedup vs baseline: 6.3715x; 1.1424x over previous
//
#include <hip/hip_runtime.h>
#include <hip/hip_bf16.h>
#include <cstddef>
#include <cstdint>

#define DEV_INLINE __device__ __forceinline__

typedef __attribute__((ext_vector_type(8))) short short8;
typedef __attribute__((ext_vector_type(4))) float f32x4;
typedef __attribute__((ext_vector_type(4))) unsigned short us4;

DEV_INLINE unsigned short f2bf(float f) {
  uint32_t u = __builtin_bit_cast(uint32_t, f);
  uint32_t r = (u + 0x7fffu + ((u >> 16) & 1u)) >> 16;
  return (unsigned short)r;
}
DEV_INLINE float bf2f(unsigned short u) {
  return __builtin_bit_cast(float, (uint32_t)u << 16);
}

// Problem constants: BS=2, F=8, C=64, H=128, W=128, HEADS=4
// 36 nodes, 14 hyperedges, 134 incidence entries (segments contiguous per edge)
__device__ __constant__ int c_cs[15] = {0,8,16,32,48,65,66,67,75,83,99,115,132,133,134};
__device__ __constant__ int c_row[134] = {
  0,1,2,3,4,5,6,7,
  8,9,10,11,12,13,14,15,
  0,1,2,3,4,5,6,7,8,9,10,11,12,13,14,15,
  0,1,2,3,4,5,6,7,8,9,10,11,12,13,14,15,
  0,1,2,3,4,5,6,7,8,9,10,11,12,13,14,15,16,
  16,
  17,
  18,19,20,21,22,23,24,25,
  26,27,28,29,30,31,32,33,
  18,19,20,21,22,23,24,25,26,27,28,29,30,31,32,33,
  18,19,20,21,22,23,24,25,26,27,28,29,30,31,32,33,
  18,19,20,21,22,23,24,25,26,27,28,29,30,31,32,33,34,
  34,
  35
};
__device__ __constant__ int c_col[134] = {
  0,0,0,0,0,0,0,0,
  1,1,1,1,1,1,1,1,
  2,2,2,2,2,2,2,2,2,2,2,2,2,2,2,2,
  3,3,3,3,3,3,3,3,3,3,3,3,3,3,3,3,
  4,4,4,4,4,4,4,4,4,4,4,4,4,4,4,4,4,
  5,
  6,
  7,7,7,7,7,7,7,7,
  8,8,8,8,8,8,8,8,
  9,9,9,9,9,9,9,9,9,9,9,9,9,9,9,9,
  10,10,10,10,10,10,10,10,10,10,10,10,10,10,10,10,
  11,11,11,11,11,11,11,11,11,11,11,11,11,11,11,11,11,
  12,
  13
};

// ---------------- text pool ----------------
__global__ void k_text_pool(const float* __restrict__ tf, const float* __restrict__ tp,
                            float* __restrict__ tn) {
  int t = blockIdx.x * blockDim.x + threadIdx.x;
  if (t >= 512) return;
  int b = t >> 8, idx = t & 255;
  int ch = idx >> 2, j = idx & 3;
  const float* p = tf + ((size_t)b * 64 + ch) * 16 + j * 4;
  const float* q = tp + ((size_t)b * 64 + ch) * 16 + j * 4;
  float m = p[0] + q[0];
  m = fmaxf(m, p[1] + q[1]);
  m = fmaxf(m, p[2] + q[2]);
  m = fmaxf(m, p[3] + q[3]);
  tn[(size_t)b * 256 + idx] = m;
}

// ---------------- input prep: (a+b) NCHW fp32 -> NHWC bf16 ----------------
__global__ __launch_bounds__(256) void k_prep(const float* __restrict__ a,
                                              const float* __restrict__ b,
                                              unsigned short* __restrict__ o) {
  int bid = blockIdx.x;
  int xb = bid & 1, y = (bid >> 1) & 127, n = bid >> 8;
  __shared__ unsigned short s[64][68];
  int t = threadIdx.x;
  const size_t base = ((size_t)n * 64) * 16384 + (size_t)y * 128 + xb * 64;
#pragma unroll
  for (int r = 0; r < 16; ++r) {
    int t2 = t + r * 256; int ci = t2 >> 6, x = t2 & 63;
    size_t off = base + (size_t)ci * 16384 + x;
    s[ci][x] = f2bf(a[off] + b[off]);
  }
  __syncthreads();
  unsigned int* op = (unsigned int*)(o + (((size_t)n * 128 + y) * 128 + xb * 64) * 64);
#pragma unroll
  for (int r = 0; r < 8; ++r) {
    int t2 = t + r * 256; int x = t2 >> 5, c2 = (t2 & 31) * 2;
    unsigned int lo = s[c2][x], hi = s[c2 + 1][x];
    op[x * 32 + (c2 >> 1)] = lo | (hi << 16);
  }
}

// ---------------- all weight transforms -> wT[tap][co][ci] bf16, one kernel ----------
__global__ void k_wtrans_all(const float* __restrict__ cv1w, const float* __restrict__ dc1w,
                             const float* __restrict__ cv2w, const float* __restrict__ dc2w,
                             const float* __restrict__ tc1w, const float* __restrict__ tc2w,
                             unsigned short* __restrict__ wtb) {
  int idx = blockIdx.x * 256 + threadIdx.x;
  const float* src; int off, lci, lco; bool tra;
  if (idx < 73728)        { src = cv1w; off = 0;       lci = 6; lco = 7; tra = false; }
  else if (idx < 147456)  { src = dc1w; off = 73728;   lci = 6; lco = 7; tra = false; }
  else if (idx < 442368)  { src = cv2w; off = 147456;  lci = 7; lco = 8; tra = false; }
  else if (idx < 737280)  { src = dc2w; off = 442368;  lci = 7; lco = 8; tra = false; }
  else if (idx < 1032192) { src = tc1w; off = 737280;  lci = 8; lco = 7; tra = true;  }
  else if (idx < 1105920) { src = tc2w; off = 1032192; lci = 7; lco = 6; tra = true;  }
  else return;
  int l = idx - off;
  int ci = l & ((1 << lci) - 1);
  int r = l >> lci;
  int co = r & ((1 << lco) - 1);
  int tap = r >> lco;
  size_t si = tra ? (((size_t)ci << lco) + co) * 9 + tap
                  : (((size_t)co << lci) + ci) * 9 + tap;
  wtb[idx] = f2bf(src[si]);
}

// ---------------- Conv2d k3 s2 p1 + bias + ReLU via bf16 MFMA ----------------
// Block: 512 thr = 8 waves (4x2); 128 co x 64 pixels per block.
template<int CI, int CO, int HO, int WO, int ROUT>
__global__ __launch_bounds__(512) void k_conv_mfma(
    const unsigned short* __restrict__ in,   // NHWC bf16 [N][2HO][2WO][CI]
    const unsigned short* __restrict__ wT,   // [9][CO][CI] bf16
    const float* __restrict__ bias,
    unsigned short* __restrict__ outn) {     // NHWC bf16 [N][HO][WO][CO]
  constexpr int HIN = HO * 2, WIN = WO * 2;
  constexpr int XHP = WO + 2;
  constexpr int R = 2 * ROUT + 1;
  constexpr int NPOS = R * 2 * XHP;
  constexpr int CB = CO / 128;
  constexpr int OB = HO / ROUT;
  __shared__ short8 sIn[NPOS * 5];
  int bid = blockIdx.x;
  int cb = bid % CB; bid /= CB;
  int oyb = bid % OB; int n = bid / OB;
  int tid = threadIdx.x;
  int wid = tid >> 6, lane = tid & 63;
  int wm = wid >> 1, wn = wid & 1;   // wm 0..3, wn 0..1
  int llo = lane & 15, lhi = lane >> 4;
  f32x4 acc[2][2] = {};
  const int iy0 = oyb * (2 * ROUT) - 1;
  for (int cs = 0; cs < CI / 32; ++cs) {
    for (int i = tid; i < NPOS * 4; i += 512) {
      int c = i & 3, q = i >> 2;
      int xh = q % XHP; int q2 = q / XHP;
      int p = q2 & 1, l = q2 >> 1;
      int x = 2 * xh + p - 1;
      int iy = iy0 + l;
      short8 v = {};
      if (x >= 0 && x < WIN && iy >= 0 && iy < HIN)
        v = *reinterpret_cast<const short8*>(in + ((((size_t)n * HIN + iy) * WIN + x) * CI + cs * 32 + c * 8));
      sIn[q * 5 + c] = v;
    }
    __syncthreads();
#pragma unroll
    for (int tap = 0; tap < 9; ++tap) {
      const int ky = tap / 3, kx = tap % 3;
      short8 afr[2], bfr[2];
#pragma unroll
      for (int m = 0; m < 2; ++m) {
        int co = cb * 128 + wm * 32 + m * 16 + llo;
        afr[m] = *reinterpret_cast<const short8*>(wT + (((size_t)tap * CO + co) * CI + cs * 32 + lhi * 8));
      }
#pragma unroll
      for (int n2 = 0; n2 < 2; ++n2) {
        int pix = wn * 32 + n2 * 16 + llo;
        int oyl = (ROUT == 2) ? (pix >> 5) : 0;
        int ox = pix - oyl * WO;
        int lrow = 2 * oyl + ky;
        int pos = (lrow * 2 + (kx & 1)) * XHP + ox + (kx >> 1);
        bfr[n2] = sIn[pos * 5 + lhi];
      }
#pragma unroll
      for (int m = 0; m < 2; ++m)
#pragma unroll
        for (int n2 = 0; n2 < 2; ++n2)
          acc[m][n2] = __builtin_amdgcn_mfma_f32_16x16x32_bf16(afr[m], bfr[n2], acc[m][n2], 0, 0, 0);
    }
    __syncthreads();
  }
#pragma unroll
  for (int m = 0; m < 2; ++m) {
    int co0 = cb * 128 + wm * 32 + m * 16 + lhi * 4;
    f32x4 bv = *reinterpret_cast<const f32x4*>(bias + co0);
#pragma unroll
    for (int n2 = 0; n2 < 2; ++n2) {
      int pix = wn * 32 + n2 * 16 + llo;
      int oyl = (ROUT == 2) ? (pix >> 5) : 0;
      int ox = pix - oyl * WO;
      int oy = oyb * ROUT + oyl;
      us4 pk;
      pk[0] = f2bf(fmaxf(acc[m][n2][0] + bv[0], 0.f));
      pk[1] = f2bf(fmaxf(acc[m][n2][1] + bv[1], 0.f));
      pk[2] = f2bf(fmaxf(acc[m][n2][2] + bv[2], 0.f));
      pk[3] = f2bf(fmaxf(acc[m][n2][3] + bv[3], 0.f));
      *reinterpret_cast<us4*>(outn + ((((size_t)n * HO + oy) * WO + ox) * CO + co0)) = pk;
    }
  }
}

// ---------------- ConvTranspose2d k3 s2 p1 op1 via bf16 MFMA (4 parity classes) ------
// OBF: bf16 NHWC out with bf16 residual. !OBF: fp32 NCHW out (float2 stores) with
// bf16 NHWC residual. GADD: fuse per-frame channel-broadcast add into input staging.
template<int CI, int CO, int Hi, int Wi, int QR, bool OBF, bool GADD>
__global__ __launch_bounds__(256) void k_deconv_mfma(
    const unsigned short* __restrict__ in,   // NHWC bf16 [N][Hi][Wi][CI]
    const unsigned short* __restrict__ wT,   // [9][CO][CI] bf16 (w[ci][co][ky][kx])
    const float* __restrict__ bias,
    const unsigned short* __restrict__ resn, // NHWC bf16 residual
    const float* __restrict__ gsrc,          // GADD: x2 node features (per-frame 256ch)
    unsigned short* __restrict__ outn,       // NHWC bf16 [N][2Hi][2Wi][CO]
    float* __restrict__ outc) {              // NCHW fp32
  constexpr int QC = 64 / QR;
  constexpr int WP = Wi + 1;
  constexpr int NPOS = (QR + 1) * WP;
  constexpr int CB = CO / 64;
  constexpr int OB = Hi / QR;
  constexpr int Ho = Hi * 2, Wo = Wi * 2;
  __shared__ short8 sIn[NPOS * 5];
  int bid = blockIdx.x;
  int cb = bid % CB; bid /= CB;
  int oyb = bid % OB; int n = bid / OB;
  int tid = threadIdx.x;
  int wid = tid >> 6, lane = tid & 63;
  int wm = wid >> 1, wn = wid & 1;
  int llo = lane & 15, lhi = lane >> 4;
  int qy0 = oyb * QR;
  const float* g = nullptr;
  if constexpr (GADD) g = gsrc + ((size_t)((n >> 3) * 18 + (n & 7))) * 256;
  f32x4 acc[4][2][2] = {};
  constexpr int tap_p[9] = {3,2,3,1,0,1,3,2,3};
  constexpr int tap_b[9] = {3,2,2,1,0,0,1,0,0};
  for (int cs = 0; cs < CI / 32; ++cs) {
    for (int i = tid; i < NPOS * 4; i += 256) {
      int c = i & 3, q = i >> 2;
      int x = q % WP, l = q / WP;
      int iy = qy0 + l;
      short8 v = {};
      if (x < Wi && iy < Hi) {
        v = *reinterpret_cast<const short8*>(in + (((size_t)(n * Hi + iy) * Wi + x) * CI + cs * 32 + c * 8));
        if constexpr (GADD) {
#pragma unroll
          for (int j = 0; j < 8; ++j) {
            float fv = bf2f((unsigned short)v[j]) + g[cs * 32 + c * 8 + j];
            v[j] = (short)f2bf(fv);
          }
        }
      }
      sIn[q * 5 + c] = v;
    }
    __syncthreads();
    short8 bfr[2][4];
#pragma unroll
    for (int n2 = 0; n2 < 2; ++n2) {
      int pix = wn * 32 + n2 * 16 + llo;
      int qyl = pix / QC, qx = pix % QC;
#pragma unroll
      for (int bs = 0; bs < 4; ++bs) {
        int pos = (qyl + (bs >> 1)) * WP + qx + (bs & 1);
        bfr[n2][bs] = sIn[pos * 5 + lhi];
      }
    }
#pragma unroll
    for (int tap = 0; tap < 9; ++tap) {
      short8 afr[2];
#pragma unroll
      for (int m = 0; m < 2; ++m) {
        int co = cb * 64 + wm * 32 + m * 16 + llo;
        afr[m] = *reinterpret_cast<const short8*>(wT + (((size_t)tap * CO + co) * CI + cs * 32 + lhi * 8));
      }
#pragma unroll
      for (int m = 0; m < 2; ++m)
#pragma unroll
        for (int n2 = 0; n2 < 2; ++n2)
          acc[tap_p[tap]][m][n2] = __builtin_amdgcn_mfma_f32_16x16x32_bf16(
              afr[m], bfr[n2][tap_b[tap]], acc[tap_p[tap]][m][n2], 0, 0, 0);
    }
    __syncthreads();
  }
#pragma unroll
  for (int m = 0; m < 2; ++m) {
    int co0 = cb * 64 + wm * 32 + m * 16 + lhi * 4;
    f32x4 bv = *reinterpret_cast<const f32x4*>(bias + co0);
#pragma unroll
    for (int n2 = 0; n2 < 2; ++n2) {
      int pix = wn * 32 + n2 * 16 + llo;
      int qyl = pix / QC, qx = pix % QC;
      int qy = qy0 + qyl;
      if constexpr (OBF) {
#pragma unroll
        for (int p = 0; p < 4; ++p) {
          int oy = 2 * qy + (p >> 1);
          int ox = 2 * qx + (p & 1);
          size_t ad = ((size_t)(n * Ho + oy) * Wo + ox) * CO + co0;
          us4 r = *reinterpret_cast<const us4*>(resn + ad);
          us4 pk;
#pragma unroll
          for (int c = 0; c < 4; ++c)
            pk[c] = f2bf(bf2f(r[c]) + fmaxf(acc[p][m][n2][c] + bv[c], 0.f));
          *reinterpret_cast<us4*>(outn + ad) = pk;
        }
      } else {
        int qx2 = 2 * qx;
#pragma unroll
        for (int dy = 0; dy < 2; ++dy) {
          int oy = 2 * qy + dy;
          size_t rb = ((size_t)(n * Ho + oy) * Wo + qx2) * CO + co0;
          us4 r0 = *reinterpret_cast<const us4*>(resn + rb);
          us4 r1 = *reinterpret_cast<const us4*>(resn + rb + CO);
#pragma unroll
          for (int c = 0; c < 4; ++c) {
            float2 st;
            st.x = bf2f(r0[c]) + fmaxf(acc[dy * 2][m][n2][c] + bv[c], 0.f);
            st.y = bf2f(r1[c]) + fmaxf(acc[dy * 2 + 1][m][n2][c] + bv[c], 0.f);
            *reinterpret_cast<float2*>(outc + ((size_t)(n * CO + co0 + c) * Ho + oy) * Wo + qx2) = st;
          }
        }
      }
    }
  }
}

// ---------------- spatial max (NHWC bf16) + LayerNorm over 256 channels ----------------
__global__ __launch_bounds__(1024) void k_maxln_n(const unsigned short* __restrict__ x,
                                                  float* __restrict__ out) {
  int n = blockIdx.x, t = threadIdx.x;
  int ch = t & 255, pg = t >> 8;
  const unsigned short* base = x + (size_t)n * 1024 * 256 + ch;
  float m = -1e30f;
  for (int p = pg; p < 1024; p += 4)
    m = fmaxf(m, bf2f(base[(size_t)p * 256]));
  __shared__ float sm4[4][256];
  __shared__ float r1[256], r2[256];
  sm4[pg][ch] = m;
  __syncthreads();
  float mv = fmaxf(fmaxf(sm4[0][ch], sm4[1][ch]), fmaxf(sm4[2][ch], sm4[3][ch]));
  if (pg == 0) r1[ch] = mv;
  __syncthreads();
  for (int s = 128; s > 0; s >>= 1) { if (t < s) r1[t] += r1[t + s]; __syncthreads(); }
  float mu = r1[0] * (1.f / 256.f);
  float d = mv - mu;
  if (pg == 0) r2[ch] = d * d;
  __syncthreads();
  for (int s = 128; s > 0; s >>= 1) { if (t < s) r2[t] += r2[t + s]; __syncthreads(); }
  if (pg == 0) out[(size_t)n * 256 + ch] = d * rsqrtf(r2[0] * (1.f / 256.f) + 1e-5f);
}

// ---------------- build node features ----------------
__global__ void k_build_x(const float* __restrict__ vn, const float* __restrict__ dn,
                          const float* __restrict__ tn, float* __restrict__ x0) {
  int b = blockIdx.x, ch = threadIdx.x;
  float s = 0.f;
  for (int f = 0; f < 8; ++f) {
    float vv = vn[((size_t)b * 8 + f) * 256 + ch];
    float dd = dn[((size_t)b * 8 + f) * 256 + ch];
    s += vv + dd;
    x0[((size_t)b * 18 + f) * 256 + ch] = vv;
    x0[((size_t)b * 18 + 8 + f) * 256 + ch] = dd;
  }
  float tv = tn[(size_t)b * 256 + ch];
  x0[((size_t)b * 18 + 16) * 256 + ch] = tv;
  x0[((size_t)b * 18 + 17) * 256 + ch] = tv + s * (1.f / 8.f);
}

// ---------------- GNN linear ----------------
__global__ __launch_bounds__(256) void k_gnn_lin(
    const float* __restrict__ x, const float* __restrict__ ea,
    const float* __restrict__ w, float* __restrict__ y, int K, int M) {
  int chunks = M >> 8;
  int r = blockIdx.x / chunks;
  int ob = (blockIdx.x % chunks) * 256 + threadIdx.x;
  const float* src = (r < 36) ? (x + (size_t)r * K) : (ea + (size_t)(r - 36) * K);
  __shared__ __align__(16) float sxr[512];
  for (int k = threadIdx.x; k < K; k += 256) sxr[k] = src[k];
  __syncthreads();
  const float4* w4 = reinterpret_cast<const float4*>(w + (size_t)ob * K);
  const float4* x4 = reinterpret_cast<const float4*>(sxr);
  float acc = 0.f;
  int k4 = K >> 2;
  for (int k = 0; k < k4; ++k) {
    float4 a = x4[k], b = w4[k];
    acc += a.x * b.x + a.y * b.y + a.z * b.z + a.w * b.w;
  }
  y[(size_t)r * M + ob] = acc;
}

// ---------------- fused attention dots + logits + segment softmax -> attw(134,4) ------
template<int OC>
__global__ __launch_bounds__(256) void k_gnn_attsm(
    const float* __restrict__ y, const float* __restrict__ att,
    float* __restrict__ attw) {
  int t = threadIdx.x;
  __shared__ float sx_s[144], seb_s[60];
  __shared__ float a_s[536];
  if (t < 200) {
    int r = t >> 2, h = t & 3;
    const float4* row = reinterpret_cast<const float4*>(y + ((size_t)r * 4 + h) * OC);
    const float4* ar = reinterpret_cast<const float4*>(att + (size_t)h * 2 * OC + (r < 36 ? 0 : OC));
    float s = 0.f;
#pragma unroll 4
    for (int k = 0; k < OC / 4; ++k) {
      float4 a = row[k], b = ar[k];
      s += a.x * b.x + a.y * b.y + a.z * b.z + a.w * b.w;
    }
    if (r < 36) sx_s[r * 4 + h] = s; else seb_s[(r - 36) * 4 + h] = s;
  }
  __syncthreads();
  for (int idx = t; idx < 536; idx += 256) {
    int i = idx >> 2, h = idx & 3;
    float v = sx_s[c_row[i] * 4 + h] + seb_s[c_col[i] * 4 + h];
    a_s[idx] = (v > 0.f) ? v : 0.2f * v;
  }
  __syncthreads();
  if (t < 56) {
    int c = t >> 2, h = t & 3;
    int st = c_cs[c], en = c_cs[c + 1];
    float m = -1e30f;
    for (int i = st; i < en; ++i) m = fmaxf(m, a_s[i * 4 + h]);
    float s = 0.f;
    for (int i = st; i < en; ++i) { float e = __expf(a_s[i * 4 + h] - m); a_s[i * 4 + h] = e; s += e; }
    float inv = 1.f / (s + 1e-16f);
    for (int i = st; i < en; ++i) a_s[i * 4 + h] *= inv;
  }
  __syncthreads();
  for (int idx = t; idx < 536; idx += 256) attw[idx] = a_s[idx];
}

// ---------------- edge aggregation ----------------
template<int OC>
__global__ __launch_bounds__(256) void k_edge_agg(
    const float* __restrict__ y, const float* __restrict__ attw,
    float* __restrict__ eb) {
  int idx = blockIdx.x * 256 + threadIdx.x;
  if (idx >= 14 * 4 * OC) return;
  int ch = idx % OC;
  int h = (idx / OC) & 3;
  int c = idx / (4 * OC);
  int st = c_cs[c], en = c_cs[c + 1];
  float s = 0.f;
  for (int i = st; i < en; ++i)
    s += attw[i * 4 + h] * y[(size_t)c_row[i] * (4 * OC) + h * OC + ch];
  eb[idx] = s * (1.f / (float)(en - st));
}

// ---------------- node aggregation ----------------
template<int OC>
__global__ __launch_bounds__(256) void k_node_agg(
    const float* __restrict__ attw, const float* __restrict__ eb,
    const float* __restrict__ ew, float* __restrict__ ho) {
  int idx = blockIdx.x * 256 + threadIdx.x;
  if (idx >= 36 * OC) return;
  int ch = idx % OC;
  int node = idx / OC;
  int b = node / 18, ln = node % 18;
  int ncols, cols[4], gis[4];
  if (ln < 16) {
    ncols = 4;
    cols[0] = b * 7 + (ln < 8 ? 0 : 1); gis[0] = b * 67 + ln;
    cols[1] = b * 7 + 2; gis[1] = b * 67 + 16 + ln;
    cols[2] = b * 7 + 3; gis[2] = b * 67 + 32 + ln;
    cols[3] = b * 7 + 4; gis[3] = b * 67 + 48 + ln;
  } else if (ln == 16) {
    ncols = 2;
    cols[0] = b * 7 + 4; gis[0] = b * 67 + 64;
    cols[1] = b * 7 + 5; gis[1] = b * 67 + 65;
    cols[2] = cols[3] = 0; gis[2] = gis[3] = 0;
  } else {
    ncols = 1;
    cols[0] = b * 7 + 6; gis[0] = b * 67 + 66;
    cols[1] = cols[2] = cols[3] = 0; gis[1] = gis[2] = gis[3] = 0;
  }
  float dsum = 0.f;
#pragma unroll
  for (int k = 0; k < 4; ++k) if (k < ncols) dsum += ew[cols[k]];
  float D = dsum > 0.f ? 1.f / dsum : 0.f;
  float s = 0.f;
#pragma unroll
  for (int k = 0; k < 4; ++k) {
    if (k < ncols) {
#pragma unroll
      for (int h = 0; h < 4; ++h)
        s += attw[gis[k] * 4 + h] * eb[((size_t)cols[k] * 4 + h) * OC + ch];
    }
  }
  ho[idx] = fmaxf(0.25f * D * s, 0.f);
}

// ---------------- GroupNorm(32) + SE layer ----------------
template<int C, int Cr>
__global__ __launch_bounds__(512) void k_gn_se(
    const float* __restrict__ hin, const float* __restrict__ w1,
    const float* __restrict__ w2, float* __restrict__ x) {
  int t = threadIdx.x;
  constexpr int gs = C >> 5;
  for (int idx = t; idx < 36 * 32; idx += 512) {
    int node = idx >> 5, g = idx & 31;
    const float* p = hin + (size_t)node * C + g * gs;
    float s = 0.f, s2 = 0.f;
#pragma unroll
    for (int k = 0; k < gs; ++k) { float v = p[k]; s += v; s2 += v * v; }
    float mu = s * (1.f / gs);
    float var = s2 * (1.f / gs) - mu * mu;
    float inv = rsqrtf(fmaxf(var, 0.f) + 1e-5f);
    float* q = x + (size_t)node * C + g * gs;
#pragma unroll
    for (int k = 0; k < gs; ++k) q[k] = (p[k] - mu) * inv;
  }
  __threadfence_block();
  __syncthreads();
  __shared__ float smean[C];
  __shared__ float spart[Cr][17];
  __shared__ float shid[Cr];
  __shared__ float sscale[C];
  if (t < C) {
    float s = 0.f;
    for (int nn = 0; nn < 36; ++nn) s += x[(size_t)nn * C + t];
    smean[t] = s * (1.f / 36.f);
  }
  __syncthreads();
  if (t < Cr * 16) {
    int hid = t >> 4, sub = t & 15;
    constexpr int CH = C / 16;
    float s = 0.f;
#pragma unroll
    for (int k = 0; k < CH; ++k)
      s += w1[(size_t)hid * C + sub * CH + k] * smean[sub * CH + k];
    spart[hid][sub] = s;
  }
  __syncthreads();
  if (t < Cr) {
    float s = 0.f;
#pragma unroll
    for (int k = 0; k < 16; ++k) s += spart[t][k];
    shid[t] = fmaxf(s, 0.f);
  }
  __syncthreads();
  if (t < C) {
    float s = 0.f;
#pragma unroll
    for (int k = 0; k < Cr; ++k) s += w2[(size_t)t * Cr + k] * shid[k];
    sscale[t] = 1.f / (1.f + __expf(-s));
  }
  __syncthreads();
  for (int idx = t; idx < 36 * C; idx += 512) x[idx] *= sscale[idx % C];
}

// ---------------- observers ----------------
__global__ void k_obs(const float* __restrict__ tn, const float* __restrict__ x2,
                      float* __restrict__ out) {
  int t = threadIdx.x;
  if (t >= 128) return;
  int b = t >> 6, ch = t & 63;
  const float* a = tn + (size_t)b * 256 + ch * 4;
  const float* c = x2 + ((size_t)b * 18 + 17) * 256 + ch * 4;
  float m = a[0] + c[0];
  m = fmaxf(m, a[1] + c[1]);
  m = fmaxf(m, a[2] + c[2]);
  m = fmaxf(m, a[3] + c[3]);
  out[b * 64 + ch] = m;
}

extern "C" void kernel_launch(void* const* d_in, const int* in_sizes, int n_in,
                              void* d_out, int out_size, void* d_ws, size_t ws_size,
                              hipStream_t stream) {
  (void)in_sizes; (void)n_in; (void)out_size; (void)ws_size;
  const float* vf    = (const float*)d_in[0];
  const float* vp    = (const float*)d_in[1];
  const float* mf    = (const float*)d_in[2];
  const float* mp    = (const float*)d_in[3];
  const float* tf    = (const float*)d_in[4];
  const float* tp    = (const float*)d_in[5];
  const float* cv1w  = (const float*)d_in[6];
  const float* cv1b  = (const float*)d_in[7];
  const float* cv2w  = (const float*)d_in[8];
  const float* cv2b  = (const float*)d_in[9];
  const float* dc1w  = (const float*)d_in[10];
  const float* dc1b  = (const float*)d_in[11];
  const float* dc2w  = (const float*)d_in[12];
  const float* dc2b  = (const float*)d_in[13];
  const float* tc1w  = (const float*)d_in[14];
  const float* tc1b  = (const float*)d_in[15];
  const float* tc2w  = (const float*)d_in[16];
  const float* tc2b  = (const float*)d_in[17];
  const float* lin1w = (const float*)d_in[18];
  const float* att1  = (const float*)d_in[19];
  const float* lin2w = (const float*)d_in[20];
  const float* att2  = (const float*)d_in[21];
  const float* ew1   = (const float*)d_in[22];
  const float* ew2   = (const float*)d_in[23];
  const float* ea1   = (const float*)d_in[24];
  const float* ea2   = (const float*)d_in[25];
  const float* se1w1 = (const float*)d_in[26];
  const float* se1w2 = (const float*)d_in[27];
  const float* se2w1 = (const float*)d_in[28];
  const float* se2w2 = (const float*)d_in[29];

  float* ws  = (float*)d_ws;
  float* out = (float*)d_out;

  // workspace layout (float units)
  unsigned short* p0n = (unsigned short*)(ws);             // 16x128x128x64 bf16 (vf+vp NHWC, kept for deconv2 residual)
  unsigned short* q1n = (unsigned short*)(ws + 8388608);   // 16x64x64x128 bf16 (d1n/v1n)
  unsigned short* t1n = (unsigned short*)(ws + 12582912);  // 16x64x64x128 bf16
  unsigned short* v2n = (unsigned short*)(ws + 16777216);  // 16x32x32x256 bf16 (d2n/v2n)
  unsigned short* wtb = (unsigned short*)(ws + 18874368);  // 1,105,920 bf16
  float* sm   = ws + 19427328;
  float* tn   = sm;                 // 512
  float* vn   = sm + 512;           // 4096
  float* dn   = sm + 4608;          // 4096
  float* x0   = sm + 8704;          // 9216
  float* xl   = sm + 17920;         // 102400
  float* eb   = sm + 120520;        // 28672
  float* ho   = sm + 149192;        // 18432
  float* x1   = sm + 167624;        // 18432
  float* x2   = sm + 186056;        // 9216
  float* attw = sm + 195272;        // 536

  unsigned short* wTc1 = wtb;             // 9*128*64
  unsigned short* wTd1 = wtb + 73728;
  unsigned short* wTc2 = wtb + 147456;    // 9*256*128
  unsigned short* wTd2 = wtb + 442368;
  unsigned short* wTt1 = wtb + 737280;    // 9*128*256 (tc1: in256->out128)
  unsigned short* wTt2 = wtb + 1032192;   // 9*64*128  (tc2: in128->out64)

  // 0. all weight transforms (one kernel)
  k_wtrans_all<<<4320, 256, 0, stream>>>(cv1w, dc1w, cv2w, dc2w, tc1w, tc2w, wtb);

  // 1. text pooling
  k_text_pool<<<2, 256, 0, stream>>>(tf, tp, tn);

  // 2. motion branch (uses p0n as scratch; overwritten by vision prep later)
  k_prep<<<4096, 256, 0, stream>>>(mf, mp, p0n);
  k_conv_mfma<64, 128, 64, 64, 1><<<1024, 512, 0, stream>>>(p0n, wTd1, dc1b, q1n);
  k_conv_mfma<128, 256, 32, 32, 2><<<512, 512, 0, stream>>>(q1n, wTd2, dc2b, v2n);
  k_maxln_n<<<16, 1024, 0, stream>>>(v2n, dn);

  // 3. vision branch (p0n kept = bf16(vf+vp); q1n = v1n kept as deconv1 residual)
  k_prep<<<4096, 256, 0, stream>>>(vf, vp, p0n);
  k_conv_mfma<64, 128, 64, 64, 1><<<1024, 512, 0, stream>>>(p0n, wTc1, cv1b, q1n);
  k_conv_mfma<128, 256, 32, 32, 2><<<512, 512, 0, stream>>>(q1n, wTc2, cv2b, v2n);
  k_maxln_n<<<16, 1024, 0, stream>>>(v2n, vn);

  // 4. node features
  k_build_x<<<2, 256, 0, stream>>>(vn, dn, tn, x0);

  // 5. GNN layer 1 (OC=512)
  k_gnn_lin<<<50 * 8, 256, 0, stream>>>(x0, ea1, lin1w, xl, 256, 2048);
  k_gnn_attsm<512><<<1, 256, 0, stream>>>(xl, att1, attw);
  k_edge_agg<512><<<112, 256, 0, stream>>>(xl, attw, eb);
  k_node_agg<512><<<72, 256, 0, stream>>>(attw, eb, ew1, ho);
  k_gn_se<512, 32><<<1, 512, 0, stream>>>(ho, se1w1, se1w2, x1);

  // 6. GNN layer 2 (OC=256)
  k_gnn_lin<<<50 * 4, 256, 0, stream>>>(x1, ea2, lin2w, xl, 512, 1024);
  k_gnn_attsm<256><<<1, 256, 0, stream>>>(xl, att2, attw);
  k_edge_agg<256><<<56, 256, 0, stream>>>(xl, attw, eb);
  k_node_agg<256><<<36, 256, 0, stream>>>(attw, eb, ew2, ho);
  k_gn_se<256, 16><<<1, 512, 0, stream>>>(ho, se2w1, se2w2, x2);

  // 7. observers
  k_obs<<<1, 128, 0, stream>>>(tn, x2, out + 16777216);

  // 8. decoder: t1n = v1n + relu(convT1(v2n + vg[fused])) ; out = bf16(vf+vp) + relu(convT2(t1n))
  k_deconv_mfma<256, 128, 32, 32, 2, true, true><<<512, 256, 0, stream>>>(
      v2n, wTt1, tc1b, q1n, x2, t1n, nullptr);
  k_deconv_mfma<128, 64, 64, 64, 1, false, false><<<1024, 256, 0, stream>>>(
      t1n, wTt2, tc2b, p0n, nullptr, nullptr, out);
}

// Round 6
// 586.210 us; speedup vs baseline: 6.3798x; 1.0013x over previous
//
#include <hip/hip_runtime.h>
#include <hip/hip_bf16.h>
#include <cstddef>
#include <cstdint>

#define DEV_INLINE __device__ __forceinline__

typedef __attribute__((ext_vector_type(8))) short short8;
typedef __attribute__((ext_vector_type(4))) float f32x4;
typedef __attribute__((ext_vector_type(4))) unsigned short us4;

DEV_INLINE unsigned short f2bf(float f) {
  uint32_t u = __builtin_bit_cast(uint32_t, f);
  uint32_t r = (u + 0x7fffu + ((u >> 16) & 1u)) >> 16;
  return (unsigned short)r;
}
DEV_INLINE float bf2f(unsigned short u) {
  return __builtin_bit_cast(float, (uint32_t)u << 16);
}

// Problem constants: BS=2, F=8, C=64, H=128, W=128, HEADS=4
// 36 nodes, 14 hyperedges, 134 incidence entries (segments contiguous per edge)
__device__ __constant__ int c_cs[15] = {0,8,16,32,48,65,66,67,75,83,99,115,132,133,134};
__device__ __constant__ int c_row[134] = {
  0,1,2,3,4,5,6,7,
  8,9,10,11,12,13,14,15,
  0,1,2,3,4,5,6,7,8,9,10,11,12,13,14,15,
  0,1,2,3,4,5,6,7,8,9,10,11,12,13,14,15,
  0,1,2,3,4,5,6,7,8,9,10,11,12,13,14,15,16,
  16,
  17,
  18,19,20,21,22,23,24,25,
  26,27,28,29,30,31,32,33,
  18,19,20,21,22,23,24,25,26,27,28,29,30,31,32,33,
  18,19,20,21,22,23,24,25,26,27,28,29,30,31,32,33,
  18,19,20,21,22,23,24,25,26,27,28,29,30,31,32,33,34,
  34,
  35
};
__device__ __constant__ int c_col[134] = {
  0,0,0,0,0,0,0,0,
  1,1,1,1,1,1,1,1,
  2,2,2,2,2,2,2,2,2,2,2,2,2,2,2,2,
  3,3,3,3,3,3,3,3,3,3,3,3,3,3,3,3,
  4,4,4,4,4,4,4,4,4,4,4,4,4,4,4,4,4,
  5,
  6,
  7,7,7,7,7,7,7,7,
  8,8,8,8,8,8,8,8,
  9,9,9,9,9,9,9,9,9,9,9,9,9,9,9,9,
  10,10,10,10,10,10,10,10,10,10,10,10,10,10,10,10,
  11,11,11,11,11,11,11,11,11,11,11,11,11,11,11,11,11,
  12,
  13
};

// ---------------- text pool ----------------
__global__ void k_text_pool(const float* __restrict__ tf, const float* __restrict__ tp,
                            float* __restrict__ tn) {
  int t = blockIdx.x * blockDim.x + threadIdx.x;
  if (t >= 512) return;
  int b = t >> 8, idx = t & 255;
  int ch = idx >> 2, j = idx & 3;
  const float* p = tf + ((size_t)b * 64 + ch) * 16 + j * 4;
  const float* q = tp + ((size_t)b * 64 + ch) * 16 + j * 4;
  float m = p[0] + q[0];
  m = fmaxf(m, p[1] + q[1]);
  m = fmaxf(m, p[2] + q[2]);
  m = fmaxf(m, p[3] + q[3]);
  tn[(size_t)b * 256 + idx] = m;
}

// ---------------- input prep: (a+b) NCHW fp32 -> NHWC bf16 ----------------
__global__ __launch_bounds__(256) void k_prep(const float* __restrict__ a,
                                              const float* __restrict__ b,
                                              unsigned short* __restrict__ o) {
  int bid = blockIdx.x;
  int xb = bid & 1, y = (bid >> 1) & 127, n = bid >> 8;
  __shared__ unsigned short s[64][68];
  int t = threadIdx.x;
  const size_t base = ((size_t)n * 64) * 16384 + (size_t)y * 128 + xb * 64;
#pragma unroll
  for (int r = 0; r < 16; ++r) {
    int t2 = t + r * 256; int ci = t2 >> 6, x = t2 & 63;
    size_t off = base + (size_t)ci * 16384 + x;
    s[ci][x] = f2bf(a[off] + b[off]);
  }
  __syncthreads();
  unsigned int* op = (unsigned int*)(o + (((size_t)n * 128 + y) * 128 + xb * 64) * 64);
#pragma unroll
  for (int r = 0; r < 8; ++r) {
    int t2 = t + r * 256; int x = t2 >> 5, c2 = (t2 & 31) * 2;
    unsigned int lo = s[c2][x], hi = s[c2 + 1][x];
    op[x * 32 + (c2 >> 1)] = lo | (hi << 16);
  }
}

// ---------------- all weight transforms -> wT[tap][co][ci] bf16, one kernel ----------
__global__ void k_wtrans_all(const float* __restrict__ cv1w, const float* __restrict__ dc1w,
                             const float* __restrict__ cv2w, const float* __restrict__ dc2w,
                             const float* __restrict__ tc1w, const float* __restrict__ tc2w,
                             unsigned short* __restrict__ wtb) {
  int idx = blockIdx.x * 256 + threadIdx.x;
  const float* src; int off, lci, lco; bool tra;
  if (idx < 73728)        { src = cv1w; off = 0;       lci = 6; lco = 7; tra = false; }
  else if (idx < 147456)  { src = dc1w; off = 73728;   lci = 6; lco = 7; tra = false; }
  else if (idx < 442368)  { src = cv2w; off = 147456;  lci = 7; lco = 8; tra = false; }
  else if (idx < 737280)  { src = dc2w; off = 442368;  lci = 7; lco = 8; tra = false; }
  else if (idx < 1032192) { src = tc1w; off = 737280;  lci = 8; lco = 7; tra = true;  }
  else if (idx < 1105920) { src = tc2w; off = 1032192; lci = 7; lco = 6; tra = true;  }
  else return;
  int l = idx - off;
  int ci = l & ((1 << lci) - 1);
  int r = l >> lci;
  int co = r & ((1 << lco) - 1);
  int tap = r >> lco;
  size_t si = tra ? (((size_t)ci << lco) + co) * 9 + tap
                  : (((size_t)co << lci) + ci) * 9 + tap;
  wtb[idx] = f2bf(src[si]);
}

// ---------------- Conv2d k3 s2 p1 + bias + ReLU via bf16 MFMA ----------------
// Block: 512 thr = 8 waves (4x2); 128 co x 64 pixels per block.
template<int CI, int CO, int HO, int WO, int ROUT>
__global__ __launch_bounds__(512) void k_conv_mfma(
    const unsigned short* __restrict__ in,   // NHWC bf16 [N][2HO][2WO][CI]
    const unsigned short* __restrict__ wT,   // [9][CO][CI] bf16
    const float* __restrict__ bias,
    unsigned short* __restrict__ outn) {     // NHWC bf16 [N][HO][WO][CO]
  constexpr int HIN = HO * 2, WIN = WO * 2;
  constexpr int XHP = WO + 2;
  constexpr int R = 2 * ROUT + 1;
  constexpr int NPOS = R * 2 * XHP;
  constexpr int CB = CO / 128;
  constexpr int OB = HO / ROUT;
  __shared__ short8 sIn[NPOS * 5];
  int bid = blockIdx.x;
  int cb = bid % CB; bid /= CB;
  int oyb = bid % OB; int n = bid / OB;
  int tid = threadIdx.x;
  int wid = tid >> 6, lane = tid & 63;
  int wm = wid >> 1, wn = wid & 1;   // wm 0..3, wn 0..1
  int llo = lane & 15, lhi = lane >> 4;
  f32x4 acc[2][2] = {};
  const int iy0 = oyb * (2 * ROUT) - 1;
  for (int cs = 0; cs < CI / 32; ++cs) {
    for (int i = tid; i < NPOS * 4; i += 512) {
      int c = i & 3, q = i >> 2;
      int xh = q % XHP; int q2 = q / XHP;
      int p = q2 & 1, l = q2 >> 1;
      int x = 2 * xh + p - 1;
      int iy = iy0 + l;
      short8 v = {};
      if (x >= 0 && x < WIN && iy >= 0 && iy < HIN)
        v = *reinterpret_cast<const short8*>(in + ((((size_t)n * HIN + iy) * WIN + x) * CI + cs * 32 + c * 8));
      sIn[q * 5 + c] = v;
    }
    __syncthreads();
#pragma unroll
    for (int tap = 0; tap < 9; ++tap) {
      const int ky = tap / 3, kx = tap % 3;
      short8 afr[2], bfr[2];
#pragma unroll
      for (int m = 0; m < 2; ++m) {
        int co = cb * 128 + wm * 32 + m * 16 + llo;
        afr[m] = *reinterpret_cast<const short8*>(wT + (((size_t)tap * CO + co) * CI + cs * 32 + lhi * 8));
      }
#pragma unroll
      for (int n2 = 0; n2 < 2; ++n2) {
        int pix = wn * 32 + n2 * 16 + llo;
        int oyl = (ROUT == 2) ? (pix >> 5) : 0;
        int ox = pix - oyl * WO;
        int lrow = 2 * oyl + ky;
        int pos = (lrow * 2 + (kx & 1)) * XHP + ox + (kx >> 1);
        bfr[n2] = sIn[pos * 5 + lhi];
      }
#pragma unroll
      for (int m = 0; m < 2; ++m)
#pragma unroll
        for (int n2 = 0; n2 < 2; ++n2)
          acc[m][n2] = __builtin_amdgcn_mfma_f32_16x16x32_bf16(afr[m], bfr[n2], acc[m][n2], 0, 0, 0);
    }
    __syncthreads();
  }
#pragma unroll
  for (int m = 0; m < 2; ++m) {
    int co0 = cb * 128 + wm * 32 + m * 16 + lhi * 4;
    f32x4 bv = *reinterpret_cast<const f32x4*>(bias + co0);
#pragma unroll
    for (int n2 = 0; n2 < 2; ++n2) {
      int pix = wn * 32 + n2 * 16 + llo;
      int oyl = (ROUT == 2) ? (pix >> 5) : 0;
      int ox = pix - oyl * WO;
      int oy = oyb * ROUT + oyl;
      us4 pk;
      pk[0] = f2bf(fmaxf(acc[m][n2][0] + bv[0], 0.f));
      pk[1] = f2bf(fmaxf(acc[m][n2][1] + bv[1], 0.f));
      pk[2] = f2bf(fmaxf(acc[m][n2][2] + bv[2], 0.f));
      pk[3] = f2bf(fmaxf(acc[m][n2][3] + bv[3], 0.f));
      *reinterpret_cast<us4*>(outn + ((((size_t)n * HO + oy) * WO + ox) * CO + co0)) = pk;
    }
  }
}

// ---------------- ConvTranspose2d k3 s2 p1 op1 via bf16 MFMA (4 parity classes) ------
// OBF: bf16 NHWC out with bf16 residual. !OBF: fp32 NCHW out (float2 stores) with
// bf16 NHWC residual. GADD: fuse per-frame channel-broadcast add into input staging.
template<int CI, int CO, int Hi, int Wi, int QR, bool OBF, bool GADD>
__global__ __launch_bounds__(256) void k_deconv_mfma(
    const unsigned short* __restrict__ in,   // NHWC bf16 [N][Hi][Wi][CI]
    const unsigned short* __restrict__ wT,   // [9][CO][CI] bf16 (w[ci][co][ky][kx])
    const float* __restrict__ bias,
    const unsigned short* __restrict__ resn, // NHWC bf16 residual
    const float* __restrict__ gsrc,          // GADD: x2 node features (per-frame 256ch)
    unsigned short* __restrict__ outn,       // NHWC bf16 [N][2Hi][2Wi][CO]
    float* __restrict__ outc) {              // NCHW fp32
  constexpr int QC = 64 / QR;
  constexpr int WP = Wi + 1;
  constexpr int NPOS = (QR + 1) * WP;
  constexpr int CB = CO / 64;
  constexpr int OB = Hi / QR;
  constexpr int Ho = Hi * 2, Wo = Wi * 2;
  __shared__ short8 sIn[NPOS * 5];
  int bid = blockIdx.x;
  int cb = bid % CB; bid /= CB;
  int oyb = bid % OB; int n = bid / OB;
  int tid = threadIdx.x;
  int wid = tid >> 6, lane = tid & 63;
  int wm = wid >> 1, wn = wid & 1;
  int llo = lane & 15, lhi = lane >> 4;
  int qy0 = oyb * QR;
  const float* g = nullptr;
  if constexpr (GADD) g = gsrc + ((size_t)((n >> 3) * 18 + (n & 7))) * 256;
  f32x4 acc[4][2][2] = {};
  constexpr int tap_p[9] = {3,2,3,1,0,1,3,2,3};
  constexpr int tap_b[9] = {3,2,2,1,0,0,1,0,0};
  for (int cs = 0; cs < CI / 32; ++cs) {
    for (int i = tid; i < NPOS * 4; i += 256) {
      int c = i & 3, q = i >> 2;
      int x = q % WP, l = q / WP;
      int iy = qy0 + l;
      short8 v = {};
      if (x < Wi && iy < Hi) {
        v = *reinterpret_cast<const short8*>(in + (((size_t)(n * Hi + iy) * Wi + x) * CI + cs * 32 + c * 8));
        if constexpr (GADD) {
#pragma unroll
          for (int j = 0; j < 8; ++j) {
            float fv = bf2f((unsigned short)v[j]) + g[cs * 32 + c * 8 + j];
            v[j] = (short)f2bf(fv);
          }
        }
      }
      sIn[q * 5 + c] = v;
    }
    __syncthreads();
    short8 bfr[2][4];
#pragma unroll
    for (int n2 = 0; n2 < 2; ++n2) {
      int pix = wn * 32 + n2 * 16 + llo;
      int qyl = pix / QC, qx = pix % QC;
#pragma unroll
      for (int bs = 0; bs < 4; ++bs) {
        int pos = (qyl + (bs >> 1)) * WP + qx + (bs & 1);
        bfr[n2][bs] = sIn[pos * 5 + lhi];
      }
    }
#pragma unroll
    for (int tap = 0; tap < 9; ++tap) {
      short8 afr[2];
#pragma unroll
      for (int m = 0; m < 2; ++m) {
        int co = cb * 64 + wm * 32 + m * 16 + llo;
        afr[m] = *reinterpret_cast<const short8*>(wT + (((size_t)tap * CO + co) * CI + cs * 32 + lhi * 8));
      }
#pragma unroll
      for (int m = 0; m < 2; ++m)
#pragma unroll
        for (int n2 = 0; n2 < 2; ++n2)
          acc[tap_p[tap]][m][n2] = __builtin_amdgcn_mfma_f32_16x16x32_bf16(
              afr[m], bfr[n2][tap_b[tap]], acc[tap_p[tap]][m][n2], 0, 0, 0);
    }
    __syncthreads();
  }
#pragma unroll
  for (int m = 0; m < 2; ++m) {
    int co0 = cb * 64 + wm * 32 + m * 16 + lhi * 4;
    f32x4 bv = *reinterpret_cast<const f32x4*>(bias + co0);
#pragma unroll
    for (int n2 = 0; n2 < 2; ++n2) {
      int pix = wn * 32 + n2 * 16 + llo;
      int qyl = pix / QC, qx = pix % QC;
      int qy = qy0 + qyl;
      if constexpr (OBF) {
#pragma unroll
        for (int p = 0; p < 4; ++p) {
          int oy = 2 * qy + (p >> 1);
          int ox = 2 * qx + (p & 1);
          size_t ad = ((size_t)(n * Ho + oy) * Wo + ox) * CO + co0;
          us4 r = *reinterpret_cast<const us4*>(resn + ad);
          us4 pk;
#pragma unroll
          for (int c = 0; c < 4; ++c)
            pk[c] = f2bf(bf2f(r[c]) + fmaxf(acc[p][m][n2][c] + bv[c], 0.f));
          *reinterpret_cast<us4*>(outn + ad) = pk;
        }
      } else {
        int qx2 = 2 * qx;
#pragma unroll
        for (int dy = 0; dy < 2; ++dy) {
          int oy = 2 * qy + dy;
          size_t rb = ((size_t)(n * Ho + oy) * Wo + qx2) * CO + co0;
          us4 r0 = *reinterpret_cast<const us4*>(resn + rb);
          us4 r1 = *reinterpret_cast<const us4*>(resn + rb + CO);
#pragma unroll
          for (int c = 0; c < 4; ++c) {
            float2 st;
            st.x = bf2f(r0[c]) + fmaxf(acc[dy * 2][m][n2][c] + bv[c], 0.f);
            st.y = bf2f(r1[c]) + fmaxf(acc[dy * 2 + 1][m][n2][c] + bv[c], 0.f);
            *reinterpret_cast<float2*>(outc + ((size_t)(n * CO + co0 + c) * Ho + oy) * Wo + qx2) = st;
          }
        }
      }
    }
  }
}

// ---------------- spatial max (NHWC bf16) + LayerNorm over 256 channels ----------------
__global__ __launch_bounds__(1024) void k_maxln_n(const unsigned short* __restrict__ x,
                                                  float* __restrict__ out) {
  int n = blockIdx.x, t = threadIdx.x;
  int ch = t & 255, pg = t >> 8;
  const unsigned short* base = x + (size_t)n * 1024 * 256 + ch;
  float m = -1e30f;
  for (int p = pg; p < 1024; p += 4)
    m = fmaxf(m, bf2f(base[(size_t)p * 256]));
  __shared__ float sm4[4][256];
  __shared__ float r1[256], r2[256];
  sm4[pg][ch] = m;
  __syncthreads();
  float mv = fmaxf(fmaxf(sm4[0][ch], sm4[1][ch]), fmaxf(sm4[2][ch], sm4[3][ch]));
  if (pg == 0) r1[ch] = mv;
  __syncthreads();
  for (int s = 128; s > 0; s >>= 1) { if (t < s) r1[t] += r1[t + s]; __syncthreads(); }
  float mu = r1[0] * (1.f / 256.f);
  float d = mv - mu;
  if (pg == 0) r2[ch] = d * d;
  __syncthreads();
  for (int s = 128; s > 0; s >>= 1) { if (t < s) r2[t] += r2[t + s]; __syncthreads(); }
  if (pg == 0) out[(size_t)n * 256 + ch] = d * rsqrtf(r2[0] * (1.f / 256.f) + 1e-5f);
}

// ---------------- build node features ----------------
__global__ void k_build_x(const float* __restrict__ vn, const float* __restrict__ dn,
                          const float* __restrict__ tn, float* __restrict__ x0) {
  int b = blockIdx.x, ch = threadIdx.x;
  float s = 0.f;
  for (int f = 0; f < 8; ++f) {
    float vv = vn[((size_t)b * 8 + f) * 256 + ch];
    float dd = dn[((size_t)b * 8 + f) * 256 + ch];
    s += vv + dd;
    x0[((size_t)b * 18 + f) * 256 + ch] = vv;
    x0[((size_t)b * 18 + 8 + f) * 256 + ch] = dd;
  }
  float tv = tn[(size_t)b * 256 + ch];
  x0[((size_t)b * 18 + 16) * 256 + ch] = tv;
  x0[((size_t)b * 18 + 17) * 256 + ch] = tv + s * (1.f / 8.f);
}

// ---------------- GNN linear ----------------
__global__ __launch_bounds__(256) void k_gnn_lin(
    const float* __restrict__ x, const float* __restrict__ ea,
    const float* __restrict__ w, float* __restrict__ y, int K, int M) {
  int chunks = M >> 8;
  int r = blockIdx.x / chunks;
  int ob = (blockIdx.x % chunks) * 256 + threadIdx.x;
  const float* src = (r < 36) ? (x + (size_t)r * K) : (ea + (size_t)(r - 36) * K);
  __shared__ __align__(16) float sxr[512];
  for (int k = threadIdx.x; k < K; k += 256) sxr[k] = src[k];
  __syncthreads();
  const float4* w4 = reinterpret_cast<const float4*>(w + (size_t)ob * K);
  const float4* x4 = reinterpret_cast<const float4*>(sxr);
  float acc = 0.f;
  int k4 = K >> 2;
  for (int k = 0; k < k4; ++k) {
    float4 a = x4[k], b = w4[k];
    acc += a.x * b.x + a.y * b.y + a.z * b.z + a.w * b.w;
  }
  y[(size_t)r * M + ob] = acc;
}

// ---------------- fused attention dots + logits + segment softmax -> attw(134,4) ------
template<int OC>
__global__ __launch_bounds__(256) void k_gnn_attsm(
    const float* __restrict__ y, const float* __restrict__ att,
    float* __restrict__ attw) {
  int t = threadIdx.x;
  __shared__ float sx_s[144], seb_s[60];
  __shared__ float a_s[536];
  if (t < 200) {
    int r = t >> 2, h = t & 3;
    const float4* row = reinterpret_cast<const float4*>(y + ((size_t)r * 4 + h) * OC);
    const float4* ar = reinterpret_cast<const float4*>(att + (size_t)h * 2 * OC + (r < 36 ? 0 : OC));
    float s = 0.f;
#pragma unroll 4
    for (int k = 0; k < OC / 4; ++k) {
      float4 a = row[k], b = ar[k];
      s += a.x * b.x + a.y * b.y + a.z * b.z + a.w * b.w;
    }
    if (r < 36) sx_s[r * 4 + h] = s; else seb_s[(r - 36) * 4 + h] = s;
  }
  __syncthreads();
  for (int idx = t; idx < 536; idx += 256) {
    int i = idx >> 2, h = idx & 3;
    float v = sx_s[c_row[i] * 4 + h] + seb_s[c_col[i] * 4 + h];
    a_s[idx] = (v > 0.f) ? v : 0.2f * v;
  }
  __syncthreads();
  if (t < 56) {
    int c = t >> 2, h = t & 3;
    int st = c_cs[c], en = c_cs[c + 1];
    float m = -1e30f;
    for (int i = st; i < en; ++i) m = fmaxf(m, a_s[i * 4 + h]);
    float s = 0.f;
    for (int i = st; i < en; ++i) { float e = __expf(a_s[i * 4 + h] - m); a_s[i * 4 + h] = e; s += e; }
    float inv = 1.f / (s + 1e-16f);
    for (int i = st; i < en; ++i) a_s[i * 4 + h] *= inv;
  }
  __syncthreads();
  for (int idx = t; idx < 536; idx += 256) attw[idx] = a_s[idx];
}

// ---------------- edge aggregation ----------------
template<int OC>
__global__ __launch_bounds__(256) void k_edge_agg(
    const float* __restrict__ y, const float* __restrict__ attw,
    float* __restrict__ eb) {
  int idx = blockIdx.x * 256 + threadIdx.x;
  if (idx >= 14 * 4 * OC) return;
  int ch = idx % OC;
  int h = (idx / OC) & 3;
  int c = idx / (4 * OC);
  int st = c_cs[c], en = c_cs[c + 1];
  float s = 0.f;
  for (int i = st; i < en; ++i)
    s += attw[i * 4 + h] * y[(size_t)c_row[i] * (4 * OC) + h * OC + ch];
  eb[idx] = s * (1.f / (float)(en - st));
}

// ---------------- node aggregation ----------------
template<int OC>
__global__ __launch_bounds__(256) void k_node_agg(
    const float* __restrict__ attw, const float* __restrict__ eb,
    const float* __restrict__ ew, float* __restrict__ ho) {
  int idx = blockIdx.x * 256 + threadIdx.x;
  if (idx >= 36 * OC) return;
  int ch = idx % OC;
  int node = idx / OC;
  int b = node / 18, ln = node % 18;
  int ncols, cols[4], gis[4];
  if (ln < 16) {
    ncols = 4;
    cols[0] = b * 7 + (ln < 8 ? 0 : 1); gis[0] = b * 67 + ln;
    cols[1] = b * 7 + 2; gis[1] = b * 67 + 16 + ln;
    cols[2] = b * 7 + 3; gis[2] = b * 67 + 32 + ln;
    cols[3] = b * 7 + 4; gis[3] = b * 67 + 48 + ln;
  } else if (ln == 16) {
    ncols = 2;
    cols[0] = b * 7 + 4; gis[0] = b * 67 + 64;
    cols[1] = b * 7 + 5; gis[1] = b * 67 + 65;
    cols[2] = cols[3] = 0; gis[2] = gis[3] = 0;
  } else {
    ncols = 1;
    cols[0] = b * 7 + 6; gis[0] = b * 67 + 66;
    cols[1] = cols[2] = cols[3] = 0; gis[1] = gis[2] = gis[3] = 0;
  }
  float dsum = 0.f;
#pragma unroll
  for (int k = 0; k < 4; ++k) if (k < ncols) dsum += ew[cols[k]];
  float D = dsum > 0.f ? 1.f / dsum : 0.f;
  float s = 0.f;
#pragma unroll
  for (int k = 0; k < 4; ++k) {
    if (k < ncols) {
#pragma unroll
      for (int h = 0; h < 4; ++h)
        s += attw[gis[k] * 4 + h] * eb[((size_t)cols[k] * 4 + h) * OC + ch];
    }
  }
  ho[idx] = fmaxf(0.25f * D * s, 0.f);
}

// ---------------- GroupNorm(32) + SE layer ----------------
template<int C, int Cr>
__global__ __launch_bounds__(512) void k_gn_se(
    const float* __restrict__ hin, const float* __restrict__ w1,
    const float* __restrict__ w2, float* __restrict__ x) {
  int t = threadIdx.x;
  constexpr int gs = C >> 5;
  for (int idx = t; idx < 36 * 32; idx += 512) {
    int node = idx >> 5, g = idx & 31;
    const float* p = hin + (size_t)node * C + g * gs;
    float s = 0.f, s2 = 0.f;
#pragma unroll
    for (int k = 0; k < gs; ++k) { float v = p[k]; s += v; s2 += v * v; }
    float mu = s * (1.f / gs);
    float var = s2 * (1.f / gs) - mu * mu;
    float inv = rsqrtf(fmaxf(var, 0.f) + 1e-5f);
    float* q = x + (size_t)node * C + g * gs;
#pragma unroll
    for (int k = 0; k < gs; ++k) q[k] = (p[k] - mu) * inv;
  }
  __threadfence_block();
  __syncthreads();
  __shared__ float smean[C];
  __shared__ float spart[Cr][17];
  __shared__ float shid[Cr];
  __shared__ float sscale[C];
  if (t < C) {
    float s = 0.f;
    for (int nn = 0; nn < 36; ++nn) s += x[(size_t)nn * C + t];
    smean[t] = s * (1.f / 36.f);
  }
  __syncthreads();
  if (t < Cr * 16) {
    int hid = t >> 4, sub = t & 15;
    constexpr int CH = C / 16;
    float s = 0.f;
#pragma unroll
    for (int k = 0; k < CH; ++k)
      s += w1[(size_t)hid * C + sub * CH + k] * smean[sub * CH + k];
    spart[hid][sub] = s;
  }
  __syncthreads();
  if (t < Cr) {
    float s = 0.f;
#pragma unroll
    for (int k = 0; k < 16; ++k) s += spart[t][k];
    shid[t] = fmaxf(s, 0.f);
  }
  __syncthreads();
  if (t < C) {
    float s = 0.f;
#pragma unroll
    for (int k = 0; k < Cr; ++k) s += w2[(size_t)t * Cr + k] * shid[k];
    sscale[t] = 1.f / (1.f + __expf(-s));
  }
  __syncthreads();
  for (int idx = t; idx < 36 * C; idx += 512) x[idx] *= sscale[idx % C];
}

// ---------------- observers ----------------
__global__ void k_obs(const float* __restrict__ tn, const float* __restrict__ x2,
                      float* __restrict__ out) {
  int t = threadIdx.x;
  if (t >= 128) return;
  int b = t >> 6, ch = t & 63;
  const float* a = tn + (size_t)b * 256 + ch * 4;
  const float* c = x2 + ((size_t)b * 18 + 17) * 256 + ch * 4;
  float m = a[0] + c[0];
  m = fmaxf(m, a[1] + c[1]);
  m = fmaxf(m, a[2] + c[2]);
  m = fmaxf(m, a[3] + c[3]);
  out[b * 64 + ch] = m;
}

extern "C" void kernel_launch(void* const* d_in, const int* in_sizes, int n_in,
                              void* d_out, int out_size, void* d_ws, size_t ws_size,
                              hipStream_t stream) {
  (void)in_sizes; (void)n_in; (void)out_size; (void)ws_size;
  const float* vf    = (const float*)d_in[0];
  const float* vp    = (const float*)d_in[1];
  const float* mf    = (const float*)d_in[2];
  const float* mp    = (const float*)d_in[3];
  const float* tf    = (const float*)d_in[4];
  const float* tp    = (const float*)d_in[5];
  const float* cv1w  = (const float*)d_in[6];
  const float* cv1b  = (const float*)d_in[7];
  const float* cv2w  = (const float*)d_in[8];
  const float* cv2b  = (const float*)d_in[9];
  const float* dc1w  = (const float*)d_in[10];
  const float* dc1b  = (const float*)d_in[11];
  const float* dc2w  = (const float*)d_in[12];
  const float* dc2b  = (const float*)d_in[13];
  const float* tc1w  = (const float*)d_in[14];
  const float* tc1b  = (const float*)d_in[15];
  const float* tc2w  = (const float*)d_in[16];
  const float* tc2b  = (const float*)d_in[17];
  const float* lin1w = (const float*)d_in[18];
  const float* att1  = (const float*)d_in[19];
  const float* lin2w = (const float*)d_in[20];
  const float* att2  = (const float*)d_in[21];
  const float* ew1   = (const float*)d_in[22];
  const float* ew2   = (const float*)d_in[23];
  const float* ea1   = (const float*)d_in[24];
  const float* ea2   = (const float*)d_in[25];
  const float* se1w1 = (const float*)d_in[26];
  const float* se1w2 = (const float*)d_in[27];
  const float* se2w1 = (const float*)d_in[28];
  const float* se2w2 = (const float*)d_in[29];

  float* ws  = (float*)d_ws;
  float* out = (float*)d_out;

  // workspace layout (float units)
  unsigned short* p0n = (unsigned short*)(ws);             // 16x128x128x64 bf16 (vf+vp NHWC, kept for deconv2 residual)
  unsigned short* q1n = (unsigned short*)(ws + 8388608);   // 16x64x64x128 bf16 (d1n/v1n)
  unsigned short* t1n = (unsigned short*)(ws + 12582912);  // 16x64x64x128 bf16
  unsigned short* v2n = (unsigned short*)(ws + 16777216);  // 16x32x32x256 bf16 (d2n/v2n)
  unsigned short* wtb = (unsigned short*)(ws + 18874368);  // 1,105,920 bf16
  float* sm   = ws + 19427328;
  float* tn   = sm;                 // 512
  float* vn   = sm + 512;           // 4096
  float* dn   = sm + 4608;          // 4096
  float* x0   = sm + 8704;          // 9216
  float* xl   = sm + 17920;         // 102400
  float* eb   = sm + 120520;        // 28672
  float* ho   = sm + 149192;        // 18432
  float* x1   = sm + 167624;        // 18432
  float* x2   = sm + 186056;        // 9216
  float* attw = sm + 195272;        // 536

  unsigned short* wTc1 = wtb;             // 9*128*64
  unsigned short* wTd1 = wtb + 73728;
  unsigned short* wTc2 = wtb + 147456;    // 9*256*128
  unsigned short* wTd2 = wtb + 442368;
  unsigned short* wTt1 = wtb + 737280;    // 9*128*256 (tc1: in256->out128)
  unsigned short* wTt2 = wtb + 1032192;   // 9*64*128  (tc2: in128->out64)

  // 0. all weight transforms (one kernel)
  k_wtrans_all<<<4320, 256, 0, stream>>>(cv1w, dc1w, cv2w, dc2w, tc1w, tc2w, wtb);

  // 1. text pooling
  k_text_pool<<<2, 256, 0, stream>>>(tf, tp, tn);

  // 2. motion branch (uses p0n as scratch; overwritten by vision prep later)
  k_prep<<<4096, 256, 0, stream>>>(mf, mp, p0n);
  k_conv_mfma<64, 128, 64, 64, 1><<<1024, 512, 0, stream>>>(p0n, wTd1, dc1b, q1n);
  k_conv_mfma<128, 256, 32, 32, 2><<<512, 512, 0, stream>>>(q1n, wTd2, dc2b, v2n);
  k_maxln_n<<<16, 1024, 0, stream>>>(v2n, dn);

  // 3. vision branch (p0n kept = bf16(vf+vp); q1n = v1n kept as deconv1 residual)
  k_prep<<<4096, 256, 0, stream>>>(vf, vp, p0n);
  k_conv_mfma<64, 128, 64, 64, 1><<<1024, 512, 0, stream>>>(p0n, wTc1, cv1b, q1n);
  k_conv_mfma<128, 256, 32, 32, 2><<<512, 512, 0, stream>>>(q1n, wTc2, cv2b, v2n);
  k_maxln_n<<<16, 1024, 0, stream>>>(v2n, vn);

  // 4. node features
  k_build_x<<<2, 256, 0, stream>>>(vn, dn, tn, x0);

  // 5. GNN layer 1 (OC=512)
  k_gnn_lin<<<50 * 8, 256, 0, stream>>>(x0, ea1, lin1w, xl, 256, 2048);
  k_gnn_attsm<512><<<1, 256, 0, stream>>>(xl, att1, attw);
  k_edge_agg<512><<<112, 256, 0, stream>>>(xl, attw, eb);
  k_node_agg<512><<<72, 256, 0, stream>>>(attw, eb, ew1, ho);
  k_gn_se<512, 32><<<1, 512, 0, stream>>>(ho, se1w1, se1w2, x1);

  // 6. GNN layer 2 (OC=256)
  k_gnn_lin<<<50 * 4, 256, 0, stream>>>(x1, ea2, lin2w, xl, 512, 1024);
  k_gnn_attsm<256><<<1, 256, 0, stream>>>(xl, att2, attw);
  k_edge_agg<256><<<56, 256, 0, stream>>>(xl, attw, eb);
  k_node_agg<256><<<36, 256, 0, stream>>>(attw, eb, ew2, ho);
  k_gn_se<256, 16><<<1, 512, 0, stream>>>(ho, se2w1, se2w2, x2);

  // 7. observers
  k_obs<<<1, 128, 0, stream>>>(tn, x2, out + 16777216);

  // 8. decoder: t1n = v1n + relu(convT1(v2n + vg[fused])) ; out = bf16(vf+vp) + relu(convT2(t1n))
  k_deconv_mfma<256, 128, 32, 32, 2, true, true><<<512, 256, 0, stream>>>(
      v2n, wTt1, tc1b, q1n, x2, t1n, nullptr);
  k_deconv_mfma<128, 64, 64, 64, 1, false, false><<<1024, 256, 0, stream>>>(
      t1n, wTt2, tc2b, p0n, nullptr, nullptr, out);
}

// Round 7
// 522.723 us; speedup vs baseline: 7.1547x; 1.1215x over previous
//
#include <hip/hip_runtime.h>
#include <hip/hip_bf16.h>
#include <cstddef>
#include <cstdint>

#define DEV_INLINE __device__ __forceinline__

typedef __attribute__((ext_vector_type(8))) short short8;
typedef __attribute__((ext_vector_type(4))) float f32x4;
typedef __attribute__((ext_vector_type(4))) unsigned short us4;

DEV_INLINE unsigned short f2bf(float f) {
  uint32_t u = __builtin_bit_cast(uint32_t, f);
  uint32_t r = (u + 0x7fffu + ((u >> 16) & 1u)) >> 16;
  return (unsigned short)r;
}
DEV_INLINE float bf2f(unsigned short u) {
  return __builtin_bit_cast(float, (uint32_t)u << 16);
}

// Problem constants: BS=2, F=8, C=64, H=128, W=128, HEADS=4
__device__ __constant__ int c_cs[15] = {0,8,16,32,48,65,66,67,75,83,99,115,132,133,134};
__device__ __constant__ int c_row[134] = {
  0,1,2,3,4,5,6,7,
  8,9,10,11,12,13,14,15,
  0,1,2,3,4,5,6,7,8,9,10,11,12,13,14,15,
  0,1,2,3,4,5,6,7,8,9,10,11,12,13,14,15,
  0,1,2,3,4,5,6,7,8,9,10,11,12,13,14,15,16,
  16,
  17,
  18,19,20,21,22,23,24,25,
  26,27,28,29,30,31,32,33,
  18,19,20,21,22,23,24,25,26,27,28,29,30,31,32,33,
  18,19,20,21,22,23,24,25,26,27,28,29,30,31,32,33,
  18,19,20,21,22,23,24,25,26,27,28,29,30,31,32,33,34,
  34,
  35
};
__device__ __constant__ int c_col[134] = {
  0,0,0,0,0,0,0,0,
  1,1,1,1,1,1,1,1,
  2,2,2,2,2,2,2,2,2,2,2,2,2,2,2,2,
  3,3,3,3,3,3,3,3,3,3,3,3,3,3,3,3,
  4,4,4,4,4,4,4,4,4,4,4,4,4,4,4,4,4,
  5,
  6,
  7,7,7,7,7,7,7,7,
  8,8,8,8,8,8,8,8,
  9,9,9,9,9,9,9,9,9,9,9,9,9,9,9,9,
  10,10,10,10,10,10,10,10,10,10,10,10,10,10,10,10,
  11,11,11,11,11,11,11,11,11,11,11,11,11,11,11,11,11,
  12,
  13
};

// ---------------- text pool ----------------
__global__ void k_text_pool(const float* __restrict__ tf, const float* __restrict__ tp,
                            float* __restrict__ tn) {
  int t = blockIdx.x * blockDim.x + threadIdx.x;
  if (t >= 512) return;
  int b = t >> 8, idx = t & 255;
  int ch = idx >> 2, j = idx & 3;
  const float* p = tf + ((size_t)b * 64 + ch) * 16 + j * 4;
  const float* q = tp + ((size_t)b * 64 + ch) * 16 + j * 4;
  float m = p[0] + q[0];
  m = fmaxf(m, p[1] + q[1]);
  m = fmaxf(m, p[2] + q[2]);
  m = fmaxf(m, p[3] + q[3]);
  tn[(size_t)b * 256 + idx] = m;
}

// ---------------- input prep: (a+b) NCHW fp32 -> NHWC bf16 ----------------
__global__ __launch_bounds__(256) void k_prep(const float* __restrict__ a,
                                              const float* __restrict__ b,
                                              unsigned short* __restrict__ o) {
  int bid = blockIdx.x;
  int xb = bid & 1, y = (bid >> 1) & 127, n = bid >> 8;
  __shared__ unsigned short s[64][68];
  int t = threadIdx.x;
  const size_t base = ((size_t)n * 64) * 16384 + (size_t)y * 128 + xb * 64;
#pragma unroll
  for (int r = 0; r < 16; ++r) {
    int t2 = t + r * 256; int ci = t2 >> 6, x = t2 & 63;
    size_t off = base + (size_t)ci * 16384 + x;
    s[ci][x] = f2bf(a[off] + b[off]);
  }
  __syncthreads();
  unsigned int* op = (unsigned int*)(o + (((size_t)n * 128 + y) * 128 + xb * 64) * 64);
#pragma unroll
  for (int r = 0; r < 8; ++r) {
    int t2 = t + r * 256; int x = t2 >> 5, c2 = (t2 & 31) * 2;
    unsigned int lo = s[c2][x], hi = s[c2 + 1][x];
    op[x * 32 + (c2 >> 1)] = lo | (hi << 16);
  }
}

// ---------------- all weight transforms -> wT[tap][co][ci] bf16, one kernel ----------
__global__ void k_wtrans_all(const float* __restrict__ cv1w, const float* __restrict__ dc1w,
                             const float* __restrict__ cv2w, const float* __restrict__ dc2w,
                             const float* __restrict__ tc1w, const float* __restrict__ tc2w,
                             unsigned short* __restrict__ wtb) {
  int idx = blockIdx.x * 256 + threadIdx.x;
  const float* src; int off, lci, lco; bool tra;
  if (idx < 73728)        { src = cv1w; off = 0;       lci = 6; lco = 7; tra = false; }
  else if (idx < 147456)  { src = dc1w; off = 73728;   lci = 6; lco = 7; tra = false; }
  else if (idx < 442368)  { src = cv2w; off = 147456;  lci = 7; lco = 8; tra = false; }
  else if (idx < 737280)  { src = dc2w; off = 442368;  lci = 7; lco = 8; tra = false; }
  else if (idx < 1032192) { src = tc1w; off = 737280;  lci = 8; lco = 7; tra = true;  }
  else if (idx < 1105920) { src = tc2w; off = 1032192; lci = 7; lco = 6; tra = true;  }
  else return;
  int l = idx - off;
  int ci = l & ((1 << lci) - 1);
  int r = l >> lci;
  int co = r & ((1 << lco) - 1);
  int tap = r >> lco;
  size_t si = tra ? (((size_t)ci << lco) + co) * 9 + tap
                  : (((size_t)co << lci) + ci) * 9 + tap;
  wtb[idx] = f2bf(src[si]);
}

// ---------------- Conv2d k3 s2 p1 + bias + ReLU via bf16 MFMA (pipelined) ----------
// Block: 512 thr = 8 waves (4x2); 128 co x 64 pixels per block.
template<int CI, int CO, int HO, int WO, int ROUT>
__global__ __launch_bounds__(512) void k_conv_mfma(
    const unsigned short* __restrict__ in,   // NHWC bf16 [N][2HO][2WO][CI]
    const unsigned short* __restrict__ wT,   // [9][CO][CI] bf16
    const float* __restrict__ bias,
    unsigned short* __restrict__ outn) {     // NHWC bf16 [N][HO][WO][CO]
  constexpr int HIN = HO * 2, WIN = WO * 2;
  constexpr int XHP = WO + 2;
  constexpr int R = 2 * ROUT + 1;
  constexpr int NPOS = R * 2 * XHP;
  constexpr int NCH = NPOS * 4;
  constexpr int NCS = CI / 32;
  constexpr int KIT = (NCH + 511) / 512;
  constexpr int CB = CO / 128;
  constexpr int OB = HO / ROUT;
  __shared__ short8 sIn[NPOS * 5];
  int bid = blockIdx.x;
  int cb = bid % CB; bid /= CB;
  int oyb = bid % OB; int n = bid / OB;
  int tid = threadIdx.x;
  int wid = tid >> 6, lane = tid & 63;
  int wm = wid >> 1, wn = wid & 1;
  int llo = lane & 15, lhi = lane >> 4;
  f32x4 acc[2][2] = {};
  const int iy0 = oyb * (2 * ROUT) - 1;
  short8 rv[KIT];
  auto loadr = [&](int cs) {
#pragma unroll
    for (int k = 0; k < KIT; ++k) {
      int i = tid + k * 512;
      short8 v = {};
      if (i < NCH) {
        int c = i & 3, q = i >> 2;
        int xh = q % XHP; int q2 = q / XHP;
        int p = q2 & 1, l = q2 >> 1;
        int x = 2 * xh + p - 1;
        int iy = iy0 + l;
        if (x >= 0 && x < WIN && iy >= 0 && iy < HIN)
          v = *reinterpret_cast<const short8*>(in + ((((size_t)n * HIN + iy) * WIN + x) * CI + cs * 32 + c * 8));
      }
      rv[k] = v;
    }
  };
  auto writes = [&]() {
#pragma unroll
    for (int k = 0; k < KIT; ++k) {
      int i = tid + k * 512;
      if (i < NCH) sIn[(i >> 2) * 5 + (i & 3)] = rv[k];
    }
  };
  loadr(0);
  for (int cs = 0; cs < NCS; ++cs) {
    writes();
    __syncthreads();
    if (cs + 1 < NCS) loadr(cs + 1);
#pragma unroll
    for (int tap = 0; tap < 9; ++tap) {
      const int ky = tap / 3, kx = tap % 3;
      short8 afr[2], bfr[2];
#pragma unroll
      for (int m = 0; m < 2; ++m) {
        int co = cb * 128 + wm * 32 + m * 16 + llo;
        afr[m] = *reinterpret_cast<const short8*>(wT + (((size_t)tap * CO + co) * CI + cs * 32 + lhi * 8));
      }
#pragma unroll
      for (int n2 = 0; n2 < 2; ++n2) {
        int pix = wn * 32 + n2 * 16 + llo;
        int oyl = (ROUT == 2) ? (pix >> 5) : 0;
        int ox = pix - oyl * WO;
        int lrow = 2 * oyl + ky;
        int pos = (lrow * 2 + (kx & 1)) * XHP + ox + (kx >> 1);
        bfr[n2] = sIn[pos * 5 + lhi];
      }
#pragma unroll
      for (int m = 0; m < 2; ++m)
#pragma unroll
        for (int n2 = 0; n2 < 2; ++n2)
          acc[m][n2] = __builtin_amdgcn_mfma_f32_16x16x32_bf16(afr[m], bfr[n2], acc[m][n2], 0, 0, 0);
    }
    __syncthreads();
  }
#pragma unroll
  for (int m = 0; m < 2; ++m) {
    int co0 = cb * 128 + wm * 32 + m * 16 + lhi * 4;
    f32x4 bv = *reinterpret_cast<const f32x4*>(bias + co0);
#pragma unroll
    for (int n2 = 0; n2 < 2; ++n2) {
      int pix = wn * 32 + n2 * 16 + llo;
      int oyl = (ROUT == 2) ? (pix >> 5) : 0;
      int ox = pix - oyl * WO;
      int oy = oyb * ROUT + oyl;
      us4 pk;
      pk[0] = f2bf(fmaxf(acc[m][n2][0] + bv[0], 0.f));
      pk[1] = f2bf(fmaxf(acc[m][n2][1] + bv[1], 0.f));
      pk[2] = f2bf(fmaxf(acc[m][n2][2] + bv[2], 0.f));
      pk[3] = f2bf(fmaxf(acc[m][n2][3] + bv[3], 0.f));
      *reinterpret_cast<us4*>(outn + ((((size_t)n * HO + oy) * WO + ox) * CO + co0)) = pk;
    }
  }
}

// ---------------- ConvTranspose2d k3 s2 p1 op1 via bf16 MFMA (pipelined) ------
template<int CI, int CO, int Hi, int Wi, int QR, bool OBF, bool GADD>
__global__ __launch_bounds__(256) void k_deconv_mfma(
    const unsigned short* __restrict__ in,   // NHWC bf16 [N][Hi][Wi][CI]
    const unsigned short* __restrict__ wT,   // [9][CO][CI] bf16 (w[ci][co][ky][kx])
    const float* __restrict__ bias,
    const unsigned short* __restrict__ resn, // NHWC bf16 residual
    const float* __restrict__ gsrc,          // GADD: x2 node features (per-frame 256ch)
    unsigned short* __restrict__ outn,       // NHWC bf16 [N][2Hi][2Wi][CO]
    float* __restrict__ outc) {              // NCHW fp32
  constexpr int QC = 64 / QR;
  constexpr int WP = Wi + 1;
  constexpr int NPOS = (QR + 1) * WP;
  constexpr int NCH = NPOS * 4;
  constexpr int NCS = CI / 32;
  constexpr int KIT = (NCH + 255) / 256;
  constexpr int CB = CO / 64;
  constexpr int OB = Hi / QR;
  constexpr int Ho = Hi * 2, Wo = Wi * 2;
  __shared__ short8 sIn[NPOS * 5];
  int bid = blockIdx.x;
  int cb = bid % CB; bid /= CB;
  int oyb = bid % OB; int n = bid / OB;
  int tid = threadIdx.x;
  int wid = tid >> 6, lane = tid & 63;
  int wm = wid >> 1, wn = wid & 1;
  int llo = lane & 15, lhi = lane >> 4;
  int qy0 = oyb * QR;
  const float* g = nullptr;
  if constexpr (GADD) g = gsrc + ((size_t)((n >> 3) * 18 + (n & 7))) * 256;
  f32x4 acc[4][2][2] = {};
  constexpr int tap_p[9] = {3,2,3,1,0,1,3,2,3};
  constexpr int tap_b[9] = {3,2,2,1,0,0,1,0,0};
  short8 rv[KIT];
  auto loadr = [&](int cs) {
#pragma unroll
    for (int k = 0; k < KIT; ++k) {
      int i = tid + k * 256;
      short8 v = {};
      if (i < NCH) {
        int c = i & 3, q = i >> 2;
        int x = q % WP, l = q / WP;
        int iy = qy0 + l;
        if (x < Wi && iy < Hi) {
          v = *reinterpret_cast<const short8*>(in + (((size_t)(n * Hi + iy) * Wi + x) * CI + cs * 32 + c * 8));
          if constexpr (GADD) {
#pragma unroll
            for (int j = 0; j < 8; ++j) {
              float fv = bf2f((unsigned short)v[j]) + g[cs * 32 + c * 8 + j];
              v[j] = (short)f2bf(fv);
            }
          }
        }
      }
      rv[k] = v;
    }
  };
  auto writes = [&]() {
#pragma unroll
    for (int k = 0; k < KIT; ++k) {
      int i = tid + k * 256;
      if (i < NCH) sIn[(i >> 2) * 5 + (i & 3)] = rv[k];
    }
  };
  loadr(0);
  for (int cs = 0; cs < NCS; ++cs) {
    writes();
    __syncthreads();
    if (cs + 1 < NCS) loadr(cs + 1);
    short8 bfr[2][4];
#pragma unroll
    for (int n2 = 0; n2 < 2; ++n2) {
      int pix = wn * 32 + n2 * 16 + llo;
      int qyl = pix / QC, qx = pix % QC;
#pragma unroll
      for (int bs = 0; bs < 4; ++bs) {
        int pos = (qyl + (bs >> 1)) * WP + qx + (bs & 1);
        bfr[n2][bs] = sIn[pos * 5 + lhi];
      }
    }
#pragma unroll
    for (int tap = 0; tap < 9; ++tap) {
      short8 afr[2];
#pragma unroll
      for (int m = 0; m < 2; ++m) {
        int co = cb * 64 + wm * 32 + m * 16 + llo;
        afr[m] = *reinterpret_cast<const short8*>(wT + (((size_t)tap * CO + co) * CI + cs * 32 + lhi * 8));
      }
#pragma unroll
      for (int m = 0; m < 2; ++m)
#pragma unroll
        for (int n2 = 0; n2 < 2; ++n2)
          acc[tap_p[tap]][m][n2] = __builtin_amdgcn_mfma_f32_16x16x32_bf16(
              afr[m], bfr[n2][tap_b[tap]], acc[tap_p[tap]][m][n2], 0, 0, 0);
    }
    __syncthreads();
  }
#pragma unroll
  for (int m = 0; m < 2; ++m) {
    int co0 = cb * 64 + wm * 32 + m * 16 + lhi * 4;
    f32x4 bv = *reinterpret_cast<const f32x4*>(bias + co0);
#pragma unroll
    for (int n2 = 0; n2 < 2; ++n2) {
      int pix = wn * 32 + n2 * 16 + llo;
      int qyl = pix / QC, qx = pix % QC;
      int qy = qy0 + qyl;
      if constexpr (OBF) {
#pragma unroll
        for (int p = 0; p < 4; ++p) {
          int oy = 2 * qy + (p >> 1);
          int ox = 2 * qx + (p & 1);
          size_t ad = ((size_t)(n * Ho + oy) * Wo + ox) * CO + co0;
          us4 r = *reinterpret_cast<const us4*>(resn + ad);
          us4 pk;
#pragma unroll
          for (int c = 0; c < 4; ++c)
            pk[c] = f2bf(bf2f(r[c]) + fmaxf(acc[p][m][n2][c] + bv[c], 0.f));
          *reinterpret_cast<us4*>(outn + ad) = pk;
        }
      } else {
        int qx2 = 2 * qx;
#pragma unroll
        for (int dy = 0; dy < 2; ++dy) {
          int oy = 2 * qy + dy;
          size_t rb = ((size_t)(n * Ho + oy) * Wo + qx2) * CO + co0;
          us4 r0 = *reinterpret_cast<const us4*>(resn + rb);
          us4 r1 = *reinterpret_cast<const us4*>(resn + rb + CO);
#pragma unroll
          for (int c = 0; c < 4; ++c) {
            float2 st;
            st.x = bf2f(r0[c]) + fmaxf(acc[dy * 2][m][n2][c] + bv[c], 0.f);
            st.y = bf2f(r1[c]) + fmaxf(acc[dy * 2 + 1][m][n2][c] + bv[c], 0.f);
            *reinterpret_cast<float2*>(outc + ((size_t)(n * CO + co0 + c) * Ho + oy) * Wo + qx2) = st;
          }
        }
      }
    }
  }
}

// ---------------- stage 1: partial spatial max (NHWC bf16), 8 blocks per n ----------
__global__ __launch_bounds__(256) void k_max_part(const unsigned short* __restrict__ x,
                                                  float* __restrict__ pmax) {
  int n = blockIdx.x >> 3, pg = blockIdx.x & 7;
  int ch = threadIdx.x;
  const unsigned short* base = x + (size_t)n * 1024 * 256 + (size_t)pg * 128 * 256 + ch;
  float m = -1e30f;
#pragma unroll 4
  for (int p = 0; p < 128; ++p)
    m = fmaxf(m, bf2f(base[(size_t)p * 256]));
  pmax[((size_t)n * 8 + pg) * 256 + ch] = m;
}

// ---------------- stage 2: combine partials + LayerNorm over 256 channels ----------
__global__ __launch_bounds__(256) void k_ln(const float* __restrict__ pmax,
                                            float* __restrict__ out) {
  int n = blockIdx.x, ch = threadIdx.x;
  float m = -1e30f;
#pragma unroll
  for (int g = 0; g < 8; ++g)
    m = fmaxf(m, pmax[((size_t)n * 8 + g) * 256 + ch]);
  __shared__ float r1[256], r2[256];
  r1[ch] = m; __syncthreads();
  for (int s = 128; s > 0; s >>= 1) { if (ch < s) r1[ch] += r1[ch + s]; __syncthreads(); }
  float mu = r1[0] * (1.f / 256.f);
  float d = m - mu;
  r2[ch] = d * d; __syncthreads();
  for (int s = 128; s > 0; s >>= 1) { if (ch < s) r2[ch] += r2[ch + s]; __syncthreads(); }
  out[(size_t)n * 256 + ch] = d * rsqrtf(r2[0] * (1.f / 256.f) + 1e-5f);
}

// ---------------- build node features ----------------
__global__ void k_build_x(const float* __restrict__ vn, const float* __restrict__ dn,
                          const float* __restrict__ tn, float* __restrict__ x0) {
  int b = blockIdx.x, ch = threadIdx.x;
  float s = 0.f;
  for (int f = 0; f < 8; ++f) {
    float vv = vn[((size_t)b * 8 + f) * 256 + ch];
    float dd = dn[((size_t)b * 8 + f) * 256 + ch];
    s += vv + dd;
    x0[((size_t)b * 18 + f) * 256 + ch] = vv;
    x0[((size_t)b * 18 + 8 + f) * 256 + ch] = dd;
  }
  float tv = tn[(size_t)b * 256 + ch];
  x0[((size_t)b * 18 + 16) * 256 + ch] = tv;
  x0[((size_t)b * 18 + 17) * 256 + ch] = tv + s * (1.f / 8.f);
}

// ---------------- GNN linear ----------------
__global__ __launch_bounds__(256) void k_gnn_lin(
    const float* __restrict__ x, const float* __restrict__ ea,
    const float* __restrict__ w, float* __restrict__ y, int K, int M) {
  int chunks = M >> 8;
  int r = blockIdx.x / chunks;
  int ob = (blockIdx.x % chunks) * 256 + threadIdx.x;
  const float* src = (r < 36) ? (x + (size_t)r * K) : (ea + (size_t)(r - 36) * K);
  __shared__ __align__(16) float sxr[512];
  for (int k = threadIdx.x; k < K; k += 256) sxr[k] = src[k];
  __syncthreads();
  const float4* w4 = reinterpret_cast<const float4*>(w + (size_t)ob * K);
  const float4* x4 = reinterpret_cast<const float4*>(sxr);
  float acc = 0.f;
  int k4 = K >> 2;
  for (int k = 0; k < k4; ++k) {
    float4 a = x4[k], b = w4[k];
    acc += a.x * b.x + a.y * b.y + a.z * b.z + a.w * b.w;
  }
  y[(size_t)r * M + ob] = acc;
}

// ---------------- fused attention dots + logits + segment softmax -> attw(134,4) ------
template<int OC>
__global__ __launch_bounds__(256) void k_gnn_attsm(
    const float* __restrict__ y, const float* __restrict__ att,
    float* __restrict__ attw) {
  int t = threadIdx.x;
  __shared__ float sx_s[144], seb_s[60];
  __shared__ float a_s[536];
  if (t < 200) {
    int r = t >> 2, h = t & 3;
    const float4* row = reinterpret_cast<const float4*>(y + ((size_t)r * 4 + h) * OC);
    const float4* ar = reinterpret_cast<const float4*>(att + (size_t)h * 2 * OC + (r < 36 ? 0 : OC));
    float s = 0.f;
#pragma unroll 4
    for (int k = 0; k < OC / 4; ++k) {
      float4 a = row[k], b = ar[k];
      s += a.x * b.x + a.y * b.y + a.z * b.z + a.w * b.w;
    }
    if (r < 36) sx_s[r * 4 + h] = s; else seb_s[(r - 36) * 4 + h] = s;
  }
  __syncthreads();
  for (int idx = t; idx < 536; idx += 256) {
    int i = idx >> 2, h = idx & 3;
    float v = sx_s[c_row[i] * 4 + h] + seb_s[c_col[i] * 4 + h];
    a_s[idx] = (v > 0.f) ? v : 0.2f * v;
  }
  __syncthreads();
  if (t < 56) {
    int c = t >> 2, h = t & 3;
    int st = c_cs[c], en = c_cs[c + 1];
    float m = -1e30f;
    for (int i = st; i < en; ++i) m = fmaxf(m, a_s[i * 4 + h]);
    float s = 0.f;
    for (int i = st; i < en; ++i) { float e = __expf(a_s[i * 4 + h] - m); a_s[i * 4 + h] = e; s += e; }
    float inv = 1.f / (s + 1e-16f);
    for (int i = st; i < en; ++i) a_s[i * 4 + h] *= inv;
  }
  __syncthreads();
  for (int idx = t; idx < 536; idx += 256) attw[idx] = a_s[idx];
}

// ---------------- edge aggregation ----------------
template<int OC>
__global__ __launch_bounds__(256) void k_edge_agg(
    const float* __restrict__ y, const float* __restrict__ attw,
    float* __restrict__ eb) {
  int idx = blockIdx.x * 256 + threadIdx.x;
  if (idx >= 14 * 4 * OC) return;
  int ch = idx % OC;
  int h = (idx / OC) & 3;
  int c = idx / (4 * OC);
  int st = c_cs[c], en = c_cs[c + 1];
  float s = 0.f;
  for (int i = st; i < en; ++i)
    s += attw[i * 4 + h] * y[(size_t)c_row[i] * (4 * OC) + h * OC + ch];
  eb[idx] = s * (1.f / (float)(en - st));
}

// ---------------- node aggregation ----------------
template<int OC>
__global__ __launch_bounds__(256) void k_node_agg(
    const float* __restrict__ attw, const float* __restrict__ eb,
    const float* __restrict__ ew, float* __restrict__ ho) {
  int idx = blockIdx.x * 256 + threadIdx.x;
  if (idx >= 36 * OC) return;
  int ch = idx % OC;
  int node = idx / OC;
  int b = node / 18, ln = node % 18;
  int ncols, cols[4], gis[4];
  if (ln < 16) {
    ncols = 4;
    cols[0] = b * 7 + (ln < 8 ? 0 : 1); gis[0] = b * 67 + ln;
    cols[1] = b * 7 + 2; gis[1] = b * 67 + 16 + ln;
    cols[2] = b * 7 + 3; gis[2] = b * 67 + 32 + ln;
    cols[3] = b * 7 + 4; gis[3] = b * 67 + 48 + ln;
  } else if (ln == 16) {
    ncols = 2;
    cols[0] = b * 7 + 4; gis[0] = b * 67 + 64;
    cols[1] = b * 7 + 5; gis[1] = b * 67 + 65;
    cols[2] = cols[3] = 0; gis[2] = gis[3] = 0;
  } else {
    ncols = 1;
    cols[0] = b * 7 + 6; gis[0] = b * 67 + 66;
    cols[1] = cols[2] = cols[3] = 0; gis[1] = gis[2] = gis[3] = 0;
  }
  float dsum = 0.f;
#pragma unroll
  for (int k = 0; k < 4; ++k) if (k < ncols) dsum += ew[cols[k]];
  float D = dsum > 0.f ? 1.f / dsum : 0.f;
  float s = 0.f;
#pragma unroll
  for (int k = 0; k < 4; ++k) {
    if (k < ncols) {
#pragma unroll
      for (int h = 0; h < 4; ++h)
        s += attw[gis[k] * 4 + h] * eb[((size_t)cols[k] * 4 + h) * OC + ch];
    }
  }
  ho[idx] = fmaxf(0.25f * D * s, 0.f);
}

// ---------------- GroupNorm(32) + SE layer ----------------
template<int C, int Cr>
__global__ __launch_bounds__(512) void k_gn_se(
    const float* __restrict__ hin, const float* __restrict__ w1,
    const float* __restrict__ w2, float* __restrict__ x) {
  int t = threadIdx.x;
  constexpr int gs = C >> 5;
  for (int idx = t; idx < 36 * 32; idx += 512) {
    int node = idx >> 5, g = idx & 31;
    const float* p = hin + (size_t)node * C + g * gs;
    float s = 0.f, s2 = 0.f;
#pragma unroll
    for (int k = 0; k < gs; ++k) { float v = p[k]; s += v; s2 += v * v; }
    float mu = s * (1.f / gs);
    float var = s2 * (1.f / gs) - mu * mu;
    float inv = rsqrtf(fmaxf(var, 0.f) + 1e-5f);
    float* q = x + (size_t)node * C + g * gs;
#pragma unroll
    for (int k = 0; k < gs; ++k) q[k] = (p[k] - mu) * inv;
  }
  __threadfence_block();
  __syncthreads();
  __shared__ float smean[C];
  __shared__ float spart[Cr][17];
  __shared__ float shid[Cr];
  __shared__ float sscale[C];
  if (t < C) {
    float s = 0.f;
    for (int nn = 0; nn < 36; ++nn) s += x[(size_t)nn * C + t];
    smean[t] = s * (1.f / 36.f);
  }
  __syncthreads();
  if (t < Cr * 16) {
    int hid = t >> 4, sub = t & 15;
    constexpr int CH = C / 16;
    float s = 0.f;
#pragma unroll
    for (int k = 0; k < CH; ++k)
      s += w1[(size_t)hid * C + sub * CH + k] * smean[sub * CH + k];
    spart[hid][sub] = s;
  }
  __syncthreads();
  if (t < Cr) {
    float s = 0.f;
#pragma unroll
    for (int k = 0; k < 16; ++k) s += spart[t][k];
    shid[t] = fmaxf(s, 0.f);
  }
  __syncthreads();
  if (t < C) {
    float s = 0.f;
#pragma unroll
    for (int k = 0; k < Cr; ++k) s += w2[(size_t)t * Cr + k] * shid[k];
    sscale[t] = 1.f / (1.f + __expf(-s));
  }
  __syncthreads();
  for (int idx = t; idx < 36 * C; idx += 512) x[idx] *= sscale[idx % C];
}

// ---------------- observers ----------------
__global__ void k_obs(const float* __restrict__ tn, const float* __restrict__ x2,
                      float* __restrict__ out) {
  int t = threadIdx.x;
  if (t >= 128) return;
  int b = t >> 6, ch = t & 63;
  const float* a = tn + (size_t)b * 256 + ch * 4;
  const float* c = x2 + ((size_t)b * 18 + 17) * 256 + ch * 4;
  float m = a[0] + c[0];
  m = fmaxf(m, a[1] + c[1]);
  m = fmaxf(m, a[2] + c[2]);
  m = fmaxf(m, a[3] + c[3]);
  out[b * 64 + ch] = m;
}

extern "C" void kernel_launch(void* const* d_in, const int* in_sizes, int n_in,
                              void* d_out, int out_size, void* d_ws, size_t ws_size,
                              hipStream_t stream) {
  (void)in_sizes; (void)n_in; (void)out_size; (void)ws_size;
  const float* vf    = (const float*)d_in[0];
  const float* vp    = (const float*)d_in[1];
  const float* mf    = (const float*)d_in[2];
  const float* mp    = (const float*)d_in[3];
  const float* tf    = (const float*)d_in[4];
  const float* tp    = (const float*)d_in[5];
  const float* cv1w  = (const float*)d_in[6];
  const float* cv1b  = (const float*)d_in[7];
  const float* cv2w  = (const float*)d_in[8];
  const float* cv2b  = (const float*)d_in[9];
  const float* dc1w  = (const float*)d_in[10];
  const float* dc1b  = (const float*)d_in[11];
  const float* dc2w  = (const float*)d_in[12];
  const float* dc2b  = (const float*)d_in[13];
  const float* tc1w  = (const float*)d_in[14];
  const float* tc1b  = (const float*)d_in[15];
  const float* tc2w  = (const float*)d_in[16];
  const float* tc2b  = (const float*)d_in[17];
  const float* lin1w = (const float*)d_in[18];
  const float* att1  = (const float*)d_in[19];
  const float* lin2w = (const float*)d_in[20];
  const float* att2  = (const float*)d_in[21];
  const float* ew1   = (const float*)d_in[22];
  const float* ew2   = (const float*)d_in[23];
  const float* ea1   = (const float*)d_in[24];
  const float* ea2   = (const float*)d_in[25];
  const float* se1w1 = (const float*)d_in[26];
  const float* se1w2 = (const float*)d_in[27];
  const float* se2w1 = (const float*)d_in[28];
  const float* se2w2 = (const float*)d_in[29];

  float* ws  = (float*)d_ws;
  float* out = (float*)d_out;

  // workspace layout (float units)
  unsigned short* p0n = (unsigned short*)(ws);             // 16x128x128x64 bf16 (vf+vp NHWC)
  unsigned short* q1n = (unsigned short*)(ws + 8388608);   // 16x64x64x128 bf16 (d1n/v1n)
  unsigned short* t1n = (unsigned short*)(ws + 12582912);  // 16x64x64x128 bf16
  unsigned short* v2n = (unsigned short*)(ws + 16777216);  // 16x32x32x256 bf16 (d2n/v2n)
  unsigned short* wtb = (unsigned short*)(ws + 18874368);  // 1,105,920 bf16
  float* sm   = ws + 19427328;
  float* tn   = sm;                 // 512
  float* vn   = sm + 512;           // 4096
  float* dn   = sm + 4608;          // 4096
  float* x0   = sm + 8704;          // 9216
  float* xl   = sm + 17920;         // 102400
  float* eb   = sm + 120520;        // 28672
  float* ho   = sm + 149192;        // 18432
  float* x1   = sm + 167624;        // 18432
  float* x2   = sm + 186056;        // 9216
  float* attw = sm + 195272;        // 536
  float* pmax = sm + 195904;        // 32768 (16 n x 8 pg x 256 ch)

  unsigned short* wTc1 = wtb;             // 9*128*64
  unsigned short* wTd1 = wtb + 73728;
  unsigned short* wTc2 = wtb + 147456;    // 9*256*128
  unsigned short* wTd2 = wtb + 442368;
  unsigned short* wTt1 = wtb + 737280;    // 9*128*256 (tc1: in256->out128)
  unsigned short* wTt2 = wtb + 1032192;   // 9*64*128  (tc2: in128->out64)

  // 0. all weight transforms (one kernel)
  k_wtrans_all<<<4320, 256, 0, stream>>>(cv1w, dc1w, cv2w, dc2w, tc1w, tc2w, wtb);

  // 1. text pooling
  k_text_pool<<<2, 256, 0, stream>>>(tf, tp, tn);

  // 2. motion branch (uses p0n as scratch; overwritten by vision prep later)
  k_prep<<<4096, 256, 0, stream>>>(mf, mp, p0n);
  k_conv_mfma<64, 128, 64, 64, 1><<<1024, 512, 0, stream>>>(p0n, wTd1, dc1b, q1n);
  k_conv_mfma<128, 256, 32, 32, 2><<<512, 512, 0, stream>>>(q1n, wTd2, dc2b, v2n);
  k_max_part<<<128, 256, 0, stream>>>(v2n, pmax);
  k_ln<<<16, 256, 0, stream>>>(pmax, dn);

  // 3. vision branch (p0n kept = bf16(vf+vp); q1n = v1n kept as deconv1 residual)
  k_prep<<<4096, 256, 0, stream>>>(vf, vp, p0n);
  k_conv_mfma<64, 128, 64, 64, 1><<<1024, 512, 0, stream>>>(p0n, wTc1, cv1b, q1n);
  k_conv_mfma<128, 256, 32, 32, 2><<<512, 512, 0, stream>>>(q1n, wTc2, cv2b, v2n);
  k_max_part<<<128, 256, 0, stream>>>(v2n, pmax);
  k_ln<<<16, 256, 0, stream>>>(pmax, vn);

  // 4. node features
  k_build_x<<<2, 256, 0, stream>>>(vn, dn, tn, x0);

  // 5. GNN layer 1 (OC=512)
  k_gnn_lin<<<50 * 8, 256, 0, stream>>>(x0, ea1, lin1w, xl, 256, 2048);
  k_gnn_attsm<512><<<1, 256, 0, stream>>>(xl, att1, attw);
  k_edge_agg<512><<<112, 256, 0, stream>>>(xl, attw, eb);
  k_node_agg<512><<<72, 256, 0, stream>>>(attw, eb, ew1, ho);
  k_gn_se<512, 32><<<1, 512, 0, stream>>>(ho, se1w1, se1w2, x1);

  // 6. GNN layer 2 (OC=256)
  k_gnn_lin<<<50 * 4, 256, 0, stream>>>(x1, ea2, lin2w, xl, 512, 1024);
  k_gnn_attsm<256><<<1, 256, 0, stream>>>(xl, att2, attw);
  k_edge_agg<256><<<56, 256, 0, stream>>>(xl, attw, eb);
  k_node_agg<256><<<36, 256, 0, stream>>>(attw, eb, ew2, ho);
  k_gn_se<256, 16><<<1, 512, 0, stream>>>(ho, se2w1, se2w2, x2);

  // 7. observers
  k_obs<<<1, 128, 0, stream>>>(tn, x2, out + 16777216);

  // 8. decoder: t1n = v1n + relu(convT1(v2n + vg[fused])) ; out = bf16(vf+vp) + relu(convT2(t1n))
  k_deconv_mfma<256, 128, 32, 32, 2, true, true><<<512, 256, 0, stream>>>(
      v2n, wTt1, tc1b, q1n, x2, t1n, nullptr);
  k_deconv_mfma<128, 64, 64, 64, 1, false, false><<<1024, 256, 0, stream>>>(
      t1n, wTt2, tc2b, p0n, nullptr, nullptr, out);
}

// Round 8
// 486.589 us; speedup vs baseline: 7.6860x; 1.0743x over previous
//
#include <hip/hip_runtime.h>
#include <hip/hip_bf16.h>
#include <cstddef>
#include <cstdint>

#define DEV_INLINE __device__ __forceinline__

typedef __attribute__((ext_vector_type(8))) short short8;
typedef __attribute__((ext_vector_type(4))) float f32x4;
typedef __attribute__((ext_vector_type(4))) unsigned short us4;

DEV_INLINE unsigned short f2bf(float f) {
  uint32_t u = __builtin_bit_cast(uint32_t, f);
  uint32_t r = (u + 0x7fffu + ((u >> 16) & 1u)) >> 16;
  return (unsigned short)r;
}
DEV_INLINE float bf2f(unsigned short u) {
  return __builtin_bit_cast(float, (uint32_t)u << 16);
}

// Problem constants: BS=2, F=8, C=64, H=128, W=128, HEADS=4
__device__ __constant__ int c_cs[15] = {0,8,16,32,48,65,66,67,75,83,99,115,132,133,134};
__device__ __constant__ int c_row[134] = {
  0,1,2,3,4,5,6,7,
  8,9,10,11,12,13,14,15,
  0,1,2,3,4,5,6,7,8,9,10,11,12,13,14,15,
  0,1,2,3,4,5,6,7,8,9,10,11,12,13,14,15,
  0,1,2,3,4,5,6,7,8,9,10,11,12,13,14,15,16,
  16,
  17,
  18,19,20,21,22,23,24,25,
  26,27,28,29,30,31,32,33,
  18,19,20,21,22,23,24,25,26,27,28,29,30,31,32,33,
  18,19,20,21,22,23,24,25,26,27,28,29,30,31,32,33,
  18,19,20,21,22,23,24,25,26,27,28,29,30,31,32,33,34,
  34,
  35
};
__device__ __constant__ int c_col[134] = {
  0,0,0,0,0,0,0,0,
  1,1,1,1,1,1,1,1,
  2,2,2,2,2,2,2,2,2,2,2,2,2,2,2,2,
  3,3,3,3,3,3,3,3,3,3,3,3,3,3,3,3,
  4,4,4,4,4,4,4,4,4,4,4,4,4,4,4,4,4,
  5,
  6,
  7,7,7,7,7,7,7,7,
  8,8,8,8,8,8,8,8,
  9,9,9,9,9,9,9,9,9,9,9,9,9,9,9,9,
  10,10,10,10,10,10,10,10,10,10,10,10,10,10,10,10,
  11,11,11,11,11,11,11,11,11,11,11,11,11,11,11,11,11,
  12,
  13
};

// ---------------- text pool ----------------
__global__ void k_text_pool(const float* __restrict__ tf, const float* __restrict__ tp,
                            float* __restrict__ tn) {
  int t = blockIdx.x * blockDim.x + threadIdx.x;
  if (t >= 512) return;
  int b = t >> 8, idx = t & 255;
  int ch = idx >> 2, j = idx & 3;
  const float* p = tf + ((size_t)b * 64 + ch) * 16 + j * 4;
  const float* q = tp + ((size_t)b * 64 + ch) * 16 + j * 4;
  float m = p[0] + q[0];
  m = fmaxf(m, p[1] + q[1]);
  m = fmaxf(m, p[2] + q[2]);
  m = fmaxf(m, p[3] + q[3]);
  tn[(size_t)b * 256 + idx] = m;
}

// ---------------- input prep: (a+b) NCHW fp32 -> NHWC bf16 (conflict-free) ----------
// Tile: 64 ch x 64 x per block. LDS su[cpair][x] packed uint (2 channels).
// Bank for su[cp][x] = (65*cp + x) % 32 = (cp + x) % 32 -> conflict-free both phases.
__global__ __launch_bounds__(256) void k_prep(const float* __restrict__ a,
                                              const float* __restrict__ b,
                                              unsigned short* __restrict__ o) {
  int bid = blockIdx.x;
  int xb = bid & 1, y = (bid >> 1) & 127, n = bid >> 8;
  __shared__ unsigned int su[32][65];
  int t = threadIdx.x;
  const size_t base = ((size_t)n * 64) * 16384 + (size_t)y * 128 + xb * 64;
#pragma unroll
  for (int it = 0; it < 2; ++it) {
    int i = t + it * 256;
    int cpair = i >> 4;   // 0..31
    int x4 = i & 15;      // 0..15 (4 x each)
    size_t off = base + (size_t)(2 * cpair) * 16384 + x4 * 4;
    float4 a0 = *reinterpret_cast<const float4*>(a + off);
    float4 b0 = *reinterpret_cast<const float4*>(b + off);
    float4 a1 = *reinterpret_cast<const float4*>(a + off + 16384);
    float4 b1 = *reinterpret_cast<const float4*>(b + off + 16384);
    unsigned int* row = &su[cpair][x4 * 4];
    row[0] = (unsigned int)f2bf(a0.x + b0.x) | ((unsigned int)f2bf(a1.x + b1.x) << 16);
    row[1] = (unsigned int)f2bf(a0.y + b0.y) | ((unsigned int)f2bf(a1.y + b1.y) << 16);
    row[2] = (unsigned int)f2bf(a0.z + b0.z) | ((unsigned int)f2bf(a1.z + b1.z) << 16);
    row[3] = (unsigned int)f2bf(a0.w + b0.w) | ((unsigned int)f2bf(a1.w + b1.w) << 16);
  }
  __syncthreads();
  unsigned int* op = (unsigned int*)(o + (((size_t)n * 128 + y) * 128 + xb * 64) * 64);
#pragma unroll
  for (int it = 0; it < 2; ++it) {
    int i = t + it * 256;
    int x = i >> 3;       // 0..63
    int cq = i & 7;       // 0..7 (4 cpairs each)
    uint4 v;
    v.x = su[cq * 4 + 0][x];
    v.y = su[cq * 4 + 1][x];
    v.z = su[cq * 4 + 2][x];
    v.w = su[cq * 4 + 3][x];
    *reinterpret_cast<uint4*>(op + x * 32 + cq * 4) = v;
  }
}

// ---------------- all weight transforms -> wT[tap][co][ci] bf16, one kernel ----------
__global__ void k_wtrans_all(const float* __restrict__ cv1w, const float* __restrict__ dc1w,
                             const float* __restrict__ cv2w, const float* __restrict__ dc2w,
                             const float* __restrict__ tc1w, const float* __restrict__ tc2w,
                             unsigned short* __restrict__ wtb) {
  int idx = blockIdx.x * 256 + threadIdx.x;
  const float* src; int off, lci, lco; bool tra;
  if (idx < 73728)        { src = cv1w; off = 0;       lci = 6; lco = 7; tra = false; }
  else if (idx < 147456)  { src = dc1w; off = 73728;   lci = 6; lco = 7; tra = false; }
  else if (idx < 442368)  { src = cv2w; off = 147456;  lci = 7; lco = 8; tra = false; }
  else if (idx < 737280)  { src = dc2w; off = 442368;  lci = 7; lco = 8; tra = false; }
  else if (idx < 1032192) { src = tc1w; off = 737280;  lci = 8; lco = 7; tra = true;  }
  else if (idx < 1105920) { src = tc2w; off = 1032192; lci = 7; lco = 6; tra = true;  }
  else return;
  int l = idx - off;
  int ci = l & ((1 << lci) - 1);
  int r = l >> lci;
  int co = r & ((1 << lco) - 1);
  int tap = r >> lco;
  size_t si = tra ? (((size_t)ci << lco) + co) * 9 + tap
                  : (((size_t)co << lci) + ci) * 9 + tap;
  wtb[idx] = f2bf(src[si]);
}

// ---------------- Conv2d k3 s2 p1 + bias + ReLU via bf16 MFMA (pipelined) ----------
template<int CI, int CO, int HO, int WO, int ROUT>
__global__ __launch_bounds__(512) void k_conv_mfma(
    const unsigned short* __restrict__ in,   // NHWC bf16 [N][2HO][2WO][CI]
    const unsigned short* __restrict__ wT,   // [9][CO][CI] bf16
    const float* __restrict__ bias,
    unsigned short* __restrict__ outn) {     // NHWC bf16 [N][HO][WO][CO]
  constexpr int HIN = HO * 2, WIN = WO * 2;
  constexpr int XHP = WO + 2;
  constexpr int R = 2 * ROUT + 1;
  constexpr int NPOS = R * 2 * XHP;
  constexpr int NCH = NPOS * 4;
  constexpr int NCS = CI / 32;
  constexpr int KIT = (NCH + 511) / 512;
  constexpr int CB = CO / 128;
  constexpr int OB = HO / ROUT;
  __shared__ short8 sIn[NPOS * 5];
  int bid = blockIdx.x;
  int cb = bid % CB; bid /= CB;
  int oyb = bid % OB; int n = bid / OB;
  int tid = threadIdx.x;
  int wid = tid >> 6, lane = tid & 63;
  int wm = wid >> 1, wn = wid & 1;
  int llo = lane & 15, lhi = lane >> 4;
  f32x4 acc[2][2] = {};
  const int iy0 = oyb * (2 * ROUT) - 1;
  short8 rv[KIT];
  auto loadr = [&](int cs) {
#pragma unroll
    for (int k = 0; k < KIT; ++k) {
      int i = tid + k * 512;
      short8 v = {};
      if (i < NCH) {
        int c = i & 3, q = i >> 2;
        int xh = q % XHP; int q2 = q / XHP;
        int p = q2 & 1, l = q2 >> 1;
        int x = 2 * xh + p - 1;
        int iy = iy0 + l;
        if (x >= 0 && x < WIN && iy >= 0 && iy < HIN)
          v = *reinterpret_cast<const short8*>(in + ((((size_t)n * HIN + iy) * WIN + x) * CI + cs * 32 + c * 8));
      }
      rv[k] = v;
    }
  };
  auto writes = [&]() {
#pragma unroll
    for (int k = 0; k < KIT; ++k) {
      int i = tid + k * 512;
      if (i < NCH) sIn[(i >> 2) * 5 + (i & 3)] = rv[k];
    }
  };
  loadr(0);
  for (int cs = 0; cs < NCS; ++cs) {
    writes();
    __syncthreads();
    if (cs + 1 < NCS) loadr(cs + 1);
#pragma unroll
    for (int tap = 0; tap < 9; ++tap) {
      const int ky = tap / 3, kx = tap % 3;
      short8 afr[2], bfr[2];
#pragma unroll
      for (int m = 0; m < 2; ++m) {
        int co = cb * 128 + wm * 32 + m * 16 + llo;
        afr[m] = *reinterpret_cast<const short8*>(wT + (((size_t)tap * CO + co) * CI + cs * 32 + lhi * 8));
      }
#pragma unroll
      for (int n2 = 0; n2 < 2; ++n2) {
        int pix = wn * 32 + n2 * 16 + llo;
        int oyl = (ROUT == 2) ? (pix >> 5) : 0;
        int ox = pix - oyl * WO;
        int lrow = 2 * oyl + ky;
        int pos = (lrow * 2 + (kx & 1)) * XHP + ox + (kx >> 1);
        bfr[n2] = sIn[pos * 5 + lhi];
      }
#pragma unroll
      for (int m = 0; m < 2; ++m)
#pragma unroll
        for (int n2 = 0; n2 < 2; ++n2)
          acc[m][n2] = __builtin_amdgcn_mfma_f32_16x16x32_bf16(afr[m], bfr[n2], acc[m][n2], 0, 0, 0);
    }
    __syncthreads();
  }
#pragma unroll
  for (int m = 0; m < 2; ++m) {
    int co0 = cb * 128 + wm * 32 + m * 16 + lhi * 4;
    f32x4 bv = *reinterpret_cast<const f32x4*>(bias + co0);
#pragma unroll
    for (int n2 = 0; n2 < 2; ++n2) {
      int pix = wn * 32 + n2 * 16 + llo;
      int oyl = (ROUT == 2) ? (pix >> 5) : 0;
      int ox = pix - oyl * WO;
      int oy = oyb * ROUT + oyl;
      us4 pk;
      pk[0] = f2bf(fmaxf(acc[m][n2][0] + bv[0], 0.f));
      pk[1] = f2bf(fmaxf(acc[m][n2][1] + bv[1], 0.f));
      pk[2] = f2bf(fmaxf(acc[m][n2][2] + bv[2], 0.f));
      pk[3] = f2bf(fmaxf(acc[m][n2][3] + bv[3], 0.f));
      *reinterpret_cast<us4*>(outn + ((((size_t)n * HO + oy) * WO + ox) * CO + co0)) = pk;
    }
  }
}

// ---------------- ConvTranspose2d k3 s2 p1 op1 via bf16 MFMA (pipelined) ------
template<int CI, int CO, int Hi, int Wi, int QR, bool OBF, bool GADD>
__global__ __launch_bounds__(256) void k_deconv_mfma(
    const unsigned short* __restrict__ in,   // NHWC bf16 [N][Hi][Wi][CI]
    const unsigned short* __restrict__ wT,   // [9][CO][CI] bf16 (w[ci][co][ky][kx])
    const float* __restrict__ bias,
    const unsigned short* __restrict__ resn, // NHWC bf16 residual
    const float* __restrict__ gsrc,          // GADD: x2 node features (per-frame 256ch)
    unsigned short* __restrict__ outn,       // NHWC bf16 [N][2Hi][2Wi][CO]
    float* __restrict__ outc) {              // NCHW fp32
  constexpr int QC = 64 / QR;
  constexpr int WP = Wi + 1;
  constexpr int NPOS = (QR + 1) * WP;
  constexpr int NCH = NPOS * 4;
  constexpr int NCS = CI / 32;
  constexpr int KIT = (NCH + 255) / 256;
  constexpr int CB = CO / 64;
  constexpr int OB = Hi / QR;
  constexpr int Ho = Hi * 2, Wo = Wi * 2;
  __shared__ short8 sIn[NPOS * 5];
  int bid = blockIdx.x;
  int cb = bid % CB; bid /= CB;
  int oyb = bid % OB; int n = bid / OB;
  int tid = threadIdx.x;
  int wid = tid >> 6, lane = tid & 63;
  int wm = wid >> 1, wn = wid & 1;
  int llo = lane & 15, lhi = lane >> 4;
  int qy0 = oyb * QR;
  const float* g = nullptr;
  if constexpr (GADD) g = gsrc + ((size_t)((n >> 3) * 18 + (n & 7))) * 256;
  f32x4 acc[4][2][2] = {};
  constexpr int tap_p[9] = {3,2,3,1,0,1,3,2,3};
  constexpr int tap_b[9] = {3,2,2,1,0,0,1,0,0};
  short8 rv[KIT];
  auto loadr = [&](int cs) {
#pragma unroll
    for (int k = 0; k < KIT; ++k) {
      int i = tid + k * 256;
      short8 v = {};
      if (i < NCH) {
        int c = i & 3, q = i >> 2;
        int x = q % WP, l = q / WP;
        int iy = qy0 + l;
        if (x < Wi && iy < Hi) {
          v = *reinterpret_cast<const short8*>(in + (((size_t)(n * Hi + iy) * Wi + x) * CI + cs * 32 + c * 8));
          if constexpr (GADD) {
#pragma unroll
            for (int j = 0; j < 8; ++j) {
              float fv = bf2f((unsigned short)v[j]) + g[cs * 32 + c * 8 + j];
              v[j] = (short)f2bf(fv);
            }
          }
        }
      }
      rv[k] = v;
    }
  };
  auto writes = [&]() {
#pragma unroll
    for (int k = 0; k < KIT; ++k) {
      int i = tid + k * 256;
      if (i < NCH) sIn[(i >> 2) * 5 + (i & 3)] = rv[k];
    }
  };
  loadr(0);
  for (int cs = 0; cs < NCS; ++cs) {
    writes();
    __syncthreads();
    if (cs + 1 < NCS) loadr(cs + 1);
    short8 bfr[2][4];
#pragma unroll
    for (int n2 = 0; n2 < 2; ++n2) {
      int pix = wn * 32 + n2 * 16 + llo;
      int qyl = pix / QC, qx = pix % QC;
#pragma unroll
      for (int bs = 0; bs < 4; ++bs) {
        int pos = (qyl + (bs >> 1)) * WP + qx + (bs & 1);
        bfr[n2][bs] = sIn[pos * 5 + lhi];
      }
    }
#pragma unroll
    for (int tap = 0; tap < 9; ++tap) {
      short8 afr[2];
#pragma unroll
      for (int m = 0; m < 2; ++m) {
        int co = cb * 64 + wm * 32 + m * 16 + llo;
        afr[m] = *reinterpret_cast<const short8*>(wT + (((size_t)tap * CO + co) * CI + cs * 32 + lhi * 8));
      }
#pragma unroll
      for (int m = 0; m < 2; ++m)
#pragma unroll
        for (int n2 = 0; n2 < 2; ++n2)
          acc[tap_p[tap]][m][n2] = __builtin_amdgcn_mfma_f32_16x16x32_bf16(
              afr[m], bfr[n2][tap_b[tap]], acc[tap_p[tap]][m][n2], 0, 0, 0);
    }
    __syncthreads();
  }
#pragma unroll
  for (int m = 0; m < 2; ++m) {
    int co0 = cb * 64 + wm * 32 + m * 16 + lhi * 4;
    f32x4 bv = *reinterpret_cast<const f32x4*>(bias + co0);
#pragma unroll
    for (int n2 = 0; n2 < 2; ++n2) {
      int pix = wn * 32 + n2 * 16 + llo;
      int qyl = pix / QC, qx = pix % QC;
      int qy = qy0 + qyl;
      if constexpr (OBF) {
#pragma unroll
        for (int p = 0; p < 4; ++p) {
          int oy = 2 * qy + (p >> 1);
          int ox = 2 * qx + (p & 1);
          size_t ad = ((size_t)(n * Ho + oy) * Wo + ox) * CO + co0;
          us4 r = *reinterpret_cast<const us4*>(resn + ad);
          us4 pk;
#pragma unroll
          for (int c = 0; c < 4; ++c)
            pk[c] = f2bf(bf2f(r[c]) + fmaxf(acc[p][m][n2][c] + bv[c], 0.f));
          *reinterpret_cast<us4*>(outn + ad) = pk;
        }
      } else {
        int qx2 = 2 * qx;
#pragma unroll
        for (int dy = 0; dy < 2; ++dy) {
          int oy = 2 * qy + dy;
          size_t rb = ((size_t)(n * Ho + oy) * Wo + qx2) * CO + co0;
          us4 r0 = *reinterpret_cast<const us4*>(resn + rb);
          us4 r1 = *reinterpret_cast<const us4*>(resn + rb + CO);
#pragma unroll
          for (int c = 0; c < 4; ++c) {
            float2 st;
            st.x = bf2f(r0[c]) + fmaxf(acc[dy * 2][m][n2][c] + bv[c], 0.f);
            st.y = bf2f(r1[c]) + fmaxf(acc[dy * 2 + 1][m][n2][c] + bv[c], 0.f);
            *reinterpret_cast<float2*>(outc + ((size_t)(n * CO + co0 + c) * Ho + oy) * Wo + qx2) = st;
          }
        }
      }
    }
  }
}

// ---------------- stage 1: partial spatial max (NHWC bf16), vectorized ----------
__global__ __launch_bounds__(256) void k_max_part(const unsigned short* __restrict__ x,
                                                  float* __restrict__ pmax) {
  int n = blockIdx.x >> 3, pg = blockIdx.x & 7;
  int t = threadIdx.x;
  int c8 = t & 31;   // 8-channel group (8*32 = 256 ch)
  int ps = t >> 5;   // p-slice 0..7 (16 rows each)
  const unsigned short* base = x + (size_t)n * 262144 + (size_t)pg * 32768 + (size_t)c8 * 8;
  float m[8];
#pragma unroll
  for (int j = 0; j < 8; ++j) m[j] = -1e30f;
  for (int p = ps * 16; p < ps * 16 + 16; ++p) {
    short8 v = *reinterpret_cast<const short8*>(base + (size_t)p * 256);
#pragma unroll
    for (int j = 0; j < 8; ++j) m[j] = fmaxf(m[j], bf2f((unsigned short)v[j]));
  }
  __shared__ float sred[8][264];
#pragma unroll
  for (int j = 0; j < 8; ++j) sred[ps][c8 * 8 + j] = m[j];
  __syncthreads();
  float mm = sred[0][t];
#pragma unroll
  for (int g = 1; g < 8; ++g) mm = fmaxf(mm, sred[g][t]);
  pmax[((size_t)n * 8 + pg) * 256 + t] = mm;
}

// ---------------- stage 2: combine partials + LayerNorm over 256 channels ----------
__global__ __launch_bounds__(256) void k_ln(const float* __restrict__ pmax,
                                            float* __restrict__ out) {
  int n = blockIdx.x, ch = threadIdx.x;
  float m = -1e30f;
#pragma unroll
  for (int g = 0; g < 8; ++g)
    m = fmaxf(m, pmax[((size_t)n * 8 + g) * 256 + ch]);
  __shared__ float r1[256], r2[256];
  r1[ch] = m; __syncthreads();
  for (int s = 128; s > 0; s >>= 1) { if (ch < s) r1[ch] += r1[ch + s]; __syncthreads(); }
  float mu = r1[0] * (1.f / 256.f);
  float d = m - mu;
  r2[ch] = d * d; __syncthreads();
  for (int s = 128; s > 0; s >>= 1) { if (ch < s) r2[ch] += r2[ch + s]; __syncthreads(); }
  out[(size_t)n * 256 + ch] = d * rsqrtf(r2[0] * (1.f / 256.f) + 1e-5f);
}

// ---------------- build node features ----------------
__global__ void k_build_x(const float* __restrict__ vn, const float* __restrict__ dn,
                          const float* __restrict__ tn, float* __restrict__ x0) {
  int b = blockIdx.x, ch = threadIdx.x;
  float s = 0.f;
  for (int f = 0; f < 8; ++f) {
    float vv = vn[((size_t)b * 8 + f) * 256 + ch];
    float dd = dn[((size_t)b * 8 + f) * 256 + ch];
    s += vv + dd;
    x0[((size_t)b * 18 + f) * 256 + ch] = vv;
    x0[((size_t)b * 18 + 8 + f) * 256 + ch] = dd;
  }
  float tv = tn[(size_t)b * 256 + ch];
  x0[((size_t)b * 18 + 16) * 256 + ch] = tv;
  x0[((size_t)b * 18 + 17) * 256 + ch] = tv + s * (1.f / 8.f);
}

// ---------------- GNN linear ----------------
__global__ __launch_bounds__(256) void k_gnn_lin(
    const float* __restrict__ x, const float* __restrict__ ea,
    const float* __restrict__ w, float* __restrict__ y, int K, int M) {
  int chunks = M >> 8;
  int r = blockIdx.x / chunks;
  int ob = (blockIdx.x % chunks) * 256 + threadIdx.x;
  const float* src = (r < 36) ? (x + (size_t)r * K) : (ea + (size_t)(r - 36) * K);
  __shared__ __align__(16) float sxr[512];
  for (int k = threadIdx.x; k < K; k += 256) sxr[k] = src[k];
  __syncthreads();
  const float4* w4 = reinterpret_cast<const float4*>(w + (size_t)ob * K);
  const float4* x4 = reinterpret_cast<const float4*>(sxr);
  float acc = 0.f;
  int k4 = K >> 2;
  for (int k = 0; k < k4; ++k) {
    float4 a = x4[k], b = w4[k];
    acc += a.x * b.x + a.y * b.y + a.z * b.z + a.w * b.w;
  }
  y[(size_t)r * M + ob] = acc;
}

// ---------------- fused attention dots + logits + segment softmax -> attw(134,4) ------
template<int OC>
__global__ __launch_bounds__(256) void k_gnn_attsm(
    const float* __restrict__ y, const float* __restrict__ att,
    float* __restrict__ attw) {
  int t = threadIdx.x;
  __shared__ float sx_s[144], seb_s[60];
  __shared__ float a_s[536];
  if (t < 200) {
    int r = t >> 2, h = t & 3;
    const float4* row = reinterpret_cast<const float4*>(y + ((size_t)r * 4 + h) * OC);
    const float4* ar = reinterpret_cast<const float4*>(att + (size_t)h * 2 * OC + (r < 36 ? 0 : OC));
    float s = 0.f;
#pragma unroll 4
    for (int k = 0; k < OC / 4; ++k) {
      float4 a = row[k], b = ar[k];
      s += a.x * b.x + a.y * b.y + a.z * b.z + a.w * b.w;
    }
    if (r < 36) sx_s[r * 4 + h] = s; else seb_s[(r - 36) * 4 + h] = s;
  }
  __syncthreads();
  for (int idx = t; idx < 536; idx += 256) {
    int i = idx >> 2, h = idx & 3;
    float v = sx_s[c_row[i] * 4 + h] + seb_s[c_col[i] * 4 + h];
    a_s[idx] = (v > 0.f) ? v : 0.2f * v;
  }
  __syncthreads();
  if (t < 56) {
    int c = t >> 2, h = t & 3;
    int st = c_cs[c], en = c_cs[c + 1];
    float m = -1e30f;
    for (int i = st; i < en; ++i) m = fmaxf(m, a_s[i * 4 + h]);
    float s = 0.f;
    for (int i = st; i < en; ++i) { float e = __expf(a_s[i * 4 + h] - m); a_s[i * 4 + h] = e; s += e; }
    float inv = 1.f / (s + 1e-16f);
    for (int i = st; i < en; ++i) a_s[i * 4 + h] *= inv;
  }
  __syncthreads();
  for (int idx = t; idx < 536; idx += 256) attw[idx] = a_s[idx];
}

// ---------------- edge aggregation ----------------
template<int OC>
__global__ __launch_bounds__(256) void k_edge_agg(
    const float* __restrict__ y, const float* __restrict__ attw,
    float* __restrict__ eb) {
  int idx = blockIdx.x * 256 + threadIdx.x;
  if (idx >= 14 * 4 * OC) return;
  int ch = idx % OC;
  int h = (idx / OC) & 3;
  int c = idx / (4 * OC);
  int st = c_cs[c], en = c_cs[c + 1];
  float s = 0.f;
  for (int i = st; i < en; ++i)
    s += attw[i * 4 + h] * y[(size_t)c_row[i] * (4 * OC) + h * OC + ch];
  eb[idx] = s * (1.f / (float)(en - st));
}

// ---------------- node aggregation ----------------
template<int OC>
__global__ __launch_bounds__(256) void k_node_agg(
    const float* __restrict__ attw, const float* __restrict__ eb,
    const float* __restrict__ ew, float* __restrict__ ho) {
  int idx = blockIdx.x * 256 + threadIdx.x;
  if (idx >= 36 * OC) return;
  int ch = idx % OC;
  int node = idx / OC;
  int b = node / 18, ln = node % 18;
  int ncols, cols[4], gis[4];
  if (ln < 16) {
    ncols = 4;
    cols[0] = b * 7 + (ln < 8 ? 0 : 1); gis[0] = b * 67 + ln;
    cols[1] = b * 7 + 2; gis[1] = b * 67 + 16 + ln;
    cols[2] = b * 7 + 3; gis[2] = b * 67 + 32 + ln;
    cols[3] = b * 7 + 4; gis[3] = b * 67 + 48 + ln;
  } else if (ln == 16) {
    ncols = 2;
    cols[0] = b * 7 + 4; gis[0] = b * 67 + 64;
    cols[1] = b * 7 + 5; gis[1] = b * 67 + 65;
    cols[2] = cols[3] = 0; gis[2] = gis[3] = 0;
  } else {
    ncols = 1;
    cols[0] = b * 7 + 6; gis[0] = b * 67 + 66;
    cols[1] = cols[2] = cols[3] = 0; gis[1] = gis[2] = gis[3] = 0;
  }
  float dsum = 0.f;
#pragma unroll
  for (int k = 0; k < 4; ++k) if (k < ncols) dsum += ew[cols[k]];
  float D = dsum > 0.f ? 1.f / dsum : 0.f;
  float s = 0.f;
#pragma unroll
  for (int k = 0; k < 4; ++k) {
    if (k < ncols) {
#pragma unroll
      for (int h = 0; h < 4; ++h)
        s += attw[gis[k] * 4 + h] * eb[((size_t)cols[k] * 4 + h) * OC + ch];
    }
  }
  ho[idx] = fmaxf(0.25f * D * s, 0.f);
}

// ---------------- GroupNorm(32) + SE layer ----------------
template<int C, int Cr>
__global__ __launch_bounds__(512) void k_gn_se(
    const float* __restrict__ hin, const float* __restrict__ w1,
    const float* __restrict__ w2, float* __restrict__ x) {
  int t = threadIdx.x;
  constexpr int gs = C >> 5;
  for (int idx = t; idx < 36 * 32; idx += 512) {
    int node = idx >> 5, g = idx & 31;
    const float* p = hin + (size_t)node * C + g * gs;
    float s = 0.f, s2 = 0.f;
#pragma unroll
    for (int k = 0; k < gs; ++k) { float v = p[k]; s += v; s2 += v * v; }
    float mu = s * (1.f / gs);
    float var = s2 * (1.f / gs) - mu * mu;
    float inv = rsqrtf(fmaxf(var, 0.f) + 1e-5f);
    float* q = x + (size_t)node * C + g * gs;
#pragma unroll
    for (int k = 0; k < gs; ++k) q[k] = (p[k] - mu) * inv;
  }
  __threadfence_block();
  __syncthreads();
  __shared__ float smean[C];
  __shared__ float spart[Cr][17];
  __shared__ float shid[Cr];
  __shared__ float sscale[C];
  if (t < C) {
    float s = 0.f;
    for (int nn = 0; nn < 36; ++nn) s += x[(size_t)nn * C + t];
    smean[t] = s * (1.f / 36.f);
  }
  __syncthreads();
  if (t < Cr * 16) {
    int hid = t >> 4, sub = t & 15;
    constexpr int CH = C / 16;
    float s = 0.f;
#pragma unroll
    for (int k = 0; k < CH; ++k)
      s += w1[(size_t)hid * C + sub * CH + k] * smean[sub * CH + k];
    spart[hid][sub] = s;
  }
  __syncthreads();
  if (t < Cr) {
    float s = 0.f;
#pragma unroll
    for (int k = 0; k < 16; ++k) s += spart[t][k];
    shid[t] = fmaxf(s, 0.f);
  }
  __syncthreads();
  if (t < C) {
    float s = 0.f;
#pragma unroll
    for (int k = 0; k < Cr; ++k) s += w2[(size_t)t * Cr + k] * shid[k];
    sscale[t] = 1.f / (1.f + __expf(-s));
  }
  __syncthreads();
  for (int idx = t; idx < 36 * C; idx += 512) x[idx] *= sscale[idx % C];
}

// ---------------- observers ----------------
__global__ void k_obs(const float* __restrict__ tn, const float* __restrict__ x2,
                      float* __restrict__ out) {
  int t = threadIdx.x;
  if (t >= 128) return;
  int b = t >> 6, ch = t & 63;
  const float* a = tn + (size_t)b * 256 + ch * 4;
  const float* c = x2 + ((size_t)b * 18 + 17) * 256 + ch * 4;
  float m = a[0] + c[0];
  m = fmaxf(m, a[1] + c[1]);
  m = fmaxf(m, a[2] + c[2]);
  m = fmaxf(m, a[3] + c[3]);
  out[b * 64 + ch] = m;
}

extern "C" void kernel_launch(void* const* d_in, const int* in_sizes, int n_in,
                              void* d_out, int out_size, void* d_ws, size_t ws_size,
                              hipStream_t stream) {
  (void)in_sizes; (void)n_in; (void)out_size; (void)ws_size;
  const float* vf    = (const float*)d_in[0];
  const float* vp    = (const float*)d_in[1];
  const float* mf    = (const float*)d_in[2];
  const float* mp    = (const float*)d_in[3];
  const float* tf    = (const float*)d_in[4];
  const float* tp    = (const float*)d_in[5];
  const float* cv1w  = (const float*)d_in[6];
  const float* cv1b  = (const float*)d_in[7];
  const float* cv2w  = (const float*)d_in[8];
  const float* cv2b  = (const float*)d_in[9];
  const float* dc1w  = (const float*)d_in[10];
  const float* dc1b  = (const float*)d_in[11];
  const float* dc2w  = (const float*)d_in[12];
  const float* dc2b  = (const float*)d_in[13];
  const float* tc1w  = (const float*)d_in[14];
  const float* tc1b  = (const float*)d_in[15];
  const float* tc2w  = (const float*)d_in[16];
  const float* tc2b  = (const float*)d_in[17];
  const float* lin1w = (const float*)d_in[18];
  const float* att1  = (const float*)d_in[19];
  const float* lin2w = (const float*)d_in[20];
  const float* att2  = (const float*)d_in[21];
  const float* ew1   = (const float*)d_in[22];
  const float* ew2   = (const float*)d_in[23];
  const float* ea1   = (const float*)d_in[24];
  const float* ea2   = (const float*)d_in[25];
  const float* se1w1 = (const float*)d_in[26];
  const float* se1w2 = (const float*)d_in[27];
  const float* se2w1 = (const float*)d_in[28];
  const float* se2w2 = (const float*)d_in[29];

  float* ws  = (float*)d_ws;
  float* out = (float*)d_out;

  // workspace layout (float units)
  unsigned short* p0n = (unsigned short*)(ws);             // 16x128x128x64 bf16 (vf+vp NHWC)
  unsigned short* q1n = (unsigned short*)(ws + 8388608);   // 16x64x64x128 bf16 (d1n/v1n)
  unsigned short* t1n = (unsigned short*)(ws + 12582912);  // 16x64x64x128 bf16
  unsigned short* v2n = (unsigned short*)(ws + 16777216);  // 16x32x32x256 bf16 (d2n/v2n)
  unsigned short* wtb = (unsigned short*)(ws + 18874368);  // 1,105,920 bf16
  float* sm   = ws + 19427328;
  float* tn   = sm;                 // 512
  float* vn   = sm + 512;           // 4096
  float* dn   = sm + 4608;          // 4096
  float* x0   = sm + 8704;          // 9216
  float* xl   = sm + 17920;         // 102400
  float* eb   = sm + 120520;        // 28672
  float* ho   = sm + 149192;        // 18432
  float* x1   = sm + 167624;        // 18432
  float* x2   = sm + 186056;        // 9216
  float* attw = sm + 195272;        // 536
  float* pmax = sm + 195904;        // 32768 (16 n x 8 pg x 256 ch)

  unsigned short* wTc1 = wtb;             // 9*128*64
  unsigned short* wTd1 = wtb + 73728;
  unsigned short* wTc2 = wtb + 147456;    // 9*256*128
  unsigned short* wTd2 = wtb + 442368;
  unsigned short* wTt1 = wtb + 737280;    // 9*128*256 (tc1: in256->out128)
  unsigned short* wTt2 = wtb + 1032192;   // 9*64*128  (tc2: in128->out64)

  // 0. all weight transforms (one kernel)
  k_wtrans_all<<<4320, 256, 0, stream>>>(cv1w, dc1w, cv2w, dc2w, tc1w, tc2w, wtb);

  // 1. text pooling
  k_text_pool<<<2, 256, 0, stream>>>(tf, tp, tn);

  // 2. motion branch (uses p0n as scratch; overwritten by vision prep later)
  k_prep<<<4096, 256, 0, stream>>>(mf, mp, p0n);
  k_conv_mfma<64, 128, 64, 64, 1><<<1024, 512, 0, stream>>>(p0n, wTd1, dc1b, q1n);
  k_conv_mfma<128, 256, 32, 32, 2><<<512, 512, 0, stream>>>(q1n, wTd2, dc2b, v2n);
  k_max_part<<<128, 256, 0, stream>>>(v2n, pmax);
  k_ln<<<16, 256, 0, stream>>>(pmax, dn);

  // 3. vision branch (p0n kept = bf16(vf+vp); q1n = v1n kept as deconv1 residual)
  k_prep<<<4096, 256, 0, stream>>>(vf, vp, p0n);
  k_conv_mfma<64, 128, 64, 64, 1><<<1024, 512, 0, stream>>>(p0n, wTc1, cv1b, q1n);
  k_conv_mfma<128, 256, 32, 32, 2><<<512, 512, 0, stream>>>(q1n, wTc2, cv2b, v2n);
  k_max_part<<<128, 256, 0, stream>>>(v2n, pmax);
  k_ln<<<16, 256, 0, stream>>>(pmax, vn);

  // 4. node features
  k_build_x<<<2, 256, 0, stream>>>(vn, dn, tn, x0);

  // 5. GNN layer 1 (OC=512)
  k_gnn_lin<<<50 * 8, 256, 0, stream>>>(x0, ea1, lin1w, xl, 256, 2048);
  k_gnn_attsm<512><<<1, 256, 0, stream>>>(xl, att1, attw);
  k_edge_agg<512><<<112, 256, 0, stream>>>(xl, attw, eb);
  k_node_agg<512><<<72, 256, 0, stream>>>(attw, eb, ew1, ho);
  k_gn_se<512, 32><<<1, 512, 0, stream>>>(ho, se1w1, se1w2, x1);

  // 6. GNN layer 2 (OC=256)
  k_gnn_lin<<<50 * 4, 256, 0, stream>>>(x1, ea2, lin2w, xl, 512, 1024);
  k_gnn_attsm<256><<<1, 256, 0, stream>>>(xl, att2, attw);
  k_edge_agg<256><<<56, 256, 0, stream>>>(xl, attw, eb);
  k_node_agg<256><<<36, 256, 0, stream>>>(attw, eb, ew2, ho);
  k_gn_se<256, 16><<<1, 512, 0, stream>>>(ho, se2w1, se2w2, x2);

  // 7. observers
  k_obs<<<1, 128, 0, stream>>>(tn, x2, out + 16777216);

  // 8. decoder: t1n = v1n + relu(convT1(v2n + vg[fused])) ; out = bf16(vf+vp) + relu(convT2(t1n))
  k_deconv_mfma<256, 128, 32, 32, 2, true, true><<<512, 256, 0, stream>>>(
      v2n, wTt1, tc1b, q1n, x2, t1n, nullptr);
  k_deconv_mfma<128, 64, 64, 64, 1, false, false><<<1024, 256, 0, stream>>>(
      t1n, wTt2, tc2b, p0n, nullptr, nullptr, out);
}

// Round 10
// 482.701 us; speedup vs baseline: 7.7479x; 1.0081x over previous
//
#include <hip/hip_runtime.h>
#include <hip/hip_bf16.h>
#include <cstddef>
#include <cstdint>

#define DEV_INLINE __device__ __forceinline__

typedef __attribute__((ext_vector_type(8))) short short8;
typedef __attribute__((ext_vector_type(4))) float f32x4;
typedef __attribute__((ext_vector_type(2))) float f32x2;
typedef __attribute__((ext_vector_type(4))) unsigned short us4;

DEV_INLINE unsigned short f2bf(float f) {
  uint32_t u = __builtin_bit_cast(uint32_t, f);
  uint32_t r = (u + 0x7fffu + ((u >> 16) & 1u)) >> 16;
  return (unsigned short)r;
}
DEV_INLINE float bf2f(unsigned short u) {
  return __builtin_bit_cast(float, (uint32_t)u << 16);
}

// Problem constants: BS=2, F=8, C=64, H=128, W=128, HEADS=4
__device__ __constant__ int c_cs[15] = {0,8,16,32,48,65,66,67,75,83,99,115,132,133,134};
__device__ __constant__ int c_row[134] = {
  0,1,2,3,4,5,6,7,
  8,9,10,11,12,13,14,15,
  0,1,2,3,4,5,6,7,8,9,10,11,12,13,14,15,
  0,1,2,3,4,5,6,7,8,9,10,11,12,13,14,15,
  0,1,2,3,4,5,6,7,8,9,10,11,12,13,14,15,16,
  16,
  17,
  18,19,20,21,22,23,24,25,
  26,27,28,29,30,31,32,33,
  18,19,20,21,22,23,24,25,26,27,28,29,30,31,32,33,
  18,19,20,21,22,23,24,25,26,27,28,29,30,31,32,33,
  18,19,20,21,22,23,24,25,26,27,28,29,30,31,32,33,34,
  34,
  35
};
__device__ __constant__ int c_col[134] = {
  0,0,0,0,0,0,0,0,
  1,1,1,1,1,1,1,1,
  2,2,2,2,2,2,2,2,2,2,2,2,2,2,2,2,
  3,3,3,3,3,3,3,3,3,3,3,3,3,3,3,3,
  4,4,4,4,4,4,4,4,4,4,4,4,4,4,4,4,4,
  5,
  6,
  7,7,7,7,7,7,7,7,
  8,8,8,8,8,8,8,8,
  9,9,9,9,9,9,9,9,9,9,9,9,9,9,9,9,
  10,10,10,10,10,10,10,10,10,10,10,10,10,10,10,10,
  11,11,11,11,11,11,11,11,11,11,11,11,11,11,11,11,11,
  12,
  13
};

// ---------------- input prep: (a+b) NCHW fp32 -> NHWC bf16 (conflict-free) ----------
__global__ __launch_bounds__(256) void k_prep(const float* __restrict__ a,
                                              const float* __restrict__ b,
                                              unsigned short* __restrict__ o) {
  int bid = blockIdx.x;
  int xb = bid & 1, y = (bid >> 1) & 127, n = bid >> 8;
  __shared__ unsigned int su[32][65];
  int t = threadIdx.x;
  const size_t base = ((size_t)n * 64) * 16384 + (size_t)y * 128 + xb * 64;
  float4 A0[2], B0[2], A1[2], B1[2];
#pragma unroll
  for (int it = 0; it < 2; ++it) {
    int i = t + it * 256;
    int cpair = i >> 4, x4 = i & 15;
    size_t off = base + (size_t)(2 * cpair) * 16384 + x4 * 4;
    A0[it] = *reinterpret_cast<const float4*>(a + off);
    B0[it] = *reinterpret_cast<const float4*>(b + off);
    A1[it] = *reinterpret_cast<const float4*>(a + off + 16384);
    B1[it] = *reinterpret_cast<const float4*>(b + off + 16384);
  }
#pragma unroll
  for (int it = 0; it < 2; ++it) {
    int i = t + it * 256;
    int cpair = i >> 4, x4 = i & 15;
    unsigned int* row = &su[cpair][x4 * 4];
    row[0] = (unsigned int)f2bf(A0[it].x + B0[it].x) | ((unsigned int)f2bf(A1[it].x + B1[it].x) << 16);
    row[1] = (unsigned int)f2bf(A0[it].y + B0[it].y) | ((unsigned int)f2bf(A1[it].y + B1[it].y) << 16);
    row[2] = (unsigned int)f2bf(A0[it].z + B0[it].z) | ((unsigned int)f2bf(A1[it].z + B1[it].z) << 16);
    row[3] = (unsigned int)f2bf(A0[it].w + B0[it].w) | ((unsigned int)f2bf(A1[it].w + B1[it].w) << 16);
  }
  __syncthreads();
  unsigned int* op = (unsigned int*)(o + (((size_t)n * 128 + y) * 128 + xb * 64) * 64);
#pragma unroll
  for (int it = 0; it < 2; ++it) {
    int i = t + it * 256;
    int x = i >> 3, cq = i & 7;
    uint4 v;
    v.x = su[cq * 4 + 0][x];
    v.y = su[cq * 4 + 1][x];
    v.z = su[cq * 4 + 2][x];
    v.w = su[cq * 4 + 3][x];
    *reinterpret_cast<uint4*>(op + x * 32 + cq * 4) = v;
  }
}

// ---------------- all weight transforms -> wT[tap][co][ci] bf16, one kernel ----------
__global__ void k_wtrans_all(const float* __restrict__ cv1w, const float* __restrict__ dc1w,
                             const float* __restrict__ cv2w, const float* __restrict__ dc2w,
                             const float* __restrict__ tc1w, const float* __restrict__ tc2w,
                             unsigned short* __restrict__ wtb) {
  int idx = blockIdx.x * 256 + threadIdx.x;
  const float* src; int off, lci, lco; bool tra;
  if (idx < 73728)        { src = cv1w; off = 0;       lci = 6; lco = 7; tra = false; }
  else if (idx < 147456)  { src = dc1w; off = 73728;   lci = 6; lco = 7; tra = false; }
  else if (idx < 442368)  { src = cv2w; off = 147456;  lci = 7; lco = 8; tra = false; }
  else if (idx < 737280)  { src = dc2w; off = 442368;  lci = 7; lco = 8; tra = false; }
  else if (idx < 1032192) { src = tc1w; off = 737280;  lci = 8; lco = 7; tra = true;  }
  else if (idx < 1105920) { src = tc2w; off = 1032192; lci = 7; lco = 6; tra = true;  }
  else return;
  int l = idx - off;
  int ci = l & ((1 << lci) - 1);
  int r = l >> lci;
  int co = r & ((1 << lco) - 1);
  int tap = r >> lco;
  size_t si = tra ? (((size_t)ci << lco) + co) * 9 + tap
                  : (((size_t)co << lci) + ci) * 9 + tap;
  wtb[idx] = f2bf(src[si]);
}

// ---------------- Conv2d k3 s2 p1 + bias + ReLU via bf16 MFMA (pipelined) ----------
template<int CI, int CO, int HO, int WO, int ROUT>
__global__ __launch_bounds__(512, 3) void k_conv_mfma(
    const unsigned short* __restrict__ in,   // NHWC bf16 [N][2HO][2WO][CI]
    const unsigned short* __restrict__ wT,   // [9][CO][CI] bf16
    const float* __restrict__ bias,
    unsigned short* __restrict__ outn) {     // NHWC bf16 [N][HO][WO][CO]
  constexpr int HIN = HO * 2, WIN = WO * 2;
  constexpr int XHP = WO + 2;
  constexpr int R = 2 * ROUT + 1;
  constexpr int NPOS = R * 2 * XHP;
  constexpr int NCH = NPOS * 4;
  constexpr int NCS = CI / 32;
  constexpr int KIT = (NCH + 511) / 512;
  constexpr int CB = CO / 128;
  constexpr int OB = HO / ROUT;
  __shared__ short8 sIn[NPOS * 5];
  int bid = blockIdx.x;
  int cb = bid % CB; bid /= CB;
  int oyb = bid % OB; int n = bid / OB;
  int tid = threadIdx.x;
  int wid = tid >> 6, lane = tid & 63;
  int wm = wid >> 1, wn = wid & 1;
  int llo = lane & 15, lhi = lane >> 4;
  f32x4 acc[2][2] = {};
  const int iy0 = oyb * (2 * ROUT) - 1;
  short8 rv[KIT];
  auto loadr = [&](int cs) {
#pragma unroll
    for (int k = 0; k < KIT; ++k) {
      int i = tid + k * 512;
      short8 v = {};
      if (i < NCH) {
        int c = i & 3, q = i >> 2;
        int xh = q % XHP; int q2 = q / XHP;
        int p = q2 & 1, l = q2 >> 1;
        int x = 2 * xh + p - 1;
        int iy = iy0 + l;
        if (x >= 0 && x < WIN && iy >= 0 && iy < HIN)
          v = *reinterpret_cast<const short8*>(in + ((((size_t)n * HIN + iy) * WIN + x) * CI + cs * 32 + c * 8));
      }
      rv[k] = v;
    }
  };
  auto writes = [&]() {
#pragma unroll
    for (int k = 0; k < KIT; ++k) {
      int i = tid + k * 512;
      if (i < NCH) sIn[(i >> 2) * 5 + (i & 3)] = rv[k];
    }
  };
  loadr(0);
  for (int cs = 0; cs < NCS; ++cs) {
    writes();
    __syncthreads();
    if (cs + 1 < NCS) loadr(cs + 1);
    // preload all 18 weight fragments for this K-step (batched, full MLP)
    short8 afr9[9][2];
#pragma unroll
    for (int tap = 0; tap < 9; ++tap)
#pragma unroll
      for (int m = 0; m < 2; ++m) {
        int co = cb * 128 + wm * 32 + m * 16 + llo;
        afr9[tap][m] = *reinterpret_cast<const short8*>(wT + (((size_t)tap * CO + co) * CI + cs * 32 + lhi * 8));
      }
#pragma unroll
    for (int tap = 0; tap < 9; ++tap) {
      const int ky = tap / 3, kx = tap % 3;
      short8 bfr[2];
#pragma unroll
      for (int n2 = 0; n2 < 2; ++n2) {
        int pix = wn * 32 + n2 * 16 + llo;
        int oyl = (ROUT == 2) ? (pix >> 5) : 0;
        int ox = pix - oyl * WO;
        int lrow = 2 * oyl + ky;
        int pos = (lrow * 2 + (kx & 1)) * XHP + ox + (kx >> 1);
        bfr[n2] = sIn[pos * 5 + lhi];
      }
#pragma unroll
      for (int m = 0; m < 2; ++m)
#pragma unroll
        for (int n2 = 0; n2 < 2; ++n2)
          acc[m][n2] = __builtin_amdgcn_mfma_f32_16x16x32_bf16(afr9[tap][m], bfr[n2], acc[m][n2], 0, 0, 0);
    }
    __syncthreads();
  }
#pragma unroll
  for (int m = 0; m < 2; ++m) {
    int co0 = cb * 128 + wm * 32 + m * 16 + lhi * 4;
    f32x4 bv = *reinterpret_cast<const f32x4*>(bias + co0);
#pragma unroll
    for (int n2 = 0; n2 < 2; ++n2) {
      int pix = wn * 32 + n2 * 16 + llo;
      int oyl = (ROUT == 2) ? (pix >> 5) : 0;
      int ox = pix - oyl * WO;
      int oy = oyb * ROUT + oyl;
      us4 pk;
      pk[0] = f2bf(fmaxf(acc[m][n2][0] + bv[0], 0.f));
      pk[1] = f2bf(fmaxf(acc[m][n2][1] + bv[1], 0.f));
      pk[2] = f2bf(fmaxf(acc[m][n2][2] + bv[2], 0.f));
      pk[3] = f2bf(fmaxf(acc[m][n2][3] + bv[3], 0.f));
      *reinterpret_cast<us4*>(outn + ((((size_t)n * HO + oy) * WO + ox) * CO + co0)) = pk;
    }
  }
}

// ---------------- ConvTranspose2d k3 s2 p1 op1 via bf16 MFMA (pipelined) ------
template<int CI, int CO, int Hi, int Wi, int QR, bool OBF, bool GADD>
__global__ __launch_bounds__(256, 3) void k_deconv_mfma(
    const unsigned short* __restrict__ in,   // NHWC bf16 [N][Hi][Wi][CI]
    const unsigned short* __restrict__ wT,   // [9][CO][CI] bf16 (w[ci][co][ky][kx])
    const float* __restrict__ bias,
    const unsigned short* __restrict__ resn, // NHWC bf16 residual
    const float* __restrict__ gsrc,          // GADD: x2 node features (per-frame 256ch)
    unsigned short* __restrict__ outn,       // NHWC bf16 [N][2Hi][2Wi][CO]
    float* __restrict__ outc) {              // NCHW fp32
  constexpr int QC = 64 / QR;
  constexpr int WP = Wi + 1;
  constexpr int NPOS = (QR + 1) * WP;
  constexpr int NCH = NPOS * 4;
  constexpr int NCS = CI / 32;
  constexpr int KIT = (NCH + 255) / 256;
  constexpr int CB = CO / 64;
  constexpr int OB = Hi / QR;
  constexpr int Ho = Hi * 2, Wo = Wi * 2;
  __shared__ short8 sIn[NPOS * 5];
  int bid = blockIdx.x;
  int cb = bid % CB; bid /= CB;
  int oyb = bid % OB; int n = bid / OB;
  int tid = threadIdx.x;
  int wid = tid >> 6, lane = tid & 63;
  int wm = wid >> 1, wn = wid & 1;
  int llo = lane & 15, lhi = lane >> 4;
  int qy0 = oyb * QR;
  const float* g = nullptr;
  if constexpr (GADD) g = gsrc + ((size_t)((n >> 3) * 18 + (n & 7))) * 256;
  f32x4 acc[4][2][2] = {};
  constexpr int tap_p[9] = {3,2,3,1,0,1,3,2,3};
  constexpr int tap_b[9] = {3,2,2,1,0,0,1,0,0};
  short8 rv[KIT];
  auto loadr = [&](int cs) {
#pragma unroll
    for (int k = 0; k < KIT; ++k) {
      int i = tid + k * 256;
      short8 v = {};
      if (i < NCH) {
        int c = i & 3, q = i >> 2;
        int x = q % WP, l = q / WP;
        int iy = qy0 + l;
        if (x < Wi && iy < Hi) {
          v = *reinterpret_cast<const short8*>(in + (((size_t)(n * Hi + iy) * Wi + x) * CI + cs * 32 + c * 8));
          if constexpr (GADD) {
#pragma unroll
            for (int j = 0; j < 8; ++j) {
              float fv = bf2f((unsigned short)v[j]) + g[cs * 32 + c * 8 + j];
              v[j] = (short)f2bf(fv);
            }
          }
        }
      }
      rv[k] = v;
    }
  };
  auto writes = [&]() {
#pragma unroll
    for (int k = 0; k < KIT; ++k) {
      int i = tid + k * 256;
      if (i < NCH) sIn[(i >> 2) * 5 + (i & 3)] = rv[k];
    }
  };
  loadr(0);
  for (int cs = 0; cs < NCS; ++cs) {
    writes();
    __syncthreads();
    if (cs + 1 < NCS) loadr(cs + 1);
    short8 bfr[2][4];
#pragma unroll
    for (int n2 = 0; n2 < 2; ++n2) {
      int pix = wn * 32 + n2 * 16 + llo;
      int qyl = pix / QC, qx = pix % QC;
#pragma unroll
      for (int bs = 0; bs < 4; ++bs) {
        int pos = (qyl + (bs >> 1)) * WP + qx + (bs & 1);
        bfr[n2][bs] = sIn[pos * 5 + lhi];
      }
    }
#pragma unroll
    for (int m = 0; m < 2; ++m) {
      // preload this m's 9 weight fragments (batched)
      short8 afr9[9];
#pragma unroll
      for (int tap = 0; tap < 9; ++tap) {
        int co = cb * 64 + wm * 32 + m * 16 + llo;
        afr9[tap] = *reinterpret_cast<const short8*>(wT + (((size_t)tap * CO + co) * CI + cs * 32 + lhi * 8));
      }
#pragma unroll
      for (int tap = 0; tap < 9; ++tap)
#pragma unroll
        for (int n2 = 0; n2 < 2; ++n2)
          acc[tap_p[tap]][m][n2] = __builtin_amdgcn_mfma_f32_16x16x32_bf16(
              afr9[tap], bfr[n2][tap_b[tap]], acc[tap_p[tap]][m][n2], 0, 0, 0);
    }
    __syncthreads();
  }
#pragma unroll
  for (int m = 0; m < 2; ++m) {
    int co0 = cb * 64 + wm * 32 + m * 16 + lhi * 4;
    f32x4 bv = *reinterpret_cast<const f32x4*>(bias + co0);
#pragma unroll
    for (int n2 = 0; n2 < 2; ++n2) {
      int pix = wn * 32 + n2 * 16 + llo;
      int qyl = pix / QC, qx = pix % QC;
      int qy = qy0 + qyl;
      if constexpr (OBF) {
#pragma unroll
        for (int p = 0; p < 4; ++p) {
          int oy = 2 * qy + (p >> 1);
          int ox = 2 * qx + (p & 1);
          size_t ad = ((size_t)(n * Ho + oy) * Wo + ox) * CO + co0;
          us4 r = *reinterpret_cast<const us4*>(resn + ad);
          us4 pk;
#pragma unroll
          for (int c = 0; c < 4; ++c)
            pk[c] = f2bf(bf2f(r[c]) + fmaxf(acc[p][m][n2][c] + bv[c], 0.f));
          *reinterpret_cast<us4*>(outn + ad) = pk;
        }
      } else {
        int qx2 = 2 * qx;
#pragma unroll
        for (int dy = 0; dy < 2; ++dy) {
          int oy = 2 * qy + dy;
          size_t rb = ((size_t)(n * Ho + oy) * Wo + qx2) * CO + co0;
          us4 r0 = *reinterpret_cast<const us4*>(resn + rb);
          us4 r1 = *reinterpret_cast<const us4*>(resn + rb + CO);
#pragma unroll
          for (int c = 0; c < 4; ++c) {
            f32x2 st;
            st[0] = bf2f(r0[c]) + fmaxf(acc[dy * 2][m][n2][c] + bv[c], 0.f);
            st[1] = bf2f(r1[c]) + fmaxf(acc[dy * 2 + 1][m][n2][c] + bv[c], 0.f);
            // final output is never re-read: bypass caches
            __builtin_nontemporal_store(st,
                reinterpret_cast<f32x2*>(outc + ((size_t)(n * CO + co0 + c) * Ho + oy) * Wo + qx2));
          }
        }
      }
    }
  }
}

// ---------------- stage 1: partial spatial max (NHWC bf16), vectorized ----------
__global__ __launch_bounds__(256) void k_max_part(const unsigned short* __restrict__ x,
                                                  float* __restrict__ pmax) {
  int n = blockIdx.x >> 3, pg = blockIdx.x & 7;
  int t = threadIdx.x;
  int c8 = t & 31;
  int ps = t >> 5;
  const unsigned short* base = x + (size_t)n * 262144 + (size_t)pg * 32768 + (size_t)c8 * 8;
  float m[8];
#pragma unroll
  for (int j = 0; j < 8; ++j) m[j] = -1e30f;
  for (int p = ps * 16; p < ps * 16 + 16; ++p) {
    short8 v = *reinterpret_cast<const short8*>(base + (size_t)p * 256);
#pragma unroll
    for (int j = 0; j < 8; ++j) m[j] = fmaxf(m[j], bf2f((unsigned short)v[j]));
  }
  __shared__ float sred[8][264];
#pragma unroll
  for (int j = 0; j < 8; ++j) sred[ps][c8 * 8 + j] = m[j];
  __syncthreads();
  float mm = sred[0][t];
#pragma unroll
  for (int g = 1; g < 8; ++g) mm = fmaxf(mm, sred[g][t]);
  pmax[((size_t)n * 8 + pg) * 256 + t] = mm;
}

// ---------------- stage 2: combine partials + LayerNorm over 256 channels ----------
__global__ __launch_bounds__(256) void k_ln(const float* __restrict__ pmax,
                                            float* __restrict__ out) {
  int n = blockIdx.x, ch = threadIdx.x;
  float m = -1e30f;
#pragma unroll
  for (int g = 0; g < 8; ++g)
    m = fmaxf(m, pmax[((size_t)n * 8 + g) * 256 + ch]);
  __shared__ float r1[256], r2[256];
  r1[ch] = m; __syncthreads();
  for (int s = 128; s > 0; s >>= 1) { if (ch < s) r1[ch] += r1[ch + s]; __syncthreads(); }
  float mu = r1[0] * (1.f / 256.f);
  float d = m - mu;
  r2[ch] = d * d; __syncthreads();
  for (int s = 128; s > 0; s >>= 1) { if (ch < s) r2[ch] += r2[ch + s]; __syncthreads(); }
  out[(size_t)n * 256 + ch] = d * rsqrtf(r2[0] * (1.f / 256.f) + 1e-5f);
}

// ---------------- build node features (text pool fused in) ----------------
__global__ void k_build_x(const float* __restrict__ tf, const float* __restrict__ tp,
                          const float* __restrict__ vn, const float* __restrict__ dn,
                          float* __restrict__ tn, float* __restrict__ x0) {
  int b = blockIdx.x, ch = threadIdx.x;
  int c4 = ch >> 2, j = ch & 3;
  const float* p = tf + ((size_t)b * 64 + c4) * 16 + j * 4;
  const float* q = tp + ((size_t)b * 64 + c4) * 16 + j * 4;
  float tv = p[0] + q[0];
  tv = fmaxf(tv, p[1] + q[1]);
  tv = fmaxf(tv, p[2] + q[2]);
  tv = fmaxf(tv, p[3] + q[3]);
  tn[(size_t)b * 256 + ch] = tv;
  float s = 0.f;
  for (int f = 0; f < 8; ++f) {
    float vv = vn[((size_t)b * 8 + f) * 256 + ch];
    float dd = dn[((size_t)b * 8 + f) * 256 + ch];
    s += vv + dd;
    x0[((size_t)b * 18 + f) * 256 + ch] = vv;
    x0[((size_t)b * 18 + 8 + f) * 256 + ch] = dd;
  }
  x0[((size_t)b * 18 + 16) * 256 + ch] = tv;
  x0[((size_t)b * 18 + 17) * 256 + ch] = tv + s * (1.f / 8.f);
}

// ---------------- GNN linear ----------------
__global__ __launch_bounds__(256) void k_gnn_lin(
    const float* __restrict__ x, const float* __restrict__ ea,
    const float* __restrict__ w, float* __restrict__ y, int K, int M) {
  int chunks = M >> 8;
  int r = blockIdx.x / chunks;
  int ob = (blockIdx.x % chunks) * 256 + threadIdx.x;
  const float* src = (r < 36) ? (x + (size_t)r * K) : (ea + (size_t)(r - 36) * K);
  __shared__ __align__(16) float sxr[512];
  for (int k = threadIdx.x; k < K; k += 256) sxr[k] = src[k];
  __syncthreads();
  const float4* w4 = reinterpret_cast<const float4*>(w + (size_t)ob * K);
  const float4* x4 = reinterpret_cast<const float4*>(sxr);
  float acc = 0.f;
  int k4 = K >> 2;
  for (int k = 0; k < k4; ++k) {
    float4 a = x4[k], b = w4[k];
    acc += a.x * b.x + a.y * b.y + a.z * b.z + a.w * b.w;
  }
  y[(size_t)r * M + ob] = acc;
}

// ---------------- fused attention dots + logits + segment softmax -> attw(134,4) ------
template<int OC>
__global__ __launch_bounds__(256) void k_gnn_attsm(
    const float* __restrict__ y, const float* __restrict__ att,
    float* __restrict__ attw) {
  int t = threadIdx.x;
  __shared__ float sx_s[144], seb_s[60];
  __shared__ float a_s[536];
  if (t < 200) {
    int r = t >> 2, h = t & 3;
    const float4* row = reinterpret_cast<const float4*>(y + ((size_t)r * 4 + h) * OC);
    const float4* ar = reinterpret_cast<const float4*>(att + (size_t)h * 2 * OC + (r < 36 ? 0 : OC));
    float s = 0.f;
#pragma unroll 4
    for (int k = 0; k < OC / 4; ++k) {
      float4 a = row[k], b = ar[k];
      s += a.x * b.x + a.y * b.y + a.z * b.z + a.w * b.w;
    }
    if (r < 36) sx_s[r * 4 + h] = s; else seb_s[(r - 36) * 4 + h] = s;
  }
  __syncthreads();
  for (int idx = t; idx < 536; idx += 256) {
    int i = idx >> 2, h = idx & 3;
    float v = sx_s[c_row[i] * 4 + h] + seb_s[c_col[i] * 4 + h];
    a_s[idx] = (v > 0.f) ? v : 0.2f * v;
  }
  __syncthreads();
  if (t < 56) {
    int c = t >> 2, h = t & 3;
    int st = c_cs[c], en = c_cs[c + 1];
    float m = -1e30f;
    for (int i = st; i < en; ++i) m = fmaxf(m, a_s[i * 4 + h]);
    float s = 0.f;
    for (int i = st; i < en; ++i) { float e = __expf(a_s[i * 4 + h] - m); a_s[i * 4 + h] = e; s += e; }
    float inv = 1.f / (s + 1e-16f);
    for (int i = st; i < en; ++i) a_s[i * 4 + h] *= inv;
  }
  __syncthreads();
  for (int idx = t; idx < 536; idx += 256) attw[idx] = a_s[idx];
}

// ---------------- edge aggregation ----------------
template<int OC>
__global__ __launch_bounds__(256) void k_edge_agg(
    const float* __restrict__ y, const float* __restrict__ attw,
    float* __restrict__ eb) {
  int idx = blockIdx.x * 256 + threadIdx.x;
  if (idx >= 14 * 4 * OC) return;
  int ch = idx % OC;
  int h = (idx / OC) & 3;
  int c = idx / (4 * OC);
  int st = c_cs[c], en = c_cs[c + 1];
  float s = 0.f;
  for (int i = st; i < en; ++i)
    s += attw[i * 4 + h] * y[(size_t)c_row[i] * (4 * OC) + h * OC + ch];
  eb[idx] = s * (1.f / (float)(en - st));
}

// ---------------- node aggregation ----------------
template<int OC>
__global__ __launch_bounds__(256) void k_node_agg(
    const float* __restrict__ attw, const float* __restrict__ eb,
    const float* __restrict__ ew, float* __restrict__ ho) {
  int idx = blockIdx.x * 256 + threadIdx.x;
  if (idx >= 36 * OC) return;
  int ch = idx % OC;
  int node = idx / OC;
  int b = node / 18, ln = node % 18;
  int ncols, cols[4], gis[4];
  if (ln < 16) {
    ncols = 4;
    cols[0] = b * 7 + (ln < 8 ? 0 : 1); gis[0] = b * 67 + ln;
    cols[1] = b * 7 + 2; gis[1] = b * 67 + 16 + ln;
    cols[2] = b * 7 + 3; gis[2] = b * 67 + 32 + ln;
    cols[3] = b * 7 + 4; gis[3] = b * 67 + 48 + ln;
  } else if (ln == 16) {
    ncols = 2;
    cols[0] = b * 7 + 4; gis[0] = b * 67 + 64;
    cols[1] = b * 7 + 5; gis[1] = b * 67 + 65;
    cols[2] = cols[3] = 0; gis[2] = gis[3] = 0;
  } else {
    ncols = 1;
    cols[0] = b * 7 + 6; gis[0] = b * 67 + 66;
    cols[1] = cols[2] = cols[3] = 0; gis[1] = gis[2] = gis[3] = 0;
  }
  float dsum = 0.f;
#pragma unroll
  for (int k = 0; k < 4; ++k) if (k < ncols) dsum += ew[cols[k]];
  float D = dsum > 0.f ? 1.f / dsum : 0.f;
  float s = 0.f;
#pragma unroll
  for (int k = 0; k < 4; ++k) {
    if (k < ncols) {
#pragma unroll
      for (int h = 0; h < 4; ++h)
        s += attw[gis[k] * 4 + h] * eb[((size_t)cols[k] * 4 + h) * OC + ch];
    }
  }
  ho[idx] = fmaxf(0.25f * D * s, 0.f);
}

// ---------------- GroupNorm(32) + SE layer ----------------
template<int C, int Cr>
__global__ __launch_bounds__(512) void k_gn_se(
    const float* __restrict__ hin, const float* __restrict__ w1,
    const float* __restrict__ w2, float* __restrict__ x) {
  int t = threadIdx.x;
  constexpr int gs = C >> 5;
  for (int idx = t; idx < 36 * 32; idx += 512) {
    int node = idx >> 5, g = idx & 31;
    const float* p = hin + (size_t)node * C + g * gs;
    float s = 0.f, s2 = 0.f;
#pragma unroll
    for (int k = 0; k < gs; ++k) { float v = p[k]; s += v; s2 += v * v; }
    float mu = s * (1.f / gs);
    float var = s2 * (1.f / gs) - mu * mu;
    float inv = rsqrtf(fmaxf(var, 0.f) + 1e-5f);
    float* q = x + (size_t)node * C + g * gs;
#pragma unroll
    for (int k = 0; k < gs; ++k) q[k] = (p[k] - mu) * inv;
  }
  __threadfence_block();
  __syncthreads();
  __shared__ float smean[C];
  __shared__ float spart[Cr][17];
  __shared__ float shid[Cr];
  __shared__ float sscale[C];
  if (t < C) {
    float s = 0.f;
    for (int nn = 0; nn < 36; ++nn) s += x[(size_t)nn * C + t];
    smean[t] = s * (1.f / 36.f);
  }
  __syncthreads();
  if (t < Cr * 16) {
    int hid = t >> 4, sub = t & 15;
    constexpr int CH = C / 16;
    float s = 0.f;
#pragma unroll
    for (int k = 0; k < CH; ++k)
      s += w1[(size_t)hid * C + sub * CH + k] * smean[sub * CH + k];
    spart[hid][sub] = s;
  }
  __syncthreads();
  if (t < Cr) {
    float s = 0.f;
#pragma unroll
    for (int k = 0; k < 16; ++k) s += spart[t][k];
    shid[t] = fmaxf(s, 0.f);
  }
  __syncthreads();
  if (t < C) {
    float s = 0.f;
#pragma unroll
    for (int k = 0; k < Cr; ++k) s += w2[(size_t)t * Cr + k] * shid[k];
    sscale[t] = 1.f / (1.f + __expf(-s));
  }
  __syncthreads();
  for (int idx = t; idx < 36 * C; idx += 512) x[idx] *= sscale[idx % C];
}

// ---------------- observers ----------------
__global__ void k_obs(const float* __restrict__ tn, const float* __restrict__ x2,
                      float* __restrict__ out) {
  int t = threadIdx.x;
  if (t >= 128) return;
  int b = t >> 6, ch = t & 63;
  const float* a = tn + (size_t)b * 256 + ch * 4;
  const float* c = x2 + ((size_t)b * 18 + 17) * 256 + ch * 4;
  float m = a[0] + c[0];
  m = fmaxf(m, a[1] + c[1]);
  m = fmaxf(m, a[2] + c[2]);
  m = fmaxf(m, a[3] + c[3]);
  out[b * 64 + ch] = m;
}

extern "C" void kernel_launch(void* const* d_in, const int* in_sizes, int n_in,
                              void* d_out, int out_size, void* d_ws, size_t ws_size,
                              hipStream_t stream) {
  (void)in_sizes; (void)n_in; (void)out_size; (void)ws_size;
  const float* vf    = (const float*)d_in[0];
  const float* vp    = (const float*)d_in[1];
  const float* mf    = (const float*)d_in[2];
  const float* mp    = (const float*)d_in[3];
  const float* tf    = (const float*)d_in[4];
  const float* tp    = (const float*)d_in[5];
  const float* cv1w  = (const float*)d_in[6];
  const float* cv1b  = (const float*)d_in[7];
  const float* cv2w  = (const float*)d_in[8];
  const float* cv2b  = (const float*)d_in[9];
  const float* dc1w  = (const float*)d_in[10];
  const float* dc1b  = (const float*)d_in[11];
  const float* dc2w  = (const float*)d_in[12];
  const float* dc2b  = (const float*)d_in[13];
  const float* tc1w  = (const float*)d_in[14];
  const float* tc1b  = (const float*)d_in[15];
  const float* tc2w  = (const float*)d_in[16];
  const float* tc2b  = (const float*)d_in[17];
  const float* lin1w = (const float*)d_in[18];
  const float* att1  = (const float*)d_in[19];
  const float* lin2w = (const float*)d_in[20];
  const float* att2  = (const float*)d_in[21];
  const float* ew1   = (const float*)d_in[22];
  const float* ew2   = (const float*)d_in[23];
  const float* ea1   = (const float*)d_in[24];
  const float* ea2   = (const float*)d_in[25];
  const float* se1w1 = (const float*)d_in[26];
  const float* se1w2 = (const float*)d_in[27];
  const float* se2w1 = (const float*)d_in[28];
  const float* se2w2 = (const float*)d_in[29];

  float* ws  = (float*)d_ws;
  float* out = (float*)d_out;

  // workspace layout (float units)
  unsigned short* p0n = (unsigned short*)(ws);             // 16x128x128x64 bf16 (vf+vp NHWC)
  unsigned short* q1n = (unsigned short*)(ws + 8388608);   // 16x64x64x128 bf16 (d1n/v1n)
  unsigned short* t1n = (unsigned short*)(ws + 12582912);  // 16x64x64x128 bf16
  unsigned short* v2n = (unsigned short*)(ws + 16777216);  // 16x32x32x256 bf16 (d2n/v2n)
  unsigned short* wtb = (unsigned short*)(ws + 18874368);  // 1,105,920 bf16
  float* sm   = ws + 19427328;
  float* tn   = sm;                 // 512
  float* vn   = sm + 512;           // 4096
  float* dn   = sm + 4608;          // 4096
  float* x0   = sm + 8704;          // 9216
  float* xl   = sm + 17920;         // 102400
  float* eb   = sm + 120520;        // 28672
  float* ho   = sm + 149192;        // 18432
  float* x1   = sm + 167624;        // 18432
  float* x2   = sm + 186056;        // 9216
  float* attw = sm + 195272;        // 536
  float* pmax = sm + 195904;        // 32768

  unsigned short* wTc1 = wtb;             // 9*128*64
  unsigned short* wTd1 = wtb + 73728;
  unsigned short* wTc2 = wtb + 147456;    // 9*256*128
  unsigned short* wTd2 = wtb + 442368;
  unsigned short* wTt1 = wtb + 737280;    // 9*128*256 (tc1: in256->out128)
  unsigned short* wTt2 = wtb + 1032192;   // 9*64*128  (tc2: in128->out64)

  // 0. all weight transforms (one kernel)
  k_wtrans_all<<<4320, 256, 0, stream>>>(cv1w, dc1w, cv2w, dc2w, tc1w, tc2w, wtb);

  // 1. motion branch (uses p0n as scratch; overwritten by vision prep later)
  k_prep<<<4096, 256, 0, stream>>>(mf, mp, p0n);
  k_conv_mfma<64, 128, 64, 64, 1><<<1024, 512, 0, stream>>>(p0n, wTd1, dc1b, q1n);
  k_conv_mfma<128, 256, 32, 32, 2><<<512, 512, 0, stream>>>(q1n, wTd2, dc2b, v2n);
  k_max_part<<<128, 256, 0, stream>>>(v2n, pmax);
  k_ln<<<16, 256, 0, stream>>>(pmax, dn);

  // 2. vision branch (p0n kept = bf16(vf+vp); q1n = v1n kept as deconv1 residual)
  k_prep<<<4096, 256, 0, stream>>>(vf, vp, p0n);
  k_conv_mfma<64, 128, 64, 64, 1><<<1024, 512, 0, stream>>>(p0n, wTc1, cv1b, q1n);
  k_conv_mfma<128, 256, 32, 32, 2><<<512, 512, 0, stream>>>(q1n, wTc2, cv2b, v2n);
  k_max_part<<<128, 256, 0, stream>>>(v2n, pmax);
  k_ln<<<16, 256, 0, stream>>>(pmax, vn);

  // 3. node features (text pool fused)
  k_build_x<<<2, 256, 0, stream>>>(tf, tp, vn, dn, tn, x0);

  // 4. GNN layer 1 (OC=512)
  k_gnn_lin<<<50 * 8, 256, 0, stream>>>(x0, ea1, lin1w, xl, 256, 2048);
  k_gnn_attsm<512><<<1, 256, 0, stream>>>(xl, att1, attw);
  k_edge_agg<512><<<112, 256, 0, stream>>>(xl, attw, eb);
  k_node_agg<512><<<72, 256, 0, stream>>>(attw, eb, ew1, ho);
  k_gn_se<512, 32><<<1, 512, 0, stream>>>(ho, se1w1, se1w2, x1);

  // 5. GNN layer 2 (OC=256)
  k_gnn_lin<<<50 * 4, 256, 0, stream>>>(x1, ea2, lin2w, xl, 512, 1024);
  k_gnn_attsm<256><<<1, 256, 0, stream>>>(xl, att2, attw);
  k_edge_agg<256><<<56, 256, 0, stream>>>(xl, attw, eb);
  k_node_agg<256><<<36, 256, 0, stream>>>(attw, eb, ew2, ho);
  k_gn_se<256, 16><<<1, 512, 0, stream>>>(ho, se2w1, se2w2, x2);

  // 6. observers
  k_obs<<<1, 128, 0, stream>>>(tn, x2, out + 16777216);

  // 7. decoder: t1n = v1n + relu(convT1(v2n + vg[fused])) ; out = bf16(vf+vp) + relu(convT2(t1n))
  k_deconv_mfma<256, 128, 32, 32, 2, true, true><<<512, 256, 0, stream>>>(
      v2n, wTt1, tc1b, q1n, x2, t1n, nullptr);
  k_deconv_mfma<128, 64, 64, 64, 1, false, false><<<1024, 256, 0, stream>>>(
      t1n, wTt2, tc2b, p0n, nullptr, nullptr, out);
}